// Round 11
// baseline (121.586 us; speedup 1.0000x reference)
//
#include <hip/hip_runtime.h>
#include <hip/hip_bf16.h>
#include <hip/hip_fp16.h>
#include <math.h>

#define NB 4
#define NP 2048
#define NC 192
#define KNN 12
#define KSEL 32
#define NEG_SLOPE 0.2f

typedef __attribute__((ext_vector_type(8))) short bf16x8;
typedef __attribute__((ext_vector_type(8))) ushort u16x8;
typedef __attribute__((ext_vector_type(4))) float f32x4;

__device__ __forceinline__ float lrelu(float x) { return x >= 0.0f ? x : NEG_SLOPE * x; }

__device__ __forceinline__ ushort f2bf(float x) {
    unsigned u = __float_as_uint(x);
    unsigned r = (u + 0x7FFFu + ((u >> 16) & 1u)) >> 16;   // RNE
    return (ushort)r;
}

// -- kernel 1: L2-normalize; out: xn f32 (rescore), xh bf16 (sim), xb bf16 (UV)
__global__ void __launch_bounds__(256) k_normalize(const float* __restrict__ nodes,
                                                   float* __restrict__ xn,
                                                   ushort* __restrict__ xh,
                                                   ushort* __restrict__ xb) {
    int wave = threadIdx.x >> 6;
    int lane = threadIdx.x & 63;
    size_t pt = (size_t)blockIdx.x * 4 + wave;
    const float* x = nodes + pt * NC;
    float v0 = x[lane], v1 = x[lane + 64], v2 = x[lane + 128];
    float s = v0 * v0 + v1 * v1 + v2 * v2;
    #pragma unroll
    for (int off = 32; off; off >>= 1) s += __shfl_xor(s, off, 64);
    float inv = 1.0f / fmaxf(sqrtf(s), 1e-12f);
    float f0 = v0 * inv, f1 = v1 * inv, f2 = v2 * inv;
    float* o = xn + pt * NC;
    o[lane] = f0; o[lane + 64] = f1; o[lane + 128] = f2;
    ushort* oh = xh + pt * NC;
    oh[lane] = f2bf(f0); oh[lane + 64] = f2bf(f1); oh[lane + 128] = f2bf(f2);
    ushort* ob = xb + pt * NC;
    ob[lane] = f2bf(v0); ob[lane + 64] = f2bf(v1); ob[lane + 128] = f2bf(v2);
}

// ------- kernel 2: sim = Xh * Xh^T via bf16 MFMA, f16 out (half the traffic) --
__global__ void __launch_bounds__(256) k_sim4(const ushort* __restrict__ xh,
                                              ushort* __restrict__ simh,
                                              size_t xstride, size_t simstride) {
    __shared__ ushort Ah[128][72];
    __shared__ ushort Bh[128][72];
    const ushort* XbH = xh + (size_t)blockIdx.z * xstride;
    ushort* sb = simh + (size_t)blockIdx.z * simstride;
    int t = threadIdx.x;
    int w = t >> 6, l = t & 63;
    int wm = w >> 1, wn = w & 1;
    int lg = l >> 4, lr = l & 15;
    int m0 = blockIdx.y * 128, n0 = blockIdx.x * 128;

    f32x4 acc[4][4];
    #pragma unroll
    for (int mi = 0; mi < 4; ++mi)
        #pragma unroll
        for (int ni = 0; ni < 4; ++ni)
            acc[mi][ni] = (f32x4){0.f, 0.f, 0.f, 0.f};

    int r = t >> 3, c = (t & 7) * 8;
    for (int ks = 0; ks < 3; ++ks) {
        int kb = ks * 64;
        #pragma unroll
        for (int i = 0; i < 4; ++i) {
            int row = r + 32 * i;
            *reinterpret_cast<bf16x8*>(&Ah[row][c]) =
                *reinterpret_cast<const bf16x8*>(&XbH[(size_t)(m0 + row) * NC + kb + c]);
            *reinterpret_cast<bf16x8*>(&Bh[row][c]) =
                *reinterpret_cast<const bf16x8*>(&XbH[(size_t)(n0 + row) * NC + kb + c]);
        }
        __syncthreads();
        #pragma unroll
        for (int ksub = 0; ksub < 2; ++ksub) {
            int ko = ksub * 32 + 8 * lg;
            bf16x8 af[4], bf[4];
            #pragma unroll
            for (int f = 0; f < 4; ++f) {
                af[f] = *reinterpret_cast<const bf16x8*>(&Ah[wm * 64 + f * 16 + lr][ko]);
                bf[f] = *reinterpret_cast<const bf16x8*>(&Bh[wn * 64 + f * 16 + lr][ko]);
            }
            #pragma unroll
            for (int mi = 0; mi < 4; ++mi)
                #pragma unroll
                for (int ni = 0; ni < 4; ++ni)
                    acc[mi][ni] = __builtin_amdgcn_mfma_f32_16x16x32_bf16(af[mi], bf[ni], acc[mi][ni], 0, 0, 0);
        }
        __syncthreads();
    }
    #pragma unroll
    for (int mi = 0; mi < 4; ++mi)
        #pragma unroll
        for (int j = 0; j < 4; ++j) {
            int row = m0 + wm * 64 + mi * 16 + lg * 4 + j;
            ushort* hrow = sb + (size_t)row * NP;
            #pragma unroll
            for (int ni = 0; ni < 4; ++ni) {
                __half h = __float2half(acc[mi][ni][j]);
                hrow[n0 + wn * 64 + ni * 16 + lr] = *reinterpret_cast<const ushort*>(&h);
            }
        }
}

// -- kernel 3: f16 sim, packed-u32 top-32 select + exact f32 rescore -> 12-set -
// packed = (monotone-f16-key << 11) | (2047 - idx): one u32 carries val+idx,
// ties impossible, count(>theta) >= 32 structurally.
__global__ void __launch_bounds__(256) k_topk5(const ushort* __restrict__ simh,
                                               const float* __restrict__ xn,
                                               int* __restrict__ knn,
                                               size_t simstride, size_t xstride) {
    __shared__ unsigned cand[4][64];
    int wv = threadIdx.x >> 6, lane = threadIdx.x & 63;
    int row = blockIdx.x * 4 + wv;
    int batch = row / NP, p = row % NP;
    const ushort* sr = simh + (size_t)batch * simstride + (size_t)p * NP;

    u16x8 h8[4];
    #pragma unroll
    for (int i = 0; i < 4; ++i)
        h8[i] = *reinterpret_cast<const u16x8*>(sr + lane * 8 + i * 512);

    unsigned pk[32];
    #pragma unroll
    for (int i = 0; i < 4; ++i)
        #pragma unroll
        for (int j = 0; j < 8; ++j) {
            int idx = lane * 8 + i * 512 + j;
            unsigned b = (unsigned)(ushort)h8[i][j];
            unsigned key = (b & 0x8000u) ? (0xFFFFu & ~b) : (b | 0x8000u);
            unsigned v = (key << 11) | (unsigned)(2047 - idx);
            pk[i * 8 + j] = (idx == p) ? 0u : v;   // self -> sentinel 0
        }

    unsigned lmax = 0;
    #pragma unroll
    for (int i = 0; i < 32; ++i) lmax = pk[i] > lmax ? pk[i] : lmax;

    // bitonic sort (descending) of 64 lane-maxes
    unsigned sm = lmax;
    #pragma unroll
    for (int k = 2; k <= 64; k <<= 1) {
        #pragma unroll
        for (int j = k >> 1; j >= 1; j >>= 1) {
            unsigned ov = __shfl_xor(sm, j, 64);
            bool lower = (lane & j) == 0;
            bool up = (lane & k) != 0;
            unsigned lo = sm < ov ? sm : ov, hi = sm < ov ? ov : sm;
            sm = (up == lower) ? lo : hi;
        }
    }
    unsigned theta = __shfl(sm, 32, 64);   // 33rd-largest lane-max

    int cnt = 0;
    #pragma unroll
    for (int i = 0; i < 32; ++i) cnt += (pk[i] > theta) ? 1 : 0;
    int x = cnt;
    #pragma unroll
    for (int off = 1; off < 64; off <<= 1) {
        int y = __shfl_up(x, off, 64);
        if (lane >= off) x += y;
    }
    int excl = x - cnt;
    int total = __shfl(x, 63, 64);

    int my_q = -1;
    bool fb = (total < KSEL) || (total > 64);
    if (!fb) {
        cand[wv][lane] = 0u;
        asm volatile("s_waitcnt lgkmcnt(0)" ::: "memory");
        int pos = excl;
        #pragma unroll
        for (int i = 0; i < 32; ++i) {
            if (pk[i] > theta) { cand[wv][pos] = pk[i]; ++pos; }
        }
        asm volatile("s_waitcnt lgkmcnt(0)" ::: "memory");
        unsigned v = cand[wv][lane];
        #pragma unroll
        for (int k = 2; k <= 64; k <<= 1) {
            #pragma unroll
            for (int j = k >> 1; j >= 1; j >>= 1) {
                unsigned ov = __shfl_xor(v, j, 64);
                bool lower = (lane & j) == 0;
                bool up = (lane & k) != 0;
                unsigned lo = v < ov ? v : ov, hi = v < ov ? ov : v;
                v = (up == lower) ? lo : hi;
            }
        }
        unsigned mp = __shfl(v, lane >> 1, 64);   // group g -> g-th largest
        my_q = (mp == 0u) ? -1 : (int)(2047u - (mp & 0x7FFu));
    } else {
        // rare fallback (~0.4% rows): u32 insert list depth 16 + 16 extractions
        unsigned tv[16];
        #pragma unroll
        for (int q = 0; q < 16; ++q) tv[q] = 0u;
        #pragma unroll
        for (int i = 0; i < 32; ++i) {
            unsigned v = pk[i];
            if (v > tv[0]) {
                bool cg[16];
                #pragma unroll
                for (int q = 0; q < 16; ++q) cg[q] = v > tv[q];
                #pragma unroll
                for (int q = 0; q < 15; ++q)
                    tv[q] = cg[q + 1] ? tv[q + 1] : (cg[q] ? v : tv[q]);
                tv[15] = cg[15] ? v : tv[15];
            }
        }
        unsigned mp = 0u;
        #pragma unroll
        for (int rr = 0; rr < 16; ++rr) {
            unsigned bv = tv[15];
            #pragma unroll
            for (int off = 1; off < 64; off <<= 1) {
                unsigned ov = __shfl_xor(bv, off, 64);
                bv = ov > bv ? ov : bv;
            }
            if ((lane >> 1) == rr) mp = bv;
            if (bv == tv[15]) {   // unique winner pops
                #pragma unroll
                for (int s = 15; s > 0; --s) tv[s] = tv[s - 1];
                tv[0] = 0u;
            }
        }
        my_q = (mp == 0u) ? -1 : (int)(2047u - (mp & 0x7FFu));
    }

    // exact f32 rescore: group g = lane>>1 owns candidate my_q; slice lane&1
    const float* xb = xn + (size_t)batch * xstride;
    int qa = my_q < 0 ? 0 : my_q;
    const float* cp = xb + (size_t)p * NC + (lane & 1) * 96;
    const float* cq = xb + (size_t)qa * NC + (lane & 1) * 96;
    float dot = 0.f;
    #pragma unroll
    for (int i = 0; i < 24; ++i) {
        float4 a = *reinterpret_cast<const float4*>(cp + i * 4);
        float4 bq = *reinterpret_cast<const float4*>(cq + i * 4);
        dot += a.x * bq.x + a.y * bq.y + a.z * bq.z + a.w * bq.w;
    }
    dot += __shfl_xor(dot, 1, 64);
    int g = lane >> 1;
    int rank = 0;
    #pragma unroll
    for (int j = 0; j < KSEL; ++j) {
        float vj = __shfl(dot, j * 2, 64);
        int   qj = __shfl(my_q, j * 2, 64);
        if (j != g && qj >= 0 && (vj > dot || (vj == dot && qj < my_q))) ++rank;
    }
    bool keep = ((lane & 1) == 0) && (my_q >= 0) && (rank < KNN);
    unsigned long long mask = __ballot(keep);
    int pos = __popcll(mask & ((1ull << lane) - 1));
    if (keep) knn[(size_t)row * KNN + pos] = my_q;
}

// ---- prep: w1t[384][192] bf16 = [(W1a - W1b)^T ; W1b^T] ----------------------
__global__ void __launch_bounds__(256) k_w1t(const float* __restrict__ W1,
                                             ushort* __restrict__ w1t) {
    int idx = blockIdx.x * 256 + threadIdx.x;
    if (idx >= 2 * NC * NC) return;
    int n = idx / NC, k = idx % NC;
    float v;
    if (n < NC) v = W1[(size_t)k * NC + n] - W1[(size_t)(k + NC) * NC + n];
    else        v = W1[(size_t)(k + NC) * NC + (n - NC)];
    w1t[idx] = f2bf(v);
}

// ---- prep: W2T bf16 [n][k] from W2 f32 [k][n] --------------------------------
__global__ void __launch_bounds__(256) k_w2t(const float* __restrict__ W2,
                                             ushort* __restrict__ w2t) {
    int idx = blockIdx.x * 256 + threadIdx.x;
    if (idx >= NC * NC) return;
    int n = idx / NC, k = idx % NC;
    w2t[(size_t)n * NC + k] = f2bf(W2[(size_t)k * NC + n]);
}

// ---- kernel 4: [U'|V] = Xb @ w1t^T via MFMA; bias fused into U' --------------
#define UVM 32
__global__ void __launch_bounds__(256) k_uv2(const ushort* __restrict__ xb,
                                             const ushort* __restrict__ w1t,
                                             const float* __restrict__ b1,
                                             float* __restrict__ up,
                                             float* __restrict__ vv) {
    __shared__ ushort xs[UVM][200];
    int t = threadIdx.x;
    int w = t >> 6, l = t & 63;
    int lg = l >> 4, lr = l & 15;
    int p0 = blockIdx.x * UVM;
    for (int i = t; i < UVM * 24; i += 256) {
        int row = i / 24, c = (i % 24) * 8;
        *reinterpret_cast<bf16x8*>(&xs[row][c]) =
            *reinterpret_cast<const bf16x8*>(&xb[(size_t)(p0 + row) * NC + c]);
    }
    __syncthreads();
    int n0 = w * 96;
    f32x4 acc[2][6];
    #pragma unroll
    for (int mt = 0; mt < 2; ++mt)
        #pragma unroll
        for (int nt = 0; nt < 6; ++nt)
            acc[mt][nt] = (f32x4){0.f, 0.f, 0.f, 0.f};
    #pragma unroll
    for (int ks = 0; ks < 6; ++ks) {
        bf16x8 bfr[6];
        #pragma unroll
        for (int nt = 0; nt < 6; ++nt)
            bfr[nt] = *reinterpret_cast<const bf16x8*>(
                &w1t[(size_t)(n0 + nt * 16 + lr) * NC + ks * 32 + lg * 8]);
        bf16x8 a0 = *reinterpret_cast<const bf16x8*>(&xs[lr][ks * 32 + lg * 8]);
        bf16x8 a1 = *reinterpret_cast<const bf16x8*>(&xs[16 + lr][ks * 32 + lg * 8]);
        #pragma unroll
        for (int nt = 0; nt < 6; ++nt) {
            acc[0][nt] = __builtin_amdgcn_mfma_f32_16x16x32_bf16(a0, bfr[nt], acc[0][nt], 0, 0, 0);
            acc[1][nt] = __builtin_amdgcn_mfma_f32_16x16x32_bf16(a1, bfr[nt], acc[1][nt], 0, 0, 0);
        }
    }
    bool isU = (n0 < NC);
    #pragma unroll
    for (int nt = 0; nt < 6; ++nt) {
        int col = n0 + nt * 16 + lr;
        float bb = isU ? b1[col] : 0.f;
        int ocol = isU ? col : col - NC;
        float* dst = isU ? up : vv;
        #pragma unroll
        for (int mt = 0; mt < 2; ++mt)
            #pragma unroll
            for (int j = 0; j < 4; ++j) {
                int pt = p0 + mt * 16 + lg * 4 + j;
                dst[(size_t)pt * NC + ocol] = acc[mt][nt][j] + bb;
            }
    }
}

// ---- kernel 5: edge MLP; EPW=1 (48 AGPR acc), 16 waves/block, 4 waves/SIMD ---
__device__ __forceinline__ bf16x8 packh(float4 ua, float4 ub, float4 va, float4 vb) {
    union { bf16x8 v8; __hip_bfloat162 h2[4]; } r;
    r.h2[0] = __float22bfloat162_rn(make_float2(lrelu(ua.x + va.x), lrelu(ua.y + va.y)));
    r.h2[1] = __float22bfloat162_rn(make_float2(lrelu(ua.z + va.z), lrelu(ua.w + va.w)));
    r.h2[2] = __float22bfloat162_rn(make_float2(lrelu(ub.x + vb.x), lrelu(ub.y + vb.y)));
    r.h2[3] = __float22bfloat162_rn(make_float2(lrelu(ub.z + vb.z), lrelu(ub.w + vb.w)));
    return r.v8;
}

#define EW 16   // waves/block, 1 point each
__global__ void __launch_bounds__(1024, 4) k_edge7(const float* __restrict__ up,
                                                   const float* __restrict__ vv,
                                                   const int* __restrict__ knn,
                                                   const ushort* __restrict__ w2t,
                                                   const float* __restrict__ b2,
                                                   const float* __restrict__ gamma,
                                                   const float* __restrict__ beta,
                                                   float* __restrict__ out) {
    __shared__ ushort w2s[NC][200];   // 76.8 KB
    __shared__ float aggs[EW][NC];    // 12.3 KB -> 89.1 KB total, 1 block/CU
    int t = threadIdx.x;
    int wv = t >> 6, l = t & 63;
    int lg = l >> 4, lr = l & 15;

    int pt0 = blockIdx.x * EW + wv;
    int lre = lr < KNN ? lr : KNN - 1;
    int q0 = knn[(size_t)pt0 * KNN + lre];

    for (int i = t; i < NC * 24; i += 1024) {
        int r_ = i / 24, c_ = i % 24;
        *reinterpret_cast<bf16x8*>(&w2s[r_][c_ * 8]) =
            *reinterpret_cast<const bf16x8*>(&w2t[(size_t)r_ * NC + c_ * 8]);
    }
    __syncthreads();

    int b = pt0 / NP;
    const float* u0p = up + (size_t)pt0 * NC + 8 * lg;
    const float* v0p = vv + ((size_t)b * NP + q0) * NC + 8 * lg;

    f32x4 acc[12];
    #pragma unroll
    for (int nt = 0; nt < 12; ++nt) acc[nt] = (f32x4){0.f, 0.f, 0.f, 0.f};

    float4 sUa[2], sUb[2], sVa[2], sVb[2];
#define LDST(ph, ks) do { \
        sUa[ph] = *reinterpret_cast<const float4*>(u0p + (ks) * 32);     \
        sUb[ph] = *reinterpret_cast<const float4*>(u0p + (ks) * 32 + 4); \
        sVa[ph] = *reinterpret_cast<const float4*>(v0p + (ks) * 32);     \
        sVb[ph] = *reinterpret_cast<const float4*>(v0p + (ks) * 32 + 4); \
    } while (0)

    LDST(0, 0);
    #pragma unroll
    for (int ks = 0; ks < 6; ++ks) {
        int ph = ks & 1;
        if (ks < 5) LDST(ph ^ 1, ks + 1);
        bf16x8 a0 = packh(sUa[ph], sUb[ph], sVa[ph], sVb[ph]);
        #pragma unroll
        for (int nt = 0; nt < 12; ++nt) {
            bf16x8 bfr = *reinterpret_cast<const bf16x8*>(&w2s[nt * 16 + lr][ks * 32 + lg * 8]);
            acc[nt] = __builtin_amdgcn_mfma_f32_16x16x32_bf16(a0, bfr, acc[nt], 0, 0, 0);
        }
    }
#undef LDST

    #pragma unroll
    for (int nt = 0; nt < 12; ++nt) {
        float bb = b2[nt * 16 + lr];
        float s = 0.f;
        if (lg < 3) {
            #pragma unroll
            for (int j = 0; j < 4; ++j) s += lrelu(acc[nt][j] + bb);
        }
        s += __shfl_xor(s, 16, 64);
        s += __shfl_xor(s, 32, 64);
        if (lg == 0) aggs[wv][nt * 16 + lr] = s * (1.0f / KNN);
    }
    asm volatile("s_waitcnt lgkmcnt(0)" ::: "memory");

    float a0 = aggs[wv][l], a1 = aggs[wv][l + 64], a2 = aggs[wv][l + 128];
    float s = a0 + a1 + a2;
    #pragma unroll
    for (int off = 32; off; off >>= 1) s += __shfl_xor(s, off, 64);
    float mu = s / (float)NC;
    float d0 = a0 - mu, d1 = a1 - mu, d2 = a2 - mu;
    float vs = d0 * d0 + d1 * d1 + d2 * d2;
    #pragma unroll
    for (int off = 32; off; off >>= 1) vs += __shfl_xor(vs, off, 64);
    float rstd = 1.0f / sqrtf(vs / (float)NC + 1e-5f);
    float* o = out + (size_t)pt0 * NC;
    o[l]       = d0 * rstd * gamma[l]       + beta[l];
    o[l + 64]  = d1 * rstd * gamma[l + 64]  + beta[l + 64];
    o[l + 128] = d2 * rstd * gamma[l + 128] + beta[l + 128];
}

extern "C" void kernel_launch(void* const* d_in, const int* in_sizes, int n_in,
                              void* d_out, int out_size, void* d_ws, size_t ws_size,
                              hipStream_t stream) {
    const float* nodes = (const float*)d_in[0];
    const float* W1    = (const float*)d_in[1];
    const float* b1    = (const float*)d_in[2];
    const float* W2    = (const float*)d_in[3];
    const float* b2    = (const float*)d_in[4];
    const float* gamma = (const float*)d_in[5];
    const float* beta  = (const float*)d_in[6];
    float* out = (float*)d_out;

    const size_t BPC = (size_t)NB * NP * NC;
    float*  xn  = (float*)d_ws;                        // B*P*C f32
    float*  up  = xn + BPC;                            // B*P*C f32
    float*  vv  = up + BPC;                            // B*P*C f32
    ushort* xh  = (ushort*)(vv + BPC);                 // B*P*C bf16 (normalized)
    ushort* xb  = xh + BPC;                            // B*P*C bf16 (raw)
    int*    knn = (int*)(xb + BPC);                    // B*P*K
    ushort* w2t = (ushort*)(knn + (size_t)NB * NP * KNN); // C*C bf16
    ushort* w1t = w2t + (size_t)NC * NC;               // 2C*C bf16
    ushort* simh = (ushort*)(((uintptr_t)(w1t + (size_t)2 * NC * NC) + 15) & ~(uintptr_t)15);

    size_t fixed_bytes = (size_t)((char*)simh - (char*)d_ws);
    bool full = ws_size >= fixed_bytes + (size_t)NB * NP * NP * 2;

    k_normalize<<<NB * NP / 4, 256, 0, stream>>>(nodes, xn, xh, xb);
    k_w1t<<<(2 * NC * NC + 255) / 256, 256, 0, stream>>>(W1, w1t);
    k_w2t<<<(NC * NC + 255) / 256, 256, 0, stream>>>(W2, w2t);
    k_uv2<<<NB * NP / UVM, 256, 0, stream>>>(xb, w1t, b1, up, vv);
    if (full) {
        k_sim4<<<dim3(NP / 128, NP / 128, NB), 256, 0, stream>>>(xh, simh,
                                                                 (size_t)NP * NC, (size_t)NP * NP);
        k_topk5<<<NB * NP / 4, 256, 0, stream>>>(simh, xn, knn,
                                                 (size_t)NP * NP, (size_t)NP * NC);
    } else {
        for (int b = 0; b < NB; ++b) {
            k_sim4<<<dim3(NP / 128, NP / 128, 1), 256, 0, stream>>>(xh + (size_t)b * NP * NC, simh, 0, 0);
            k_topk5<<<NP / 4, 256, 0, stream>>>(simh, xn + (size_t)b * NP * NC,
                                                knn + (size_t)b * NP * KNN, 0, 0);
        }
    }
    k_edge7<<<NB * NP / EW, 1024, 0, stream>>>(up, vv, knn, w2t, b2, gamma, beta, out);
}

// Round 12
// 109.547 us; speedup vs baseline: 1.1099x; 1.1099x over previous
//
#include <hip/hip_runtime.h>
#include <hip/hip_bf16.h>
#include <hip/hip_fp16.h>
#include <math.h>

#define NB 4
#define NP 2048
#define NC 192
#define KNN 12
#define KSEL 16
#define NEG_SLOPE 0.2f

typedef __attribute__((ext_vector_type(8))) short bf16x8;
typedef __attribute__((ext_vector_type(8))) ushort u16x8;
typedef __attribute__((ext_vector_type(4))) float f32x4;

__device__ __forceinline__ float lrelu(float x) { return x >= 0.0f ? x : NEG_SLOPE * x; }

__device__ __forceinline__ ushort f2bf(float x) {
    unsigned u = __float_as_uint(x);
    unsigned r = (u + 0x7FFFu + ((u >> 16) & 1u)) >> 16;   // RNE
    return (ushort)r;
}

// monotone f16->u16 key, packed with complemented index; self -> 0 sentinel
__device__ __forceinline__ unsigned pkkey(unsigned b, int idx, int p) {
    unsigned key = (b & 0x8000u) ? (0xFFFFu & ~b) : (b | 0x8000u);
    unsigned v = (key << 11) | (unsigned)(2047 - idx);
    return (idx == p) ? 0u : v;
}

// -- kernel 1: L2-normalize; out: xn f32 (rescore), xh bf16 (sim), xb bf16 (UV)
__global__ void __launch_bounds__(256) k_normalize(const float* __restrict__ nodes,
                                                   float* __restrict__ xn,
                                                   ushort* __restrict__ xh,
                                                   ushort* __restrict__ xb) {
    int wave = threadIdx.x >> 6;
    int lane = threadIdx.x & 63;
    size_t pt = (size_t)blockIdx.x * 4 + wave;
    const float* x = nodes + pt * NC;
    float v0 = x[lane], v1 = x[lane + 64], v2 = x[lane + 128];
    float s = v0 * v0 + v1 * v1 + v2 * v2;
    #pragma unroll
    for (int off = 32; off; off >>= 1) s += __shfl_xor(s, off, 64);
    float inv = 1.0f / fmaxf(sqrtf(s), 1e-12f);
    float f0 = v0 * inv, f1 = v1 * inv, f2 = v2 * inv;
    float* o = xn + pt * NC;
    o[lane] = f0; o[lane + 64] = f1; o[lane + 128] = f2;
    ushort* oh = xh + pt * NC;
    oh[lane] = f2bf(f0); oh[lane + 64] = f2bf(f1); oh[lane + 128] = f2bf(f2);
    ushort* ob = xb + pt * NC;
    ob[lane] = f2bf(v0); ob[lane + 64] = f2bf(v1); ob[lane + 128] = f2bf(v2);
}

// ------- kernel 2: sim = Xh * Xh^T via bf16 MFMA, f16 out (half the traffic) --
__global__ void __launch_bounds__(256) k_sim4(const ushort* __restrict__ xh,
                                              ushort* __restrict__ simh,
                                              size_t xstride, size_t simstride) {
    __shared__ ushort Ah[128][72];
    __shared__ ushort Bh[128][72];
    const ushort* XbH = xh + (size_t)blockIdx.z * xstride;
    ushort* sb = simh + (size_t)blockIdx.z * simstride;
    int t = threadIdx.x;
    int w = t >> 6, l = t & 63;
    int wm = w >> 1, wn = w & 1;
    int lg = l >> 4, lr = l & 15;
    int m0 = blockIdx.y * 128, n0 = blockIdx.x * 128;

    f32x4 acc[4][4];
    #pragma unroll
    for (int mi = 0; mi < 4; ++mi)
        #pragma unroll
        for (int ni = 0; ni < 4; ++ni)
            acc[mi][ni] = (f32x4){0.f, 0.f, 0.f, 0.f};

    int r = t >> 3, c = (t & 7) * 8;
    for (int ks = 0; ks < 3; ++ks) {
        int kb = ks * 64;
        #pragma unroll
        for (int i = 0; i < 4; ++i) {
            int row = r + 32 * i;
            *reinterpret_cast<bf16x8*>(&Ah[row][c]) =
                *reinterpret_cast<const bf16x8*>(&XbH[(size_t)(m0 + row) * NC + kb + c]);
            *reinterpret_cast<bf16x8*>(&Bh[row][c]) =
                *reinterpret_cast<const bf16x8*>(&XbH[(size_t)(n0 + row) * NC + kb + c]);
        }
        __syncthreads();
        #pragma unroll
        for (int ksub = 0; ksub < 2; ++ksub) {
            int ko = ksub * 32 + 8 * lg;
            bf16x8 af[4], bf[4];
            #pragma unroll
            for (int f = 0; f < 4; ++f) {
                af[f] = *reinterpret_cast<const bf16x8*>(&Ah[wm * 64 + f * 16 + lr][ko]);
                bf[f] = *reinterpret_cast<const bf16x8*>(&Bh[wn * 64 + f * 16 + lr][ko]);
            }
            #pragma unroll
            for (int mi = 0; mi < 4; ++mi)
                #pragma unroll
                for (int ni = 0; ni < 4; ++ni)
                    acc[mi][ni] = __builtin_amdgcn_mfma_f32_16x16x32_bf16(af[mi], bf[ni], acc[mi][ni], 0, 0, 0);
        }
        __syncthreads();
    }
    #pragma unroll
    for (int mi = 0; mi < 4; ++mi)
        #pragma unroll
        for (int j = 0; j < 4; ++j) {
            int row = m0 + wm * 64 + mi * 16 + lg * 4 + j;
            ushort* hrow = sb + (size_t)row * NP;
            #pragma unroll
            for (int ni = 0; ni < 4; ++ni) {
                __half h = __float2half(acc[mi][ni][j]);
                hrow[n0 + wn * 64 + ni * 16 + lr] = *reinterpret_cast<const ushort*>(&h);
            }
        }
}

// rare fallback for one row: u32 insert list depth 16 + 16 extraction rounds
__device__ __noinline__ int topk_fb(const u16x8* h8, int p, int lane) {
    unsigned tv[16];
    #pragma unroll
    for (int q = 0; q < 16; ++q) tv[q] = 0u;
    #pragma unroll
    for (int i = 0; i < 4; ++i)
        #pragma unroll
        for (int j = 0; j < 8; ++j) {
            unsigned v = pkkey((unsigned)(ushort)h8[i][j], lane * 8 + i * 512 + j, p);
            if (v > tv[0]) {
                bool cg[16];
                #pragma unroll
                for (int q = 0; q < 16; ++q) cg[q] = v > tv[q];
                #pragma unroll
                for (int q = 0; q < 15; ++q)
                    tv[q] = cg[q + 1] ? tv[q + 1] : (cg[q] ? v : tv[q]);
                tv[15] = cg[15] ? v : tv[15];
            }
        }
    unsigned mp = 0u;
    #pragma unroll
    for (int rr = 0; rr < 16; ++rr) {
        unsigned bv = tv[15];
        #pragma unroll
        for (int off = 1; off < 64; off <<= 1) {
            unsigned ov = __shfl_xor(bv, off, 64);
            bv = ov > bv ? ov : bv;
        }
        if ((lane >> 2) == rr) mp = bv;
        if (bv == tv[15]) {
            #pragma unroll
            for (int s = 15; s > 0; --s) tv[s] = tv[s - 1];
            tv[0] = 0u;
        }
    }
    return (mp == 0u) ? -1 : (int)(2047u - (mp & 0x7FFu));
}

// -- kernel 3: 2 rows/wave, packed-u32 top-16 select + exact f32 rescore -------
__global__ void __launch_bounds__(256) k_topk6(const ushort* __restrict__ simh,
                                               const float* __restrict__ xn,
                                               int* __restrict__ knn,
                                               size_t simstride, size_t xstride) {
    __shared__ unsigned cand[4][2][64];
    int wv = threadIdx.x >> 6, lane = threadIdx.x & 63;
    int row0 = blockIdx.x * 8 + wv * 2;     // even -> both rows share a batch
    int row1 = row0 + 1;
    int b = row0 / NP;
    int p0 = row0 % NP, p1 = p0 + 1;
    const ushort* sr0 = simh + (size_t)b * simstride + (size_t)p0 * NP;
    const ushort* sr1 = sr0 + NP;

    u16x8 h80[4], h81[4];
    #pragma unroll
    for (int i = 0; i < 4; ++i) {
        h80[i] = *reinterpret_cast<const u16x8*>(sr0 + lane * 8 + i * 512);
        h81[i] = *reinterpret_cast<const u16x8*>(sr1 + lane * 8 + i * 512);
    }

    // per-lane max (recompute transform; VALU-cheap, register-cheap)
    unsigned lmax0 = 0, lmax1 = 0;
    #pragma unroll
    for (int i = 0; i < 4; ++i)
        #pragma unroll
        for (int j = 0; j < 8; ++j) {
            int idx = lane * 8 + i * 512 + j;
            unsigned v0 = pkkey((unsigned)(ushort)h80[i][j], idx, p0);
            unsigned v1 = pkkey((unsigned)(ushort)h81[i][j], idx, p1);
            lmax0 = v0 > lmax0 ? v0 : lmax0;
            lmax1 = v1 > lmax1 ? v1 : lmax1;
        }

    // interleaved descending bitonic of the 64 lane-maxes (2 rows, ILP)
    unsigned sm0 = lmax0, sm1 = lmax1;
    #pragma unroll
    for (int k = 2; k <= 64; k <<= 1) {
        #pragma unroll
        for (int j = k >> 1; j >= 1; j >>= 1) {
            unsigned ov0 = __shfl_xor(sm0, j, 64);
            unsigned ov1 = __shfl_xor(sm1, j, 64);
            bool keep_lo = (((lane & k) != 0) == ((lane & j) == 0));
            unsigned lo0 = sm0 < ov0 ? sm0 : ov0, hi0 = sm0 < ov0 ? ov0 : sm0;
            unsigned lo1 = sm1 < ov1 ? sm1 : ov1, hi1 = sm1 < ov1 ? ov1 : sm1;
            sm0 = keep_lo ? lo0 : hi0;
            sm1 = keep_lo ? lo1 : hi1;
        }
    }
    unsigned theta0 = __shfl(sm0, KSEL, 64);   // 17th-largest lane-max
    unsigned theta1 = __shfl(sm1, KSEL, 64);

    // count + exclusive scan (interleaved)
    int cnt0 = 0, cnt1 = 0;
    #pragma unroll
    for (int i = 0; i < 4; ++i)
        #pragma unroll
        for (int j = 0; j < 8; ++j) {
            int idx = lane * 8 + i * 512 + j;
            cnt0 += (pkkey((unsigned)(ushort)h80[i][j], idx, p0) > theta0) ? 1 : 0;
            cnt1 += (pkkey((unsigned)(ushort)h81[i][j], idx, p1) > theta1) ? 1 : 0;
        }
    int x0 = cnt0, x1 = cnt1;
    #pragma unroll
    for (int off = 1; off < 64; off <<= 1) {
        int y0 = __shfl_up(x0, off, 64);
        int y1 = __shfl_up(x1, off, 64);
        if (lane >= off) { x0 += y0; x1 += y1; }
    }
    int excl0 = x0 - cnt0, excl1 = x1 - cnt1;
    int total0 = __shfl(x0, 63, 64), total1 = __shfl(x1, 63, 64);
    bool fb0 = total0 > 64, fb1 = total1 > 64;   // count >= 16 guaranteed

    // compact candidates into LDS (per row, only if it fits)
    cand[wv][0][lane] = 0u;
    cand[wv][1][lane] = 0u;
    asm volatile("s_waitcnt lgkmcnt(0)" ::: "memory");
    if (!fb0) {
        int pos = excl0;
        #pragma unroll
        for (int i = 0; i < 4; ++i)
            #pragma unroll
            for (int j = 0; j < 8; ++j) {
                int idx = lane * 8 + i * 512 + j;
                unsigned v = pkkey((unsigned)(ushort)h80[i][j], idx, p0);
                if (v > theta0) { cand[wv][0][pos] = v; ++pos; }
            }
    }
    if (!fb1) {
        int pos = excl1;
        #pragma unroll
        for (int i = 0; i < 4; ++i)
            #pragma unroll
            for (int j = 0; j < 8; ++j) {
                int idx = lane * 8 + i * 512 + j;
                unsigned v = pkkey((unsigned)(ushort)h81[i][j], idx, p1);
                if (v > theta1) { cand[wv][1][pos] = v; ++pos; }
            }
    }
    asm volatile("s_waitcnt lgkmcnt(0)" ::: "memory");

    // interleaved descending bitonic of the (<=64) candidates
    unsigned v0 = cand[wv][0][lane];
    unsigned v1 = cand[wv][1][lane];
    #pragma unroll
    for (int k = 2; k <= 64; k <<= 1) {
        #pragma unroll
        for (int j = k >> 1; j >= 1; j >>= 1) {
            unsigned ov0 = __shfl_xor(v0, j, 64);
            unsigned ov1 = __shfl_xor(v1, j, 64);
            bool keep_lo = (((lane & k) != 0) == ((lane & j) == 0));
            unsigned lo0 = v0 < ov0 ? v0 : ov0, hi0 = v0 < ov0 ? ov0 : v0;
            unsigned lo1 = v1 < ov1 ? v1 : ov1, hi1 = v1 < ov1 ? ov1 : v1;
            v0 = keep_lo ? lo0 : hi0;
            v1 = keep_lo ? lo1 : hi1;
        }
    }
    int g = lane >> 2;                        // 16 groups x 4 lanes
    unsigned mp0 = __shfl(v0, g, 64);
    unsigned mp1 = __shfl(v1, g, 64);
    int my_q0 = (mp0 == 0u) ? -1 : (int)(2047u - (mp0 & 0x7FFu));
    int my_q1 = (mp1 == 0u) ? -1 : (int)(2047u - (mp1 & 0x7FFu));
    if (fb0) my_q0 = topk_fb(h80, p0, lane);
    if (fb1) my_q1 = topk_fb(h81, p1, lane);

    // exact f32 rescore (4-lane slices of 48), both rows interleaved
    const float* xb = xn + (size_t)b * xstride;
    int qa0 = my_q0 < 0 ? 0 : my_q0;
    int qa1 = my_q1 < 0 ? 0 : my_q1;
    const float* cp0 = xb + (size_t)p0 * NC + (lane & 3) * 48;
    const float* cq0 = xb + (size_t)qa0 * NC + (lane & 3) * 48;
    const float* cp1 = xb + (size_t)p1 * NC + (lane & 3) * 48;
    const float* cq1 = xb + (size_t)qa1 * NC + (lane & 3) * 48;
    float dot0 = 0.f, dot1 = 0.f;
    #pragma unroll
    for (int i = 0; i < 12; ++i) {
        float4 a0 = *reinterpret_cast<const float4*>(cp0 + i * 4);
        float4 b0 = *reinterpret_cast<const float4*>(cq0 + i * 4);
        float4 a1 = *reinterpret_cast<const float4*>(cp1 + i * 4);
        float4 b1 = *reinterpret_cast<const float4*>(cq1 + i * 4);
        dot0 += a0.x * b0.x + a0.y * b0.y + a0.z * b0.z + a0.w * b0.w;
        dot1 += a1.x * b1.x + a1.y * b1.y + a1.z * b1.z + a1.w * b1.w;
    }
    dot0 += __shfl_xor(dot0, 1, 64); dot0 += __shfl_xor(dot0, 2, 64);
    dot1 += __shfl_xor(dot1, 1, 64); dot1 += __shfl_xor(dot1, 2, 64);

    int rank0 = 0, rank1 = 0;
    #pragma unroll
    for (int j = 0; j < KSEL; ++j) {
        float vj0 = __shfl(dot0, j * 4, 64);
        int   qj0 = __shfl(my_q0, j * 4, 64);
        float vj1 = __shfl(dot1, j * 4, 64);
        int   qj1 = __shfl(my_q1, j * 4, 64);
        if (j != g && qj0 >= 0 && (vj0 > dot0 || (vj0 == dot0 && qj0 < my_q0))) ++rank0;
        if (j != g && qj1 >= 0 && (vj1 > dot1 || (vj1 == dot1 && qj1 < my_q1))) ++rank1;
    }
    bool keep0 = ((lane & 3) == 0) && (my_q0 >= 0) && (rank0 < KNN);
    unsigned long long m0 = __ballot(keep0);
    int ps0 = __popcll(m0 & ((1ull << lane) - 1));
    if (keep0) knn[(size_t)row0 * KNN + ps0] = my_q0;
    bool keep1 = ((lane & 3) == 0) && (my_q1 >= 0) && (rank1 < KNN);
    unsigned long long m1 = __ballot(keep1);
    int ps1 = __popcll(m1 & ((1ull << lane) - 1));
    if (keep1) knn[(size_t)row1 * KNN + ps1] = my_q1;
}

// ---- prep: w1t[384][192] bf16 = [(W1a - W1b)^T ; W1b^T] ----------------------
__global__ void __launch_bounds__(256) k_w1t(const float* __restrict__ W1,
                                             ushort* __restrict__ w1t) {
    int idx = blockIdx.x * 256 + threadIdx.x;
    if (idx >= 2 * NC * NC) return;
    int n = idx / NC, k = idx % NC;
    float v;
    if (n < NC) v = W1[(size_t)k * NC + n] - W1[(size_t)(k + NC) * NC + n];
    else        v = W1[(size_t)(k + NC) * NC + (n - NC)];
    w1t[idx] = f2bf(v);
}

// ---- prep: W2T bf16 [n][k] from W2 f32 [k][n] --------------------------------
__global__ void __launch_bounds__(256) k_w2t(const float* __restrict__ W2,
                                             ushort* __restrict__ w2t) {
    int idx = blockIdx.x * 256 + threadIdx.x;
    if (idx >= NC * NC) return;
    int n = idx / NC, k = idx % NC;
    w2t[(size_t)n * NC + k] = f2bf(W2[(size_t)k * NC + n]);
}

// ---- kernel 4: [U'|V] = Xb @ w1t^T via MFMA; bias fused into U' --------------
#define UVM 32
__global__ void __launch_bounds__(256) k_uv2(const ushort* __restrict__ xb,
                                             const ushort* __restrict__ w1t,
                                             const float* __restrict__ b1,
                                             float* __restrict__ up,
                                             float* __restrict__ vv) {
    __shared__ ushort xs[UVM][200];
    int t = threadIdx.x;
    int w = t >> 6, l = t & 63;
    int lg = l >> 4, lr = l & 15;
    int p0 = blockIdx.x * UVM;
    for (int i = t; i < UVM * 24; i += 256) {
        int row = i / 24, c = (i % 24) * 8;
        *reinterpret_cast<bf16x8*>(&xs[row][c]) =
            *reinterpret_cast<const bf16x8*>(&xb[(size_t)(p0 + row) * NC + c]);
    }
    __syncthreads();
    int n0 = w * 96;
    f32x4 acc[2][6];
    #pragma unroll
    for (int mt = 0; mt < 2; ++mt)
        #pragma unroll
        for (int nt = 0; nt < 6; ++nt)
            acc[mt][nt] = (f32x4){0.f, 0.f, 0.f, 0.f};
    #pragma unroll
    for (int ks = 0; ks < 6; ++ks) {
        bf16x8 bfr[6];
        #pragma unroll
        for (int nt = 0; nt < 6; ++nt)
            bfr[nt] = *reinterpret_cast<const bf16x8*>(
                &w1t[(size_t)(n0 + nt * 16 + lr) * NC + ks * 32 + lg * 8]);
        bf16x8 a0 = *reinterpret_cast<const bf16x8*>(&xs[lr][ks * 32 + lg * 8]);
        bf16x8 a1 = *reinterpret_cast<const bf16x8*>(&xs[16 + lr][ks * 32 + lg * 8]);
        #pragma unroll
        for (int nt = 0; nt < 6; ++nt) {
            acc[0][nt] = __builtin_amdgcn_mfma_f32_16x16x32_bf16(a0, bfr[nt], acc[0][nt], 0, 0, 0);
            acc[1][nt] = __builtin_amdgcn_mfma_f32_16x16x32_bf16(a1, bfr[nt], acc[1][nt], 0, 0, 0);
        }
    }
    bool isU = (n0 < NC);
    #pragma unroll
    for (int nt = 0; nt < 6; ++nt) {
        int col = n0 + nt * 16 + lr;
        float bb = isU ? b1[col] : 0.f;
        int ocol = isU ? col : col - NC;
        float* dst = isU ? up : vv;
        #pragma unroll
        for (int mt = 0; mt < 2; ++mt)
            #pragma unroll
            for (int j = 0; j < 4; ++j) {
                int pt = p0 + mt * 16 + lg * 4 + j;
                dst[(size_t)pt * NC + ocol] = acc[mt][nt][j] + bb;
            }
    }
}

// ---- kernel 5: edge MLP; EPW=1 (48 AGPR acc), 16 waves/block, 4 waves/SIMD ---
__device__ __forceinline__ bf16x8 packh(float4 ua, float4 ub, float4 va, float4 vb) {
    union { bf16x8 v8; __hip_bfloat162 h2[4]; } r;
    r.h2[0] = __float22bfloat162_rn(make_float2(lrelu(ua.x + va.x), lrelu(ua.y + va.y)));
    r.h2[1] = __float22bfloat162_rn(make_float2(lrelu(ua.z + va.z), lrelu(ua.w + va.w)));
    r.h2[2] = __float22bfloat162_rn(make_float2(lrelu(ub.x + vb.x), lrelu(ub.y + vb.y)));
    r.h2[3] = __float22bfloat162_rn(make_float2(lrelu(ub.z + vb.z), lrelu(ub.w + vb.w)));
    return r.v8;
}

#define EW 16   // waves/block, 1 point each
__global__ void __launch_bounds__(1024, 4) k_edge7(const float* __restrict__ up,
                                                   const float* __restrict__ vv,
                                                   const int* __restrict__ knn,
                                                   const ushort* __restrict__ w2t,
                                                   const float* __restrict__ b2,
                                                   const float* __restrict__ gamma,
                                                   const float* __restrict__ beta,
                                                   float* __restrict__ out) {
    __shared__ ushort w2s[NC][200];   // 76.8 KB
    __shared__ float aggs[EW][NC];    // 12.3 KB -> 89.1 KB total, 1 block/CU
    int t = threadIdx.x;
    int wv = t >> 6, l = t & 63;
    int lg = l >> 4, lr = l & 15;

    int pt0 = blockIdx.x * EW + wv;
    int lre = lr < KNN ? lr : KNN - 1;
    int q0 = knn[(size_t)pt0 * KNN + lre];

    for (int i = t; i < NC * 24; i += 1024) {
        int r_ = i / 24, c_ = i % 24;
        *reinterpret_cast<bf16x8*>(&w2s[r_][c_ * 8]) =
            *reinterpret_cast<const bf16x8*>(&w2t[(size_t)r_ * NC + c_ * 8]);
    }
    __syncthreads();

    int b = pt0 / NP;
    const float* u0p = up + (size_t)pt0 * NC + 8 * lg;
    const float* v0p = vv + ((size_t)b * NP + q0) * NC + 8 * lg;

    f32x4 acc[12];
    #pragma unroll
    for (int nt = 0; nt < 12; ++nt) acc[nt] = (f32x4){0.f, 0.f, 0.f, 0.f};

    float4 sUa[2], sUb[2], sVa[2], sVb[2];
#define LDST(ph, ks) do { \
        sUa[ph] = *reinterpret_cast<const float4*>(u0p + (ks) * 32);     \
        sUb[ph] = *reinterpret_cast<const float4*>(u0p + (ks) * 32 + 4); \
        sVa[ph] = *reinterpret_cast<const float4*>(v0p + (ks) * 32);     \
        sVb[ph] = *reinterpret_cast<const float4*>(v0p + (ks) * 32 + 4); \
    } while (0)

    LDST(0, 0);
    #pragma unroll
    for (int ks = 0; ks < 6; ++ks) {
        int ph = ks & 1;
        if (ks < 5) LDST(ph ^ 1, ks + 1);
        bf16x8 a0 = packh(sUa[ph], sUb[ph], sVa[ph], sVb[ph]);
        #pragma unroll
        for (int nt = 0; nt < 12; ++nt) {
            bf16x8 bfr = *reinterpret_cast<const bf16x8*>(&w2s[nt * 16 + lr][ks * 32 + lg * 8]);
            acc[nt] = __builtin_amdgcn_mfma_f32_16x16x32_bf16(a0, bfr, acc[nt], 0, 0, 0);
        }
    }
#undef LDST

    #pragma unroll
    for (int nt = 0; nt < 12; ++nt) {
        float bb = b2[nt * 16 + lr];
        float s = 0.f;
        if (lg < 3) {
            #pragma unroll
            for (int j = 0; j < 4; ++j) s += lrelu(acc[nt][j] + bb);
        }
        s += __shfl_xor(s, 16, 64);
        s += __shfl_xor(s, 32, 64);
        if (lg == 0) aggs[wv][nt * 16 + lr] = s * (1.0f / KNN);
    }
    asm volatile("s_waitcnt lgkmcnt(0)" ::: "memory");

    float a0 = aggs[wv][l], a1 = aggs[wv][l + 64], a2 = aggs[wv][l + 128];
    float s = a0 + a1 + a2;
    #pragma unroll
    for (int off = 32; off; off >>= 1) s += __shfl_xor(s, off, 64);
    float mu = s / (float)NC;
    float d0 = a0 - mu, d1 = a1 - mu, d2 = a2 - mu;
    float vs = d0 * d0 + d1 * d1 + d2 * d2;
    #pragma unroll
    for (int off = 32; off; off >>= 1) vs += __shfl_xor(vs, off, 64);
    float rstd = 1.0f / sqrtf(vs / (float)NC + 1e-5f);
    float* o = out + (size_t)pt0 * NC;
    o[l]       = d0 * rstd * gamma[l]       + beta[l];
    o[l + 64]  = d1 * rstd * gamma[l + 64]  + beta[l + 64];
    o[l + 128] = d2 * rstd * gamma[l + 128] + beta[l + 128];
}

extern "C" void kernel_launch(void* const* d_in, const int* in_sizes, int n_in,
                              void* d_out, int out_size, void* d_ws, size_t ws_size,
                              hipStream_t stream) {
    const float* nodes = (const float*)d_in[0];
    const float* W1    = (const float*)d_in[1];
    const float* b1    = (const float*)d_in[2];
    const float* W2    = (const float*)d_in[3];
    const float* b2    = (const float*)d_in[4];
    const float* gamma = (const float*)d_in[5];
    const float* beta  = (const float*)d_in[6];
    float* out = (float*)d_out;

    const size_t BPC = (size_t)NB * NP * NC;
    float*  xn  = (float*)d_ws;                        // B*P*C f32
    float*  up  = xn + BPC;                            // B*P*C f32
    float*  vv  = up + BPC;                            // B*P*C f32
    ushort* xh  = (ushort*)(vv + BPC);                 // B*P*C bf16 (normalized)
    ushort* xb  = xh + BPC;                            // B*P*C bf16 (raw)
    int*    knn = (int*)(xb + BPC);                    // B*P*K
    ushort* w2t = (ushort*)(knn + (size_t)NB * NP * KNN); // C*C bf16
    ushort* w1t = w2t + (size_t)NC * NC;               // 2C*C bf16
    ushort* simh = (ushort*)(((uintptr_t)(w1t + (size_t)2 * NC * NC) + 15) & ~(uintptr_t)15);

    size_t fixed_bytes = (size_t)((char*)simh - (char*)d_ws);
    bool full = ws_size >= fixed_bytes + (size_t)NB * NP * NP * 2;

    k_normalize<<<NB * NP / 4, 256, 0, stream>>>(nodes, xn, xh, xb);
    k_w1t<<<(2 * NC * NC + 255) / 256, 256, 0, stream>>>(W1, w1t);
    k_w2t<<<(NC * NC + 255) / 256, 256, 0, stream>>>(W2, w2t);
    k_uv2<<<NB * NP / UVM, 256, 0, stream>>>(xb, w1t, b1, up, vv);
    if (full) {
        k_sim4<<<dim3(NP / 128, NP / 128, NB), 256, 0, stream>>>(xh, simh,
                                                                 (size_t)NP * NC, (size_t)NP * NP);
        k_topk6<<<NB * NP / 8, 256, 0, stream>>>(simh, xn, knn,
                                                 (size_t)NP * NP, (size_t)NP * NC);
    } else {
        for (int b = 0; b < NB; ++b) {
            k_sim4<<<dim3(NP / 128, NP / 128, 1), 256, 0, stream>>>(xh + (size_t)b * NP * NC, simh, 0, 0);
            k_topk6<<<NP / 8, 256, 0, stream>>>(simh, xn + (size_t)b * NP * NC,
                                                knn + (size_t)b * NP * KNN, 0, 0);
        }
    }
    k_edge7<<<NB * NP / EW, 1024, 0, stream>>>(up, vv, knn, w2t, b2, gamma, beta, out);
}

// Round 13
// 106.792 us; speedup vs baseline: 1.1385x; 1.0258x over previous
//
#include <hip/hip_runtime.h>
#include <hip/hip_bf16.h>
#include <hip/hip_fp16.h>
#include <math.h>

#define NB 4
#define NP 2048
#define NC 192
#define KNN 12
#define KSEL 16
#define NEG_SLOPE 0.2f

typedef __attribute__((ext_vector_type(8))) short bf16x8;
typedef __attribute__((ext_vector_type(8))) ushort u16x8;
typedef __attribute__((ext_vector_type(4))) float f32x4;

__device__ __forceinline__ float lrelu(float x) { return x >= 0.0f ? x : NEG_SLOPE * x; }

__device__ __forceinline__ ushort f2bf(float x) {
    unsigned u = __float_as_uint(x);
    unsigned r = (u + 0x7FFFu + ((u >> 16) & 1u)) >> 16;   // RNE
    return (ushort)r;
}

// monotone f16->u16 key, packed with complemented index; self -> 0 sentinel
__device__ __forceinline__ unsigned pkkey(unsigned b, int idx, int p) {
    unsigned key = (b & 0x8000u) ? (0xFFFFu & ~b) : (b | 0x8000u);
    unsigned v = (key << 11) | (unsigned)(2047 - idx);
    return (idx == p) ? 0u : v;
}

// -- kernel 1: L2-normalize; out: xn f32 (rescore), xh bf16 (sim), xb bf16 (UV)
__global__ void __launch_bounds__(256) k_normalize(const float* __restrict__ nodes,
                                                   float* __restrict__ xn,
                                                   ushort* __restrict__ xh,
                                                   ushort* __restrict__ xb) {
    int wave = threadIdx.x >> 6;
    int lane = threadIdx.x & 63;
    size_t pt = (size_t)blockIdx.x * 4 + wave;
    const float* x = nodes + pt * NC;
    float v0 = x[lane], v1 = x[lane + 64], v2 = x[lane + 128];
    float s = v0 * v0 + v1 * v1 + v2 * v2;
    #pragma unroll
    for (int off = 32; off; off >>= 1) s += __shfl_xor(s, off, 64);
    float inv = 1.0f / fmaxf(sqrtf(s), 1e-12f);
    float f0 = v0 * inv, f1 = v1 * inv, f2 = v2 * inv;
    float* o = xn + pt * NC;
    o[lane] = f0; o[lane + 64] = f1; o[lane + 128] = f2;
    ushort* oh = xh + pt * NC;
    oh[lane] = f2bf(f0); oh[lane + 64] = f2bf(f1); oh[lane + 128] = f2bf(f2);
    ushort* ob = xb + pt * NC;
    ob[lane] = f2bf(v0); ob[lane + 64] = f2bf(v1); ob[lane + 128] = f2bf(v2);
}

// ------- kernel 2: sim = Xh * Xh^T via bf16 MFMA, f16 out (half the traffic) --
__global__ void __launch_bounds__(256) k_sim4(const ushort* __restrict__ xh,
                                              ushort* __restrict__ simh,
                                              size_t xstride, size_t simstride) {
    __shared__ ushort Ah[128][72];
    __shared__ ushort Bh[128][72];
    const ushort* XbH = xh + (size_t)blockIdx.z * xstride;
    ushort* sb = simh + (size_t)blockIdx.z * simstride;
    int t = threadIdx.x;
    int w = t >> 6, l = t & 63;
    int wm = w >> 1, wn = w & 1;
    int lg = l >> 4, lr = l & 15;
    int m0 = blockIdx.y * 128, n0 = blockIdx.x * 128;

    f32x4 acc[4][4];
    #pragma unroll
    for (int mi = 0; mi < 4; ++mi)
        #pragma unroll
        for (int ni = 0; ni < 4; ++ni)
            acc[mi][ni] = (f32x4){0.f, 0.f, 0.f, 0.f};

    int r = t >> 3, c = (t & 7) * 8;
    for (int ks = 0; ks < 3; ++ks) {
        int kb = ks * 64;
        #pragma unroll
        for (int i = 0; i < 4; ++i) {
            int row = r + 32 * i;
            *reinterpret_cast<bf16x8*>(&Ah[row][c]) =
                *reinterpret_cast<const bf16x8*>(&XbH[(size_t)(m0 + row) * NC + kb + c]);
            *reinterpret_cast<bf16x8*>(&Bh[row][c]) =
                *reinterpret_cast<const bf16x8*>(&XbH[(size_t)(n0 + row) * NC + kb + c]);
        }
        __syncthreads();
        #pragma unroll
        for (int ksub = 0; ksub < 2; ++ksub) {
            int ko = ksub * 32 + 8 * lg;
            bf16x8 af[4], bf[4];
            #pragma unroll
            for (int f = 0; f < 4; ++f) {
                af[f] = *reinterpret_cast<const bf16x8*>(&Ah[wm * 64 + f * 16 + lr][ko]);
                bf[f] = *reinterpret_cast<const bf16x8*>(&Bh[wn * 64 + f * 16 + lr][ko]);
            }
            #pragma unroll
            for (int mi = 0; mi < 4; ++mi)
                #pragma unroll
                for (int ni = 0; ni < 4; ++ni)
                    acc[mi][ni] = __builtin_amdgcn_mfma_f32_16x16x32_bf16(af[mi], bf[ni], acc[mi][ni], 0, 0, 0);
        }
        __syncthreads();
    }
    #pragma unroll
    for (int mi = 0; mi < 4; ++mi)
        #pragma unroll
        for (int j = 0; j < 4; ++j) {
            int row = m0 + wm * 64 + mi * 16 + lg * 4 + j;
            ushort* hrow = sb + (size_t)row * NP;
            #pragma unroll
            for (int ni = 0; ni < 4; ++ni) {
                __half h = __float2half(acc[mi][ni][j]);
                hrow[n0 + wn * 64 + ni * 16 + lr] = *reinterpret_cast<const ushort*>(&h);
            }
        }
}

// rare fallback for one row: u32 insert list depth 16 + 16 extraction rounds.
// MUST be forceinline: a noinline pointer arg forces h8 to scratch (R12: 33 MB
// WRITE_SIZE of pure spill traffic).
__device__ __forceinline__ int topk_fb(const u16x8 h8[4], int p, int lane) {
    unsigned tv[16];
    #pragma unroll
    for (int q = 0; q < 16; ++q) tv[q] = 0u;
    #pragma unroll
    for (int i = 0; i < 4; ++i)
        #pragma unroll
        for (int j = 0; j < 8; ++j) {
            unsigned v = pkkey((unsigned)(ushort)h8[i][j], lane * 8 + i * 512 + j, p);
            if (v > tv[0]) {
                bool cg[16];
                #pragma unroll
                for (int q = 0; q < 16; ++q) cg[q] = v > tv[q];
                #pragma unroll
                for (int q = 0; q < 15; ++q)
                    tv[q] = cg[q + 1] ? tv[q + 1] : (cg[q] ? v : tv[q]);
                tv[15] = cg[15] ? v : tv[15];
            }
        }
    unsigned mp = 0u;
    #pragma unroll
    for (int rr = 0; rr < 16; ++rr) {
        unsigned bv = tv[15];
        #pragma unroll
        for (int off = 1; off < 64; off <<= 1) {
            unsigned ov = __shfl_xor(bv, off, 64);
            bv = ov > bv ? ov : bv;
        }
        if ((lane >> 2) == rr) mp = bv;
        if (bv == tv[15]) {
            #pragma unroll
            for (int s = 15; s > 0; --s) tv[s] = tv[s - 1];
            tv[0] = 0u;
        }
    }
    return (mp == 0u) ? -1 : (int)(2047u - (mp & 0x7FFu));
}

// -- kernel 3: 2 rows/wave, packed-u32 top-16 select + exact f32 rescore -------
__global__ void __launch_bounds__(256) k_topk6(const ushort* __restrict__ simh,
                                               const float* __restrict__ xn,
                                               int* __restrict__ knn,
                                               size_t simstride, size_t xstride) {
    __shared__ unsigned cand[4][2][64];
    int wv = threadIdx.x >> 6, lane = threadIdx.x & 63;
    int row0 = blockIdx.x * 8 + wv * 2;     // even -> both rows share a batch
    int row1 = row0 + 1;
    int b = row0 / NP;
    int p0 = row0 % NP, p1 = p0 + 1;
    const ushort* sr0 = simh + (size_t)b * simstride + (size_t)p0 * NP;
    const ushort* sr1 = sr0 + NP;

    u16x8 h80[4], h81[4];
    #pragma unroll
    for (int i = 0; i < 4; ++i) {
        h80[i] = *reinterpret_cast<const u16x8*>(sr0 + lane * 8 + i * 512);
        h81[i] = *reinterpret_cast<const u16x8*>(sr1 + lane * 8 + i * 512);
    }

    // per-lane max (recompute transform; VALU-cheap, register-cheap)
    unsigned lmax0 = 0, lmax1 = 0;
    #pragma unroll
    for (int i = 0; i < 4; ++i)
        #pragma unroll
        for (int j = 0; j < 8; ++j) {
            int idx = lane * 8 + i * 512 + j;
            unsigned v0 = pkkey((unsigned)(ushort)h80[i][j], idx, p0);
            unsigned v1 = pkkey((unsigned)(ushort)h81[i][j], idx, p1);
            lmax0 = v0 > lmax0 ? v0 : lmax0;
            lmax1 = v1 > lmax1 ? v1 : lmax1;
        }

    // interleaved descending bitonic of the 64 lane-maxes (2 rows, ILP)
    unsigned sm0 = lmax0, sm1 = lmax1;
    #pragma unroll
    for (int k = 2; k <= 64; k <<= 1) {
        #pragma unroll
        for (int j = k >> 1; j >= 1; j >>= 1) {
            unsigned ov0 = __shfl_xor(sm0, j, 64);
            unsigned ov1 = __shfl_xor(sm1, j, 64);
            bool keep_lo = (((lane & k) != 0) == ((lane & j) == 0));
            unsigned lo0 = sm0 < ov0 ? sm0 : ov0, hi0 = sm0 < ov0 ? ov0 : sm0;
            unsigned lo1 = sm1 < ov1 ? sm1 : ov1, hi1 = sm1 < ov1 ? ov1 : sm1;
            sm0 = keep_lo ? lo0 : hi0;
            sm1 = keep_lo ? lo1 : hi1;
        }
    }
    unsigned theta0 = __shfl(sm0, KSEL, 64);   // 17th-largest lane-max
    unsigned theta1 = __shfl(sm1, KSEL, 64);

    // count + exclusive scan (interleaved)
    int cnt0 = 0, cnt1 = 0;
    #pragma unroll
    for (int i = 0; i < 4; ++i)
        #pragma unroll
        for (int j = 0; j < 8; ++j) {
            int idx = lane * 8 + i * 512 + j;
            cnt0 += (pkkey((unsigned)(ushort)h80[i][j], idx, p0) > theta0) ? 1 : 0;
            cnt1 += (pkkey((unsigned)(ushort)h81[i][j], idx, p1) > theta1) ? 1 : 0;
        }
    int x0 = cnt0, x1 = cnt1;
    #pragma unroll
    for (int off = 1; off < 64; off <<= 1) {
        int y0 = __shfl_up(x0, off, 64);
        int y1 = __shfl_up(x1, off, 64);
        if (lane >= off) { x0 += y0; x1 += y1; }
    }
    int excl0 = x0 - cnt0, excl1 = x1 - cnt1;
    int total0 = __shfl(x0, 63, 64), total1 = __shfl(x1, 63, 64);
    bool fb0 = total0 > 64, fb1 = total1 > 64;   // count >= 16 guaranteed

    // compact candidates into LDS (per row, only if it fits)
    cand[wv][0][lane] = 0u;
    cand[wv][1][lane] = 0u;
    asm volatile("s_waitcnt lgkmcnt(0)" ::: "memory");
    if (!fb0) {
        int pos = excl0;
        #pragma unroll
        for (int i = 0; i < 4; ++i)
            #pragma unroll
            for (int j = 0; j < 8; ++j) {
                int idx = lane * 8 + i * 512 + j;
                unsigned v = pkkey((unsigned)(ushort)h80[i][j], idx, p0);
                if (v > theta0) { cand[wv][0][pos] = v; ++pos; }
            }
    }
    if (!fb1) {
        int pos = excl1;
        #pragma unroll
        for (int i = 0; i < 4; ++i)
            #pragma unroll
            for (int j = 0; j < 8; ++j) {
                int idx = lane * 8 + i * 512 + j;
                unsigned v = pkkey((unsigned)(ushort)h81[i][j], idx, p1);
                if (v > theta1) { cand[wv][1][pos] = v; ++pos; }
            }
    }
    asm volatile("s_waitcnt lgkmcnt(0)" ::: "memory");

    // interleaved descending bitonic of the (<=64) candidates
    unsigned v0 = cand[wv][0][lane];
    unsigned v1 = cand[wv][1][lane];
    #pragma unroll
    for (int k = 2; k <= 64; k <<= 1) {
        #pragma unroll
        for (int j = k >> 1; j >= 1; j >>= 1) {
            unsigned ov0 = __shfl_xor(v0, j, 64);
            unsigned ov1 = __shfl_xor(v1, j, 64);
            bool keep_lo = (((lane & k) != 0) == ((lane & j) == 0));
            unsigned lo0 = v0 < ov0 ? v0 : ov0, hi0 = v0 < ov0 ? ov0 : v0;
            unsigned lo1 = v1 < ov1 ? v1 : ov1, hi1 = v1 < ov1 ? ov1 : v1;
            v0 = keep_lo ? lo0 : hi0;
            v1 = keep_lo ? lo1 : hi1;
        }
    }
    int g = lane >> 2;                        // 16 groups x 4 lanes
    unsigned mp0 = __shfl(v0, g, 64);
    unsigned mp1 = __shfl(v1, g, 64);
    int my_q0 = (mp0 == 0u) ? -1 : (int)(2047u - (mp0 & 0x7FFu));
    int my_q1 = (mp1 == 0u) ? -1 : (int)(2047u - (mp1 & 0x7FFu));
    if (fb0) my_q0 = topk_fb(h80, p0, lane);
    if (fb1) my_q1 = topk_fb(h81, p1, lane);

    // exact f32 rescore (4-lane slices of 48), both rows interleaved
    const float* xb = xn + (size_t)b * xstride;
    int qa0 = my_q0 < 0 ? 0 : my_q0;
    int qa1 = my_q1 < 0 ? 0 : my_q1;
    const float* cp0 = xb + (size_t)p0 * NC + (lane & 3) * 48;
    const float* cq0 = xb + (size_t)qa0 * NC + (lane & 3) * 48;
    const float* cp1 = xb + (size_t)p1 * NC + (lane & 3) * 48;
    const float* cq1 = xb + (size_t)qa1 * NC + (lane & 3) * 48;
    float dot0 = 0.f, dot1 = 0.f;
    #pragma unroll
    for (int i = 0; i < 12; ++i) {
        float4 a0 = *reinterpret_cast<const float4*>(cp0 + i * 4);
        float4 b0 = *reinterpret_cast<const float4*>(cq0 + i * 4);
        float4 a1 = *reinterpret_cast<const float4*>(cp1 + i * 4);
        float4 b1 = *reinterpret_cast<const float4*>(cq1 + i * 4);
        dot0 += a0.x * b0.x + a0.y * b0.y + a0.z * b0.z + a0.w * b0.w;
        dot1 += a1.x * b1.x + a1.y * b1.y + a1.z * b1.z + a1.w * b1.w;
    }
    dot0 += __shfl_xor(dot0, 1, 64); dot0 += __shfl_xor(dot0, 2, 64);
    dot1 += __shfl_xor(dot1, 1, 64); dot1 += __shfl_xor(dot1, 2, 64);

    int rank0 = 0, rank1 = 0;
    #pragma unroll
    for (int j = 0; j < KSEL; ++j) {
        float vj0 = __shfl(dot0, j * 4, 64);
        int   qj0 = __shfl(my_q0, j * 4, 64);
        float vj1 = __shfl(dot1, j * 4, 64);
        int   qj1 = __shfl(my_q1, j * 4, 64);
        if (j != g && qj0 >= 0 && (vj0 > dot0 || (vj0 == dot0 && qj0 < my_q0))) ++rank0;
        if (j != g && qj1 >= 0 && (vj1 > dot1 || (vj1 == dot1 && qj1 < my_q1))) ++rank1;
    }
    bool keep0 = ((lane & 3) == 0) && (my_q0 >= 0) && (rank0 < KNN);
    unsigned long long m0 = __ballot(keep0);
    int ps0 = __popcll(m0 & ((1ull << lane) - 1));
    if (keep0) knn[(size_t)row0 * KNN + ps0] = my_q0;
    bool keep1 = ((lane & 3) == 0) && (my_q1 >= 0) && (rank1 < KNN);
    unsigned long long m1 = __ballot(keep1);
    int ps1 = __popcll(m1 & ((1ull << lane) - 1));
    if (keep1) knn[(size_t)row1 * KNN + ps1] = my_q1;
}

// ---- prep: w1t[384][192] bf16 = [(W1a - W1b)^T ; W1b^T] ----------------------
__global__ void __launch_bounds__(256) k_w1t(const float* __restrict__ W1,
                                             ushort* __restrict__ w1t) {
    int idx = blockIdx.x * 256 + threadIdx.x;
    if (idx >= 2 * NC * NC) return;
    int n = idx / NC, k = idx % NC;
    float v;
    if (n < NC) v = W1[(size_t)k * NC + n] - W1[(size_t)(k + NC) * NC + n];
    else        v = W1[(size_t)(k + NC) * NC + (n - NC)];
    w1t[idx] = f2bf(v);
}

// ---- prep: W2T bf16 [n][k] from W2 f32 [k][n] --------------------------------
__global__ void __launch_bounds__(256) k_w2t(const float* __restrict__ W2,
                                             ushort* __restrict__ w2t) {
    int idx = blockIdx.x * 256 + threadIdx.x;
    if (idx >= NC * NC) return;
    int n = idx / NC, k = idx % NC;
    w2t[(size_t)n * NC + k] = f2bf(W2[(size_t)k * NC + n]);
}

// ---- kernel 4: [U'|V] = Xb @ w1t^T via MFMA; bias fused into U' --------------
#define UVM 32
__global__ void __launch_bounds__(256) k_uv2(const ushort* __restrict__ xb,
                                             const ushort* __restrict__ w1t,
                                             const float* __restrict__ b1,
                                             float* __restrict__ up,
                                             float* __restrict__ vv) {
    __shared__ ushort xs[UVM][200];
    int t = threadIdx.x;
    int w = t >> 6, l = t & 63;
    int lg = l >> 4, lr = l & 15;
    int p0 = blockIdx.x * UVM;
    for (int i = t; i < UVM * 24; i += 256) {
        int row = i / 24, c = (i % 24) * 8;
        *reinterpret_cast<bf16x8*>(&xs[row][c]) =
            *reinterpret_cast<const bf16x8*>(&xb[(size_t)(p0 + row) * NC + c]);
    }
    __syncthreads();
    int n0 = w * 96;
    f32x4 acc[2][6];
    #pragma unroll
    for (int mt = 0; mt < 2; ++mt)
        #pragma unroll
        for (int nt = 0; nt < 6; ++nt)
            acc[mt][nt] = (f32x4){0.f, 0.f, 0.f, 0.f};
    #pragma unroll
    for (int ks = 0; ks < 6; ++ks) {
        bf16x8 bfr[6];
        #pragma unroll
        for (int nt = 0; nt < 6; ++nt)
            bfr[nt] = *reinterpret_cast<const bf16x8*>(
                &w1t[(size_t)(n0 + nt * 16 + lr) * NC + ks * 32 + lg * 8]);
        bf16x8 a0 = *reinterpret_cast<const bf16x8*>(&xs[lr][ks * 32 + lg * 8]);
        bf16x8 a1 = *reinterpret_cast<const bf16x8*>(&xs[16 + lr][ks * 32 + lg * 8]);
        #pragma unroll
        for (int nt = 0; nt < 6; ++nt) {
            acc[0][nt] = __builtin_amdgcn_mfma_f32_16x16x32_bf16(a0, bfr[nt], acc[0][nt], 0, 0, 0);
            acc[1][nt] = __builtin_amdgcn_mfma_f32_16x16x32_bf16(a1, bfr[nt], acc[1][nt], 0, 0, 0);
        }
    }
    bool isU = (n0 < NC);
    #pragma unroll
    for (int nt = 0; nt < 6; ++nt) {
        int col = n0 + nt * 16 + lr;
        float bb = isU ? b1[col] : 0.f;
        int ocol = isU ? col : col - NC;
        float* dst = isU ? up : vv;
        #pragma unroll
        for (int mt = 0; mt < 2; ++mt)
            #pragma unroll
            for (int j = 0; j < 4; ++j) {
                int pt = p0 + mt * 16 + lg * 4 + j;
                dst[(size_t)pt * NC + ocol] = acc[mt][nt][j] + bb;
            }
    }
}

// ---- kernel 5: edge MLP; EPW=1 (48 AGPR acc), 16 waves/block, 4 waves/SIMD ---
__device__ __forceinline__ bf16x8 packh(float4 ua, float4 ub, float4 va, float4 vb) {
    union { bf16x8 v8; __hip_bfloat162 h2[4]; } r;
    r.h2[0] = __float22bfloat162_rn(make_float2(lrelu(ua.x + va.x), lrelu(ua.y + va.y)));
    r.h2[1] = __float22bfloat162_rn(make_float2(lrelu(ua.z + va.z), lrelu(ua.w + va.w)));
    r.h2[2] = __float22bfloat162_rn(make_float2(lrelu(ub.x + vb.x), lrelu(ub.y + vb.y)));
    r.h2[3] = __float22bfloat162_rn(make_float2(lrelu(ub.z + vb.z), lrelu(ub.w + vb.w)));
    return r.v8;
}

#define EW 16   // waves/block, 1 point each
__global__ void __launch_bounds__(1024, 4) k_edge7(const float* __restrict__ up,
                                                   const float* __restrict__ vv,
                                                   const int* __restrict__ knn,
                                                   const ushort* __restrict__ w2t,
                                                   const float* __restrict__ b2,
                                                   const float* __restrict__ gamma,
                                                   const float* __restrict__ beta,
                                                   float* __restrict__ out) {
    __shared__ ushort w2s[NC][200];   // 76.8 KB
    __shared__ float aggs[EW][NC];    // 12.3 KB -> 89.1 KB total, 1 block/CU
    int t = threadIdx.x;
    int wv = t >> 6, l = t & 63;
    int lg = l >> 4, lr = l & 15;

    int pt0 = blockIdx.x * EW + wv;
    int lre = lr < KNN ? lr : KNN - 1;
    int q0 = knn[(size_t)pt0 * KNN + lre];

    for (int i = t; i < NC * 24; i += 1024) {
        int r_ = i / 24, c_ = i % 24;
        *reinterpret_cast<bf16x8*>(&w2s[r_][c_ * 8]) =
            *reinterpret_cast<const bf16x8*>(&w2t[(size_t)r_ * NC + c_ * 8]);
    }
    __syncthreads();

    int b = pt0 / NP;
    const float* u0p = up + (size_t)pt0 * NC + 8 * lg;
    const float* v0p = vv + ((size_t)b * NP + q0) * NC + 8 * lg;

    f32x4 acc[12];
    #pragma unroll
    for (int nt = 0; nt < 12; ++nt) acc[nt] = (f32x4){0.f, 0.f, 0.f, 0.f};

    float4 sUa[2], sUb[2], sVa[2], sVb[2];
#define LDST(ph, ks) do { \
        sUa[ph] = *reinterpret_cast<const float4*>(u0p + (ks) * 32);     \
        sUb[ph] = *reinterpret_cast<const float4*>(u0p + (ks) * 32 + 4); \
        sVa[ph] = *reinterpret_cast<const float4*>(v0p + (ks) * 32);     \
        sVb[ph] = *reinterpret_cast<const float4*>(v0p + (ks) * 32 + 4); \
    } while (0)

    LDST(0, 0);
    #pragma unroll
    for (int ks = 0; ks < 6; ++ks) {
        int ph = ks & 1;
        if (ks < 5) LDST(ph ^ 1, ks + 1);
        bf16x8 a0 = packh(sUa[ph], sUb[ph], sVa[ph], sVb[ph]);
        #pragma unroll
        for (int nt = 0; nt < 12; ++nt) {
            bf16x8 bfr = *reinterpret_cast<const bf16x8*>(&w2s[nt * 16 + lr][ks * 32 + lg * 8]);
            acc[nt] = __builtin_amdgcn_mfma_f32_16x16x32_bf16(a0, bfr, acc[nt], 0, 0, 0);
        }
    }
#undef LDST

    #pragma unroll
    for (int nt = 0; nt < 12; ++nt) {
        float bb = b2[nt * 16 + lr];
        float s = 0.f;
        if (lg < 3) {
            #pragma unroll
            for (int j = 0; j < 4; ++j) s += lrelu(acc[nt][j] + bb);
        }
        s += __shfl_xor(s, 16, 64);
        s += __shfl_xor(s, 32, 64);
        if (lg == 0) aggs[wv][nt * 16 + lr] = s * (1.0f / KNN);
    }
    asm volatile("s_waitcnt lgkmcnt(0)" ::: "memory");

    float a0 = aggs[wv][l], a1 = aggs[wv][l + 64], a2 = aggs[wv][l + 128];
    float s = a0 + a1 + a2;
    #pragma unroll
    for (int off = 32; off; off >>= 1) s += __shfl_xor(s, off, 64);
    float mu = s / (float)NC;
    float d0 = a0 - mu, d1 = a1 - mu, d2 = a2 - mu;
    float vs = d0 * d0 + d1 * d1 + d2 * d2;
    #pragma unroll
    for (int off = 32; off; off >>= 1) vs += __shfl_xor(vs, off, 64);
    float rstd = 1.0f / sqrtf(vs / (float)NC + 1e-5f);
    float* o = out + (size_t)pt0 * NC;
    o[l]       = d0 * rstd * gamma[l]       + beta[l];
    o[l + 64]  = d1 * rstd * gamma[l + 64]  + beta[l + 64];
    o[l + 128] = d2 * rstd * gamma[l + 128] + beta[l + 128];
}

extern "C" void kernel_launch(void* const* d_in, const int* in_sizes, int n_in,
                              void* d_out, int out_size, void* d_ws, size_t ws_size,
                              hipStream_t stream) {
    const float* nodes = (const float*)d_in[0];
    const float* W1    = (const float*)d_in[1];
    const float* b1    = (const float*)d_in[2];
    const float* W2    = (const float*)d_in[3];
    const float* b2    = (const float*)d_in[4];
    const float* gamma = (const float*)d_in[5];
    const float* beta  = (const float*)d_in[6];
    float* out = (float*)d_out;

    const size_t BPC = (size_t)NB * NP * NC;
    float*  xn  = (float*)d_ws;                        // B*P*C f32
    float*  up  = xn + BPC;                            // B*P*C f32
    float*  vv  = up + BPC;                            // B*P*C f32
    ushort* xh  = (ushort*)(vv + BPC);                 // B*P*C bf16 (normalized)
    ushort* xb  = xh + BPC;                            // B*P*C bf16 (raw)
    int*    knn = (int*)(xb + BPC);                    // B*P*K
    ushort* w2t = (ushort*)(knn + (size_t)NB * NP * KNN); // C*C bf16
    ushort* w1t = w2t + (size_t)NC * NC;               // 2C*C bf16
    ushort* simh = (ushort*)(((uintptr_t)(w1t + (size_t)2 * NC * NC) + 15) & ~(uintptr_t)15);

    size_t fixed_bytes = (size_t)((char*)simh - (char*)d_ws);
    bool full = ws_size >= fixed_bytes + (size_t)NB * NP * NP * 2;

    k_normalize<<<NB * NP / 4, 256, 0, stream>>>(nodes, xn, xh, xb);
    k_w1t<<<(2 * NC * NC + 255) / 256, 256, 0, stream>>>(W1, w1t);
    k_w2t<<<(NC * NC + 255) / 256, 256, 0, stream>>>(W2, w2t);
    k_uv2<<<NB * NP / UVM, 256, 0, stream>>>(xb, w1t, b1, up, vv);
    if (full) {
        k_sim4<<<dim3(NP / 128, NP / 128, NB), 256, 0, stream>>>(xh, simh,
                                                                 (size_t)NP * NC, (size_t)NP * NP);
        k_topk6<<<NB * NP / 8, 256, 0, stream>>>(simh, xn, knn,
                                                 (size_t)NP * NP, (size_t)NP * NC);
    } else {
        for (int b = 0; b < NB; ++b) {
            k_sim4<<<dim3(NP / 128, NP / 128, 1), 256, 0, stream>>>(xh + (size_t)b * NP * NC, simh, 0, 0);
            k_topk6<<<NP / 8, 256, 0, stream>>>(simh, xn + (size_t)b * NP * NC,
                                                knn + (size_t)b * NP * KNN, 0, 0);
        }
    }
    k_edge7<<<NB * NP / EW, 1024, 0, stream>>>(up, vv, knn, w2t, b2, gamma, beta, out);
}

// Round 14
// 99.646 us; speedup vs baseline: 1.2202x; 1.0717x over previous
//
#include <hip/hip_runtime.h>
#include <hip/hip_bf16.h>
#include <hip/hip_fp16.h>
#include <math.h>

#define NB 4
#define NP 2048
#define NC 192
#define KNN 12
#define KSEL 16
#define NEG_SLOPE 0.2f

typedef __attribute__((ext_vector_type(8))) short bf16x8;
typedef __attribute__((ext_vector_type(8))) ushort u16x8;
typedef __attribute__((ext_vector_type(4))) float f32x4;

__device__ __forceinline__ float lrelu(float x) { return x >= 0.0f ? x : NEG_SLOPE * x; }

__device__ __forceinline__ ushort f2bf(float x) {
    unsigned u = __float_as_uint(x);
    unsigned r = (u + 0x7FFFu + ((u >> 16) & 1u)) >> 16;   // RNE
    return (ushort)r;
}

// monotone f16->u16 key, packed with complemented index; self -> 0 sentinel
__device__ __forceinline__ unsigned pkkey(unsigned b, int idx, int p) {
    unsigned key = (b & 0x8000u) ? (0xFFFFu & ~b) : (b | 0x8000u);
    unsigned v = (key << 11) | (unsigned)(2047 - idx);
    return (idx == p) ? 0u : v;
}

// -- kernel 1: L2-normalize; out: xn f32 (rescore), xh bf16 (sim), xb bf16 (UV)
__global__ void __launch_bounds__(256) k_normalize(const float* __restrict__ nodes,
                                                   float* __restrict__ xn,
                                                   ushort* __restrict__ xh,
                                                   ushort* __restrict__ xb) {
    int wave = threadIdx.x >> 6;
    int lane = threadIdx.x & 63;
    size_t pt = (size_t)blockIdx.x * 4 + wave;
    const float* x = nodes + pt * NC;
    float v0 = x[lane], v1 = x[lane + 64], v2 = x[lane + 128];
    float s = v0 * v0 + v1 * v1 + v2 * v2;
    #pragma unroll
    for (int off = 32; off; off >>= 1) s += __shfl_xor(s, off, 64);
    float inv = 1.0f / fmaxf(sqrtf(s), 1e-12f);
    float f0 = v0 * inv, f1 = v1 * inv, f2 = v2 * inv;
    float* o = xn + pt * NC;
    o[lane] = f0; o[lane + 64] = f1; o[lane + 128] = f2;
    ushort* oh = xh + pt * NC;
    oh[lane] = f2bf(f0); oh[lane + 64] = f2bf(f1); oh[lane + 128] = f2bf(f2);
    ushort* ob = xb + pt * NC;
    ob[lane] = f2bf(v0); ob[lane + 64] = f2bf(v1); ob[lane + 128] = f2bf(v2);
}

// ------- kernel 2: sim = Xh * Xh^T via bf16 MFMA, f16 out (half the traffic) --
__global__ void __launch_bounds__(256) k_sim4(const ushort* __restrict__ xh,
                                              ushort* __restrict__ simh,
                                              size_t xstride, size_t simstride) {
    __shared__ ushort Ah[128][72];
    __shared__ ushort Bh[128][72];
    const ushort* XbH = xh + (size_t)blockIdx.z * xstride;
    ushort* sb = simh + (size_t)blockIdx.z * simstride;
    int t = threadIdx.x;
    int w = t >> 6, l = t & 63;
    int wm = w >> 1, wn = w & 1;
    int lg = l >> 4, lr = l & 15;
    int m0 = blockIdx.y * 128, n0 = blockIdx.x * 128;

    f32x4 acc[4][4];
    #pragma unroll
    for (int mi = 0; mi < 4; ++mi)
        #pragma unroll
        for (int ni = 0; ni < 4; ++ni)
            acc[mi][ni] = (f32x4){0.f, 0.f, 0.f, 0.f};

    int r = t >> 3, c = (t & 7) * 8;
    for (int ks = 0; ks < 3; ++ks) {
        int kb = ks * 64;
        #pragma unroll
        for (int i = 0; i < 4; ++i) {
            int row = r + 32 * i;
            *reinterpret_cast<bf16x8*>(&Ah[row][c]) =
                *reinterpret_cast<const bf16x8*>(&XbH[(size_t)(m0 + row) * NC + kb + c]);
            *reinterpret_cast<bf16x8*>(&Bh[row][c]) =
                *reinterpret_cast<const bf16x8*>(&XbH[(size_t)(n0 + row) * NC + kb + c]);
        }
        __syncthreads();
        #pragma unroll
        for (int ksub = 0; ksub < 2; ++ksub) {
            int ko = ksub * 32 + 8 * lg;
            bf16x8 af[4], bf[4];
            #pragma unroll
            for (int f = 0; f < 4; ++f) {
                af[f] = *reinterpret_cast<const bf16x8*>(&Ah[wm * 64 + f * 16 + lr][ko]);
                bf[f] = *reinterpret_cast<const bf16x8*>(&Bh[wn * 64 + f * 16 + lr][ko]);
            }
            #pragma unroll
            for (int mi = 0; mi < 4; ++mi)
                #pragma unroll
                for (int ni = 0; ni < 4; ++ni)
                    acc[mi][ni] = __builtin_amdgcn_mfma_f32_16x16x32_bf16(af[mi], bf[ni], acc[mi][ni], 0, 0, 0);
        }
        __syncthreads();
    }
    #pragma unroll
    for (int mi = 0; mi < 4; ++mi)
        #pragma unroll
        for (int j = 0; j < 4; ++j) {
            int row = m0 + wm * 64 + mi * 16 + lg * 4 + j;
            ushort* hrow = sb + (size_t)row * NP;
            #pragma unroll
            for (int ni = 0; ni < 4; ++ni) {
                __half h = __float2half(acc[mi][ni][j]);
                hrow[n0 + wn * 64 + ni * 16 + lr] = *reinterpret_cast<const ushort*>(&h);
            }
        }
}

// rare fallback: u32 insert list depth 16 + 16 extraction rounds (forceinline:
// pointer-escape would spill h8 to scratch — R12 lesson, 33 MB WRITE_SIZE).
__device__ __forceinline__ int topk_fb(const u16x8 h8[4], int p, int lane) {
    unsigned tv[16];
    #pragma unroll
    for (int q = 0; q < 16; ++q) tv[q] = 0u;
    #pragma unroll
    for (int i = 0; i < 4; ++i)
        #pragma unroll
        for (int j = 0; j < 8; ++j) {
            unsigned v = pkkey((unsigned)(ushort)h8[i][j], lane * 8 + i * 512 + j, p);
            if (v > tv[0]) {
                bool cg[16];
                #pragma unroll
                for (int q = 0; q < 16; ++q) cg[q] = v > tv[q];
                #pragma unroll
                for (int q = 0; q < 15; ++q)
                    tv[q] = cg[q + 1] ? tv[q + 1] : (cg[q] ? v : tv[q]);
                tv[15] = cg[15] ? v : tv[15];
            }
        }
    unsigned mp = 0u;
    #pragma unroll
    for (int rr = 0; rr < 16; ++rr) {
        unsigned bv = tv[15];
        #pragma unroll
        for (int off = 1; off < 64; off <<= 1) {
            unsigned ov = __shfl_xor(bv, off, 64);
            bv = ov > bv ? ov : bv;
        }
        if ((lane >> 2) == rr) mp = bv;
        if (bv == tv[15]) {
            #pragma unroll
            for (int s = 15; s > 0; --s) tv[s] = tv[s - 1];
            tv[0] = 0u;
        }
    }
    return (mp == 0u) ? -1 : (int)(2047u - (mp & 0x7FFu));
}

// -- kernel 3: 1 row/wave, low-VGPR packed-u32 top-16 + exact f32 rescore ------
__global__ void __launch_bounds__(256) k_topk7(const ushort* __restrict__ simh,
                                               const float* __restrict__ xn,
                                               int* __restrict__ knn,
                                               size_t simstride, size_t xstride) {
    __shared__ unsigned cand[4][64];
    int wv = threadIdx.x >> 6, lane = threadIdx.x & 63;
    int row = blockIdx.x * 4 + wv;
    int b = row / NP, p = row % NP;
    const ushort* sr = simh + (size_t)b * simstride + (size_t)p * NP;

    u16x8 h8[4];
    #pragma unroll
    for (int i = 0; i < 4; ++i)
        h8[i] = *reinterpret_cast<const u16x8*>(sr + lane * 8 + i * 512);

    // pass A: per-lane max key
    unsigned lmax = 0;
    #pragma unroll
    for (int i = 0; i < 4; ++i)
        #pragma unroll
        for (int j = 0; j < 8; ++j) {
            unsigned v = pkkey((unsigned)(ushort)h8[i][j], lane * 8 + i * 512 + j, p);
            lmax = v > lmax ? v : lmax;
        }

    // descending bitonic of 64 lane-maxes -> theta = 17th largest
    unsigned sm = lmax;
    #pragma unroll
    for (int k = 2; k <= 64; k <<= 1) {
        #pragma unroll
        for (int j = k >> 1; j >= 1; j >>= 1) {
            unsigned ov = __shfl_xor(sm, j, 64);
            bool keep_lo = (((lane & k) != 0) == ((lane & j) == 0));
            unsigned lo = sm < ov ? sm : ov, hi = sm < ov ? ov : sm;
            sm = keep_lo ? lo : hi;
        }
    }
    unsigned theta = __shfl(sm, KSEL, 64);

    // pass B: count + exclusive scan
    int cnt = 0;
    #pragma unroll
    for (int i = 0; i < 4; ++i)
        #pragma unroll
        for (int j = 0; j < 8; ++j)
            cnt += (pkkey((unsigned)(ushort)h8[i][j], lane * 8 + i * 512 + j, p) > theta) ? 1 : 0;
    int x = cnt;
    #pragma unroll
    for (int off = 1; off < 64; off <<= 1) {
        int y = __shfl_up(x, off, 64);
        if (lane >= off) x += y;
    }
    int excl = x - cnt;
    int total = __shfl(x, 63, 64);

    int my_q;
    if (total <= 64) {   // count >= 16 structurally guaranteed
        // pass C: compact candidates into LDS, then one descending bitonic
        cand[wv][lane] = 0u;
        asm volatile("s_waitcnt lgkmcnt(0)" ::: "memory");
        int pos = excl;
        #pragma unroll
        for (int i = 0; i < 4; ++i)
            #pragma unroll
            for (int j = 0; j < 8; ++j) {
                unsigned v = pkkey((unsigned)(ushort)h8[i][j], lane * 8 + i * 512 + j, p);
                if (v > theta) { cand[wv][pos] = v; ++pos; }
            }
        asm volatile("s_waitcnt lgkmcnt(0)" ::: "memory");
        unsigned v = cand[wv][lane];
        #pragma unroll
        for (int k = 2; k <= 64; k <<= 1) {
            #pragma unroll
            for (int j = k >> 1; j >= 1; j >>= 1) {
                unsigned ov = __shfl_xor(v, j, 64);
                bool keep_lo = (((lane & k) != 0) == ((lane & j) == 0));
                unsigned lo = v < ov ? v : ov, hi = v < ov ? ov : v;
                v = keep_lo ? lo : hi;
            }
        }
        unsigned mp = __shfl(v, lane >> 2, 64);   // group g -> g-th largest
        my_q = (mp == 0u) ? -1 : (int)(2047u - (mp & 0x7FFu));
    } else {
        my_q = topk_fb(h8, p, lane);              // rare
    }

    // exact f32 rescore: group g = lane>>2 owns candidate my_q; slice lane&3
    const float* xb = xn + (size_t)b * xstride;
    int qa = my_q < 0 ? 0 : my_q;
    const float* cp = xb + (size_t)p * NC + (lane & 3) * 48;
    const float* cq = xb + (size_t)qa * NC + (lane & 3) * 48;
    float dot = 0.f;
    #pragma unroll
    for (int i = 0; i < 12; ++i) {
        float4 a = *reinterpret_cast<const float4*>(cp + i * 4);
        float4 bq = *reinterpret_cast<const float4*>(cq + i * 4);
        dot += a.x * bq.x + a.y * bq.y + a.z * bq.z + a.w * bq.w;
    }
    dot += __shfl_xor(dot, 1, 64);
    dot += __shfl_xor(dot, 2, 64);
    int g = lane >> 2;
    int rank = 0;
    #pragma unroll
    for (int j = 0; j < KSEL; ++j) {
        float vj = __shfl(dot, j * 4, 64);
        int   qj = __shfl(my_q, j * 4, 64);
        if (j != g && qj >= 0 && (vj > dot || (vj == dot && qj < my_q))) ++rank;
    }
    bool keep = ((lane & 3) == 0) && (my_q >= 0) && (rank < KNN);
    unsigned long long mask = __ballot(keep);
    int pos = __popcll(mask & ((1ull << lane) - 1));
    if (keep) knn[(size_t)row * KNN + pos] = my_q;
}

// ---- prep: w1t[384][192] bf16 = [(W1a - W1b)^T ; W1b^T] ----------------------
__global__ void __launch_bounds__(256) k_w1t(const float* __restrict__ W1,
                                             ushort* __restrict__ w1t) {
    int idx = blockIdx.x * 256 + threadIdx.x;
    if (idx >= 2 * NC * NC) return;
    int n = idx / NC, k = idx % NC;
    float v;
    if (n < NC) v = W1[(size_t)k * NC + n] - W1[(size_t)(k + NC) * NC + n];
    else        v = W1[(size_t)(k + NC) * NC + (n - NC)];
    w1t[idx] = f2bf(v);
}

// ---- prep: W2T bf16 [n][k] from W2 f32 [k][n] --------------------------------
__global__ void __launch_bounds__(256) k_w2t(const float* __restrict__ W2,
                                             ushort* __restrict__ w2t) {
    int idx = blockIdx.x * 256 + threadIdx.x;
    if (idx >= NC * NC) return;
    int n = idx / NC, k = idx % NC;
    w2t[(size_t)n * NC + k] = f2bf(W2[(size_t)k * NC + n]);
}

// ---- kernel 4: [U'|V] = Xb @ w1t^T via MFMA; bias fused into U' --------------
#define UVM 32
__global__ void __launch_bounds__(256) k_uv2(const ushort* __restrict__ xb,
                                             const ushort* __restrict__ w1t,
                                             const float* __restrict__ b1,
                                             float* __restrict__ up,
                                             float* __restrict__ vv) {
    __shared__ ushort xs[UVM][200];
    int t = threadIdx.x;
    int w = t >> 6, l = t & 63;
    int lg = l >> 4, lr = l & 15;
    int p0 = blockIdx.x * UVM;
    for (int i = t; i < UVM * 24; i += 256) {
        int row = i / 24, c = (i % 24) * 8;
        *reinterpret_cast<bf16x8*>(&xs[row][c]) =
            *reinterpret_cast<const bf16x8*>(&xb[(size_t)(p0 + row) * NC + c]);
    }
    __syncthreads();
    int n0 = w * 96;
    f32x4 acc[2][6];
    #pragma unroll
    for (int mt = 0; mt < 2; ++mt)
        #pragma unroll
        for (int nt = 0; nt < 6; ++nt)
            acc[mt][nt] = (f32x4){0.f, 0.f, 0.f, 0.f};
    #pragma unroll
    for (int ks = 0; ks < 6; ++ks) {
        bf16x8 bfr[6];
        #pragma unroll
        for (int nt = 0; nt < 6; ++nt)
            bfr[nt] = *reinterpret_cast<const bf16x8*>(
                &w1t[(size_t)(n0 + nt * 16 + lr) * NC + ks * 32 + lg * 8]);
        bf16x8 a0 = *reinterpret_cast<const bf16x8*>(&xs[lr][ks * 32 + lg * 8]);
        bf16x8 a1 = *reinterpret_cast<const bf16x8*>(&xs[16 + lr][ks * 32 + lg * 8]);
        #pragma unroll
        for (int nt = 0; nt < 6; ++nt) {
            acc[0][nt] = __builtin_amdgcn_mfma_f32_16x16x32_bf16(a0, bfr[nt], acc[0][nt], 0, 0, 0);
            acc[1][nt] = __builtin_amdgcn_mfma_f32_16x16x32_bf16(a1, bfr[nt], acc[1][nt], 0, 0, 0);
        }
    }
    bool isU = (n0 < NC);
    #pragma unroll
    for (int nt = 0; nt < 6; ++nt) {
        int col = n0 + nt * 16 + lr;
        float bb = isU ? b1[col] : 0.f;
        int ocol = isU ? col : col - NC;
        float* dst = isU ? up : vv;
        #pragma unroll
        for (int mt = 0; mt < 2; ++mt)
            #pragma unroll
            for (int j = 0; j < 4; ++j) {
                int pt = p0 + mt * 16 + lg * 4 + j;
                dst[(size_t)pt * NC + ocol] = acc[mt][nt][j] + bb;
            }
    }
}

// ---- kernel 5: edge MLP; EPW=1 (48 AGPR acc), 16 waves/block, 4 waves/SIMD ---
__device__ __forceinline__ bf16x8 packh(float4 ua, float4 ub, float4 va, float4 vb) {
    union { bf16x8 v8; __hip_bfloat162 h2[4]; } r;
    r.h2[0] = __float22bfloat162_rn(make_float2(lrelu(ua.x + va.x), lrelu(ua.y + va.y)));
    r.h2[1] = __float22bfloat162_rn(make_float2(lrelu(ua.z + va.z), lrelu(ua.w + va.w)));
    r.h2[2] = __float22bfloat162_rn(make_float2(lrelu(ub.x + vb.x), lrelu(ub.y + vb.y)));
    r.h2[3] = __float22bfloat162_rn(make_float2(lrelu(ub.z + vb.z), lrelu(ub.w + vb.w)));
    return r.v8;
}

#define EW 16   // waves/block, 1 point each
__global__ void __launch_bounds__(1024, 4) k_edge7(const float* __restrict__ up,
                                                   const float* __restrict__ vv,
                                                   const int* __restrict__ knn,
                                                   const ushort* __restrict__ w2t,
                                                   const float* __restrict__ b2,
                                                   const float* __restrict__ gamma,
                                                   const float* __restrict__ beta,
                                                   float* __restrict__ out) {
    __shared__ ushort w2s[NC][200];   // 76.8 KB
    __shared__ float aggs[EW][NC];    // 12.3 KB -> 89.1 KB total, 1 block/CU
    int t = threadIdx.x;
    int wv = t >> 6, l = t & 63;
    int lg = l >> 4, lr = l & 15;

    int pt0 = blockIdx.x * EW + wv;
    int lre = lr < KNN ? lr : KNN - 1;
    int q0 = knn[(size_t)pt0 * KNN + lre];

    for (int i = t; i < NC * 24; i += 1024) {
        int r_ = i / 24, c_ = i % 24;
        *reinterpret_cast<bf16x8*>(&w2s[r_][c_ * 8]) =
            *reinterpret_cast<const bf16x8*>(&w2t[(size_t)r_ * NC + c_ * 8]);
    }
    __syncthreads();

    int b = pt0 / NP;
    const float* u0p = up + (size_t)pt0 * NC + 8 * lg;
    const float* v0p = vv + ((size_t)b * NP + q0) * NC + 8 * lg;

    f32x4 acc[12];
    #pragma unroll
    for (int nt = 0; nt < 12; ++nt) acc[nt] = (f32x4){0.f, 0.f, 0.f, 0.f};

    float4 sUa[2], sUb[2], sVa[2], sVb[2];
#define LDST(ph, ks) do { \
        sUa[ph] = *reinterpret_cast<const float4*>(u0p + (ks) * 32);     \
        sUb[ph] = *reinterpret_cast<const float4*>(u0p + (ks) * 32 + 4); \
        sVa[ph] = *reinterpret_cast<const float4*>(v0p + (ks) * 32);     \
        sVb[ph] = *reinterpret_cast<const float4*>(v0p + (ks) * 32 + 4); \
    } while (0)

    LDST(0, 0);
    #pragma unroll
    for (int ks = 0; ks < 6; ++ks) {
        int ph = ks & 1;
        if (ks < 5) LDST(ph ^ 1, ks + 1);
        bf16x8 a0 = packh(sUa[ph], sUb[ph], sVa[ph], sVb[ph]);
        #pragma unroll
        for (int nt = 0; nt < 12; ++nt) {
            bf16x8 bfr = *reinterpret_cast<const bf16x8*>(&w2s[nt * 16 + lr][ks * 32 + lg * 8]);
            acc[nt] = __builtin_amdgcn_mfma_f32_16x16x32_bf16(a0, bfr, acc[nt], 0, 0, 0);
        }
    }
#undef LDST

    #pragma unroll
    for (int nt = 0; nt < 12; ++nt) {
        float bb = b2[nt * 16 + lr];
        float s = 0.f;
        if (lg < 3) {
            #pragma unroll
            for (int j = 0; j < 4; ++j) s += lrelu(acc[nt][j] + bb);
        }
        s += __shfl_xor(s, 16, 64);
        s += __shfl_xor(s, 32, 64);
        if (lg == 0) aggs[wv][nt * 16 + lr] = s * (1.0f / KNN);
    }
    asm volatile("s_waitcnt lgkmcnt(0)" ::: "memory");

    float a0 = aggs[wv][l], a1 = aggs[wv][l + 64], a2 = aggs[wv][l + 128];
    float s = a0 + a1 + a2;
    #pragma unroll
    for (int off = 32; off; off >>= 1) s += __shfl_xor(s, off, 64);
    float mu = s / (float)NC;
    float d0 = a0 - mu, d1 = a1 - mu, d2 = a2 - mu;
    float vs = d0 * d0 + d1 * d1 + d2 * d2;
    #pragma unroll
    for (int off = 32; off; off >>= 1) vs += __shfl_xor(vs, off, 64);
    float rstd = 1.0f / sqrtf(vs / (float)NC + 1e-5f);
    float* o = out + (size_t)pt0 * NC;
    o[l]       = d0 * rstd * gamma[l]       + beta[l];
    o[l + 64]  = d1 * rstd * gamma[l + 64]  + beta[l + 64];
    o[l + 128] = d2 * rstd * gamma[l + 128] + beta[l + 128];
}

extern "C" void kernel_launch(void* const* d_in, const int* in_sizes, int n_in,
                              void* d_out, int out_size, void* d_ws, size_t ws_size,
                              hipStream_t stream) {
    const float* nodes = (const float*)d_in[0];
    const float* W1    = (const float*)d_in[1];
    const float* b1    = (const float*)d_in[2];
    const float* W2    = (const float*)d_in[3];
    const float* b2    = (const float*)d_in[4];
    const float* gamma = (const float*)d_in[5];
    const float* beta  = (const float*)d_in[6];
    float* out = (float*)d_out;

    const size_t BPC = (size_t)NB * NP * NC;
    float*  xn  = (float*)d_ws;                        // B*P*C f32
    float*  up  = xn + BPC;                            // B*P*C f32
    float*  vv  = up + BPC;                            // B*P*C f32
    ushort* xh  = (ushort*)(vv + BPC);                 // B*P*C bf16 (normalized)
    ushort* xb  = xh + BPC;                            // B*P*C bf16 (raw)
    int*    knn = (int*)(xb + BPC);                    // B*P*K
    ushort* w2t = (ushort*)(knn + (size_t)NB * NP * KNN); // C*C bf16
    ushort* w1t = w2t + (size_t)NC * NC;               // 2C*C bf16
    ushort* simh = (ushort*)(((uintptr_t)(w1t + (size_t)2 * NC * NC) + 15) & ~(uintptr_t)15);

    size_t fixed_bytes = (size_t)((char*)simh - (char*)d_ws);
    bool full = ws_size >= fixed_bytes + (size_t)NB * NP * NP * 2;

    k_normalize<<<NB * NP / 4, 256, 0, stream>>>(nodes, xn, xh, xb);
    k_w1t<<<(2 * NC * NC + 255) / 256, 256, 0, stream>>>(W1, w1t);
    k_w2t<<<(NC * NC + 255) / 256, 256, 0, stream>>>(W2, w2t);
    k_uv2<<<NB * NP / UVM, 256, 0, stream>>>(xb, w1t, b1, up, vv);
    if (full) {
        k_sim4<<<dim3(NP / 128, NP / 128, NB), 256, 0, stream>>>(xh, simh,
                                                                 (size_t)NP * NC, (size_t)NP * NP);
        k_topk7<<<NB * NP / 4, 256, 0, stream>>>(simh, xn, knn,
                                                 (size_t)NP * NP, (size_t)NP * NC);
    } else {
        for (int b = 0; b < NB; ++b) {
            k_sim4<<<dim3(NP / 128, NP / 128, 1), 256, 0, stream>>>(xh + (size_t)b * NP * NC, simh, 0, 0);
            k_topk7<<<NP / 4, 256, 0, stream>>>(simh, xn + (size_t)b * NP * NC,
                                                knn + (size_t)b * NP * KNN, 0, 0);
        }
    }
    k_edge7<<<NB * NP / EW, 1024, 0, stream>>>(up, vv, knn, w2t, b2, gamma, beta, out);
}

// Round 15
// 85.197 us; speedup vs baseline: 1.4271x; 1.1696x over previous
//
#include <hip/hip_runtime.h>
#include <hip/hip_bf16.h>
#include <hip/hip_fp16.h>
#include <math.h>

#define NB 4
#define NP 2048
#define NC 192
#define KNN 12
#define KSEL 16
#define NEG_SLOPE 0.2f

typedef __attribute__((ext_vector_type(8))) short bf16x8;
typedef __attribute__((ext_vector_type(8))) ushort u16x8;
typedef __attribute__((ext_vector_type(4))) float f32x4;

__device__ __forceinline__ float lrelu(float x) { return x >= 0.0f ? x : NEG_SLOPE * x; }

__device__ __forceinline__ ushort f2bf(float x) {
    unsigned u = __float_as_uint(x);
    unsigned r = (u + 0x7FFFu + ((u >> 16) & 1u)) >> 16;   // RNE
    return (ushort)r;
}

// monotone f16->u16 key, packed with complemented index; self -> 0 sentinel
__device__ __forceinline__ unsigned pkkey(unsigned b, int idx, int p) {
    unsigned key = (b & 0x8000u) ? (0xFFFFu & ~b) : (b | 0x8000u);
    unsigned v = (key << 11) | (unsigned)(2047 - idx);
    return (idx == p) ? 0u : v;
}

// ---------------- device bodies (shared by fused + standalone wrappers) -------

__device__ __forceinline__ void dev_normalize(const float* __restrict__ nodes,
                                              float* __restrict__ xn,
                                              ushort* __restrict__ xh,
                                              ushort* __restrict__ xb, int blk) {
    int wave = threadIdx.x >> 6;
    int lane = threadIdx.x & 63;
    size_t pt = (size_t)blk * 4 + wave;
    const float* x = nodes + pt * NC;
    float v0 = x[lane], v1 = x[lane + 64], v2 = x[lane + 128];
    float s = v0 * v0 + v1 * v1 + v2 * v2;
    #pragma unroll
    for (int off = 32; off; off >>= 1) s += __shfl_xor(s, off, 64);
    float inv = 1.0f / fmaxf(sqrtf(s), 1e-12f);
    float f0 = v0 * inv, f1 = v1 * inv, f2 = v2 * inv;
    float* o = xn + pt * NC;
    o[lane] = f0; o[lane + 64] = f1; o[lane + 128] = f2;
    ushort* oh = xh + pt * NC;
    oh[lane] = f2bf(f0); oh[lane + 64] = f2bf(f1); oh[lane + 128] = f2bf(f2);
    ushort* ob = xb + pt * NC;
    ob[lane] = f2bf(v0); ob[lane + 64] = f2bf(v1); ob[lane + 128] = f2bf(v2);
}

// ---- kernel 1 (fused prep): normalize | w1t | w2t, branch on blockIdx -------
__global__ void __launch_bounds__(256) k_prep(const float* __restrict__ nodes,
                                              const float* __restrict__ W1,
                                              const float* __restrict__ W2,
                                              float* __restrict__ xn,
                                              ushort* __restrict__ xh,
                                              ushort* __restrict__ xb,
                                              ushort* __restrict__ w1t,
                                              ushort* __restrict__ w2t) {
    int bid = blockIdx.x;
    if (bid < NB * NP / 4) {
        dev_normalize(nodes, xn, xh, xb, bid);
    } else if (bid < NB * NP / 4 + 2 * NC * NC / 256) {
        int idx = (bid - NB * NP / 4) * 256 + threadIdx.x;   // [0, 2*NC*NC)
        int n = idx / NC, k = idx % NC;
        float v;
        if (n < NC) v = W1[(size_t)k * NC + n] - W1[(size_t)(k + NC) * NC + n];
        else        v = W1[(size_t)(k + NC) * NC + (n - NC)];
        w1t[idx] = f2bf(v);
    } else {
        int idx = (bid - NB * NP / 4 - 2 * NC * NC / 256) * 256 + threadIdx.x;  // [0, NC*NC)
        int n = idx / NC, k = idx % NC;
        w2t[(size_t)n * NC + k] = f2bf(W2[(size_t)k * NC + n]);
    }
}

// ---- sim body: 128x128 tile bf16 MFMA, f16 out -------------------------------
__device__ __forceinline__ void dev_sim4(ushort (*Ah)[72], ushort (*Bh)[72],
                                         const ushort* __restrict__ xh,
                                         ushort* __restrict__ simh,
                                         int bx, int by, int bz,
                                         size_t xstride, size_t simstride) {
    const ushort* XbH = xh + (size_t)bz * xstride;
    ushort* sb = simh + (size_t)bz * simstride;
    int t = threadIdx.x;
    int w = t >> 6, l = t & 63;
    int wm = w >> 1, wn = w & 1;
    int lg = l >> 4, lr = l & 15;
    int m0 = by * 128, n0 = bx * 128;

    f32x4 acc[4][4];
    #pragma unroll
    for (int mi = 0; mi < 4; ++mi)
        #pragma unroll
        for (int ni = 0; ni < 4; ++ni)
            acc[mi][ni] = (f32x4){0.f, 0.f, 0.f, 0.f};

    int r = t >> 3, c = (t & 7) * 8;
    for (int ks = 0; ks < 3; ++ks) {
        int kb = ks * 64;
        #pragma unroll
        for (int i = 0; i < 4; ++i) {
            int row = r + 32 * i;
            *reinterpret_cast<bf16x8*>(&Ah[row][c]) =
                *reinterpret_cast<const bf16x8*>(&XbH[(size_t)(m0 + row) * NC + kb + c]);
            *reinterpret_cast<bf16x8*>(&Bh[row][c]) =
                *reinterpret_cast<const bf16x8*>(&XbH[(size_t)(n0 + row) * NC + kb + c]);
        }
        __syncthreads();
        #pragma unroll
        for (int ksub = 0; ksub < 2; ++ksub) {
            int ko = ksub * 32 + 8 * lg;
            bf16x8 af[4], bf[4];
            #pragma unroll
            for (int f = 0; f < 4; ++f) {
                af[f] = *reinterpret_cast<const bf16x8*>(&Ah[wm * 64 + f * 16 + lr][ko]);
                bf[f] = *reinterpret_cast<const bf16x8*>(&Bh[wn * 64 + f * 16 + lr][ko]);
            }
            #pragma unroll
            for (int mi = 0; mi < 4; ++mi)
                #pragma unroll
                for (int ni = 0; ni < 4; ++ni)
                    acc[mi][ni] = __builtin_amdgcn_mfma_f32_16x16x32_bf16(af[mi], bf[ni], acc[mi][ni], 0, 0, 0);
        }
        __syncthreads();
    }
    #pragma unroll
    for (int mi = 0; mi < 4; ++mi)
        #pragma unroll
        for (int j = 0; j < 4; ++j) {
            int row = m0 + wm * 64 + mi * 16 + lg * 4 + j;
            ushort* hrow = sb + (size_t)row * NP;
            #pragma unroll
            for (int ni = 0; ni < 4; ++ni) {
                __half h = __float2half(acc[mi][ni][j]);
                hrow[n0 + wn * 64 + ni * 16 + lr] = *reinterpret_cast<const ushort*>(&h);
            }
        }
}

// ---- uv body: [U'|V] = Xb @ w1t^T via MFMA; bias fused into U' ---------------
#define UVM 32
__device__ __forceinline__ void dev_uv2(ushort (*xs)[200],
                                        const ushort* __restrict__ xb,
                                        const ushort* __restrict__ w1t,
                                        const float* __restrict__ b1,
                                        float* __restrict__ up,
                                        float* __restrict__ vv, int blk) {
    int t = threadIdx.x;
    int w = t >> 6, l = t & 63;
    int lg = l >> 4, lr = l & 15;
    int p0 = blk * UVM;
    for (int i = t; i < UVM * 24; i += 256) {
        int row = i / 24, c = (i % 24) * 8;
        *reinterpret_cast<bf16x8*>(&xs[row][c]) =
            *reinterpret_cast<const bf16x8*>(&xb[(size_t)(p0 + row) * NC + c]);
    }
    __syncthreads();
    int n0 = w * 96;
    f32x4 acc[2][6];
    #pragma unroll
    for (int mt = 0; mt < 2; ++mt)
        #pragma unroll
        for (int nt = 0; nt < 6; ++nt)
            acc[mt][nt] = (f32x4){0.f, 0.f, 0.f, 0.f};
    #pragma unroll
    for (int ks = 0; ks < 6; ++ks) {
        bf16x8 bfr[6];
        #pragma unroll
        for (int nt = 0; nt < 6; ++nt)
            bfr[nt] = *reinterpret_cast<const bf16x8*>(
                &w1t[(size_t)(n0 + nt * 16 + lr) * NC + ks * 32 + lg * 8]);
        bf16x8 a0 = *reinterpret_cast<const bf16x8*>(&xs[lr][ks * 32 + lg * 8]);
        bf16x8 a1 = *reinterpret_cast<const bf16x8*>(&xs[16 + lr][ks * 32 + lg * 8]);
        #pragma unroll
        for (int nt = 0; nt < 6; ++nt) {
            acc[0][nt] = __builtin_amdgcn_mfma_f32_16x16x32_bf16(a0, bfr[nt], acc[0][nt], 0, 0, 0);
            acc[1][nt] = __builtin_amdgcn_mfma_f32_16x16x32_bf16(a1, bfr[nt], acc[1][nt], 0, 0, 0);
        }
    }
    bool isU = (n0 < NC);
    #pragma unroll
    for (int nt = 0; nt < 6; ++nt) {
        int col = n0 + nt * 16 + lr;
        float bb = isU ? b1[col] : 0.f;
        int ocol = isU ? col : col - NC;
        float* dst = isU ? up : vv;
        #pragma unroll
        for (int mt = 0; mt < 2; ++mt)
            #pragma unroll
            for (int j = 0; j < 4; ++j) {
                int pt = p0 + mt * 16 + lg * 4 + j;
                dst[(size_t)pt * NC + ocol] = acc[mt][nt][j] + bb;
            }
    }
}

// ---- kernel 2 (fused): uv2 (blocks 0..255) | sim4 (blocks 256..1279) ---------
__global__ void __launch_bounds__(256) k_uvsim(const ushort* __restrict__ xb,
                                               const ushort* __restrict__ w1t,
                                               const float* __restrict__ b1,
                                               float* __restrict__ up,
                                               float* __restrict__ vv,
                                               const ushort* __restrict__ xh,
                                               ushort* __restrict__ simh) {
    extern __shared__ char smem[];
    if (blockIdx.x < NB * NP / UVM) {
        dev_uv2((ushort(*)[200])smem, xb, w1t, b1, up, vv, blockIdx.x);
    } else {
        int sb_ = blockIdx.x - NB * NP / UVM;
        int bz = sb_ >> 8, rem = sb_ & 255, by = rem >> 4, bx = rem & 15;
        ushort (*Ah)[72] = (ushort(*)[72])smem;
        ushort (*Bh)[72] = Ah + 128;
        dev_sim4(Ah, Bh, xh, simh, bx, by, bz, (size_t)NP * NC, (size_t)NP * NP);
    }
}

// ---- standalone wrappers (ws-frugal fallback path) ---------------------------
__global__ void __launch_bounds__(256) k_uv2(const ushort* __restrict__ xb,
                                             const ushort* __restrict__ w1t,
                                             const float* __restrict__ b1,
                                             float* __restrict__ up,
                                             float* __restrict__ vv) {
    __shared__ ushort xs[UVM][200];
    dev_uv2(xs, xb, w1t, b1, up, vv, blockIdx.x);
}

__global__ void __launch_bounds__(256) k_sim4(const ushort* __restrict__ xh,
                                              ushort* __restrict__ simh,
                                              size_t xstride, size_t simstride) {
    __shared__ ushort Ah[128][72];
    __shared__ ushort Bh[128][72];
    dev_sim4(Ah, Bh, xh, simh, blockIdx.x, blockIdx.y, blockIdx.z, xstride, simstride);
}

// rare fallback: u32 insert list depth 16 + 16 extraction rounds (forceinline:
// pointer-escape would spill h8 to scratch — R12 lesson, 33 MB WRITE_SIZE).
__device__ __forceinline__ int topk_fb(const u16x8 h8[4], int p, int lane) {
    unsigned tv[16];
    #pragma unroll
    for (int q = 0; q < 16; ++q) tv[q] = 0u;
    #pragma unroll
    for (int i = 0; i < 4; ++i)
        #pragma unroll
        for (int j = 0; j < 8; ++j) {
            unsigned v = pkkey((unsigned)(ushort)h8[i][j], lane * 8 + i * 512 + j, p);
            if (v > tv[0]) {
                bool cg[16];
                #pragma unroll
                for (int q = 0; q < 16; ++q) cg[q] = v > tv[q];
                #pragma unroll
                for (int q = 0; q < 15; ++q)
                    tv[q] = cg[q + 1] ? tv[q + 1] : (cg[q] ? v : tv[q]);
                tv[15] = cg[15] ? v : tv[15];
            }
        }
    unsigned mp = 0u;
    #pragma unroll
    for (int rr = 0; rr < 16; ++rr) {
        unsigned bv = tv[15];
        #pragma unroll
        for (int off = 1; off < 64; off <<= 1) {
            unsigned ov = __shfl_xor(bv, off, 64);
            bv = ov > bv ? ov : bv;
        }
        if ((lane >> 2) == rr) mp = bv;
        if (bv == tv[15]) {
            #pragma unroll
            for (int s = 15; s > 0; --s) tv[s] = tv[s - 1];
            tv[0] = 0u;
        }
    }
    return (mp == 0u) ? -1 : (int)(2047u - (mp & 0x7FFu));
}

// -- kernel 3: 1 row/wave, low-VGPR packed-u32 top-16 + exact f32 rescore ------
__global__ void __launch_bounds__(256) k_topk7(const ushort* __restrict__ simh,
                                               const float* __restrict__ xn,
                                               int* __restrict__ knn,
                                               size_t simstride, size_t xstride) {
    __shared__ unsigned cand[4][64];
    int wv = threadIdx.x >> 6, lane = threadIdx.x & 63;
    int row = blockIdx.x * 4 + wv;
    int b = row / NP, p = row % NP;
    const ushort* sr = simh + (size_t)b * simstride + (size_t)p * NP;

    u16x8 h8[4];
    #pragma unroll
    for (int i = 0; i < 4; ++i)
        h8[i] = *reinterpret_cast<const u16x8*>(sr + lane * 8 + i * 512);

    unsigned lmax = 0;
    #pragma unroll
    for (int i = 0; i < 4; ++i)
        #pragma unroll
        for (int j = 0; j < 8; ++j) {
            unsigned v = pkkey((unsigned)(ushort)h8[i][j], lane * 8 + i * 512 + j, p);
            lmax = v > lmax ? v : lmax;
        }

    unsigned sm = lmax;
    #pragma unroll
    for (int k = 2; k <= 64; k <<= 1) {
        #pragma unroll
        for (int j = k >> 1; j >= 1; j >>= 1) {
            unsigned ov = __shfl_xor(sm, j, 64);
            bool keep_lo = (((lane & k) != 0) == ((lane & j) == 0));
            unsigned lo = sm < ov ? sm : ov, hi = sm < ov ? ov : sm;
            sm = keep_lo ? lo : hi;
        }
    }
    unsigned theta = __shfl(sm, KSEL, 64);

    int cnt = 0;
    #pragma unroll
    for (int i = 0; i < 4; ++i)
        #pragma unroll
        for (int j = 0; j < 8; ++j)
            cnt += (pkkey((unsigned)(ushort)h8[i][j], lane * 8 + i * 512 + j, p) > theta) ? 1 : 0;
    int x = cnt;
    #pragma unroll
    for (int off = 1; off < 64; off <<= 1) {
        int y = __shfl_up(x, off, 64);
        if (lane >= off) x += y;
    }
    int excl = x - cnt;
    int total = __shfl(x, 63, 64);

    int my_q;
    if (total <= 64) {
        cand[wv][lane] = 0u;
        asm volatile("s_waitcnt lgkmcnt(0)" ::: "memory");
        int pos = excl;
        #pragma unroll
        for (int i = 0; i < 4; ++i)
            #pragma unroll
            for (int j = 0; j < 8; ++j) {
                unsigned v = pkkey((unsigned)(ushort)h8[i][j], lane * 8 + i * 512 + j, p);
                if (v > theta) { cand[wv][pos] = v; ++pos; }
            }
        asm volatile("s_waitcnt lgkmcnt(0)" ::: "memory");
        unsigned v = cand[wv][lane];
        #pragma unroll
        for (int k = 2; k <= 64; k <<= 1) {
            #pragma unroll
            for (int j = k >> 1; j >= 1; j >>= 1) {
                unsigned ov = __shfl_xor(v, j, 64);
                bool keep_lo = (((lane & k) != 0) == ((lane & j) == 0));
                unsigned lo = v < ov ? v : ov, hi = v < ov ? ov : v;
                v = keep_lo ? lo : hi;
            }
        }
        unsigned mp = __shfl(v, lane >> 2, 64);
        my_q = (mp == 0u) ? -1 : (int)(2047u - (mp & 0x7FFu));
    } else {
        my_q = topk_fb(h8, p, lane);
    }

    const float* xb = xn + (size_t)b * xstride;
    int qa = my_q < 0 ? 0 : my_q;
    const float* cp = xb + (size_t)p * NC + (lane & 3) * 48;
    const float* cq = xb + (size_t)qa * NC + (lane & 3) * 48;
    float dot = 0.f;
    #pragma unroll
    for (int i = 0; i < 12; ++i) {
        float4 a = *reinterpret_cast<const float4*>(cp + i * 4);
        float4 bq = *reinterpret_cast<const float4*>(cq + i * 4);
        dot += a.x * bq.x + a.y * bq.y + a.z * bq.z + a.w * bq.w;
    }
    dot += __shfl_xor(dot, 1, 64);
    dot += __shfl_xor(dot, 2, 64);
    int g = lane >> 2;
    int rank = 0;
    #pragma unroll
    for (int j = 0; j < KSEL; ++j) {
        float vj = __shfl(dot, j * 4, 64);
        int   qj = __shfl(my_q, j * 4, 64);
        if (j != g && qj >= 0 && (vj > dot || (vj == dot && qj < my_q))) ++rank;
    }
    bool keep = ((lane & 3) == 0) && (my_q >= 0) && (rank < KNN);
    unsigned long long mask = __ballot(keep);
    int pos = __popcll(mask & ((1ull << lane) - 1));
    if (keep) knn[(size_t)row * KNN + pos] = my_q;
}

// ---- kernel 5: edge MLP; EPW=1 (48 AGPR acc), 16 waves/block, 4 waves/SIMD ---
__device__ __forceinline__ bf16x8 packh(float4 ua, float4 ub, float4 va, float4 vb) {
    union { bf16x8 v8; __hip_bfloat162 h2[4]; } r;
    r.h2[0] = __float22bfloat162_rn(make_float2(lrelu(ua.x + va.x), lrelu(ua.y + va.y)));
    r.h2[1] = __float22bfloat162_rn(make_float2(lrelu(ua.z + va.z), lrelu(ua.w + va.w)));
    r.h2[2] = __float22bfloat162_rn(make_float2(lrelu(ub.x + vb.x), lrelu(ub.y + vb.y)));
    r.h2[3] = __float22bfloat162_rn(make_float2(lrelu(ub.z + vb.z), lrelu(ub.w + vb.w)));
    return r.v8;
}

#define EW 16   // waves/block, 1 point each
__global__ void __launch_bounds__(1024, 4) k_edge7(const float* __restrict__ up,
                                                   const float* __restrict__ vv,
                                                   const int* __restrict__ knn,
                                                   const ushort* __restrict__ w2t,
                                                   const float* __restrict__ b2,
                                                   const float* __restrict__ gamma,
                                                   const float* __restrict__ beta,
                                                   float* __restrict__ out) {
    __shared__ ushort w2s[NC][200];   // 76.8 KB
    __shared__ float aggs[EW][NC];    // 12.3 KB -> 89.1 KB total, 1 block/CU
    int t = threadIdx.x;
    int wv = t >> 6, l = t & 63;
    int lg = l >> 4, lr = l & 15;

    int pt0 = blockIdx.x * EW + wv;
    int lre = lr < KNN ? lr : KNN - 1;
    int q0 = knn[(size_t)pt0 * KNN + lre];

    for (int i = t; i < NC * 24; i += 1024) {
        int r_ = i / 24, c_ = i % 24;
        *reinterpret_cast<bf16x8*>(&w2s[r_][c_ * 8]) =
            *reinterpret_cast<const bf16x8*>(&w2t[(size_t)r_ * NC + c_ * 8]);
    }
    __syncthreads();

    int b = pt0 / NP;
    const float* u0p = up + (size_t)pt0 * NC + 8 * lg;
    const float* v0p = vv + ((size_t)b * NP + q0) * NC + 8 * lg;

    f32x4 acc[12];
    #pragma unroll
    for (int nt = 0; nt < 12; ++nt) acc[nt] = (f32x4){0.f, 0.f, 0.f, 0.f};

    float4 sUa[2], sUb[2], sVa[2], sVb[2];
#define LDST(ph, ks) do { \
        sUa[ph] = *reinterpret_cast<const float4*>(u0p + (ks) * 32);     \
        sUb[ph] = *reinterpret_cast<const float4*>(u0p + (ks) * 32 + 4); \
        sVa[ph] = *reinterpret_cast<const float4*>(v0p + (ks) * 32);     \
        sVb[ph] = *reinterpret_cast<const float4*>(v0p + (ks) * 32 + 4); \
    } while (0)

    LDST(0, 0);
    #pragma unroll
    for (int ks = 0; ks < 6; ++ks) {
        int ph = ks & 1;
        if (ks < 5) LDST(ph ^ 1, ks + 1);
        bf16x8 a0 = packh(sUa[ph], sUb[ph], sVa[ph], sVb[ph]);
        #pragma unroll
        for (int nt = 0; nt < 12; ++nt) {
            bf16x8 bfr = *reinterpret_cast<const bf16x8*>(&w2s[nt * 16 + lr][ks * 32 + lg * 8]);
            acc[nt] = __builtin_amdgcn_mfma_f32_16x16x32_bf16(a0, bfr, acc[nt], 0, 0, 0);
        }
    }
#undef LDST

    #pragma unroll
    for (int nt = 0; nt < 12; ++nt) {
        float bb = b2[nt * 16 + lr];
        float s = 0.f;
        if (lg < 3) {
            #pragma unroll
            for (int j = 0; j < 4; ++j) s += lrelu(acc[nt][j] + bb);
        }
        s += __shfl_xor(s, 16, 64);
        s += __shfl_xor(s, 32, 64);
        if (lg == 0) aggs[wv][nt * 16 + lr] = s * (1.0f / KNN);
    }
    asm volatile("s_waitcnt lgkmcnt(0)" ::: "memory");

    float a0 = aggs[wv][l], a1 = aggs[wv][l + 64], a2 = aggs[wv][l + 128];
    float s = a0 + a1 + a2;
    #pragma unroll
    for (int off = 32; off; off >>= 1) s += __shfl_xor(s, off, 64);
    float mu = s / (float)NC;
    float d0 = a0 - mu, d1 = a1 - mu, d2 = a2 - mu;
    float vs = d0 * d0 + d1 * d1 + d2 * d2;
    #pragma unroll
    for (int off = 32; off; off >>= 1) vs += __shfl_xor(vs, off, 64);
    float rstd = 1.0f / sqrtf(vs / (float)NC + 1e-5f);
    float* o = out + (size_t)pt0 * NC;
    o[l]       = d0 * rstd * gamma[l]       + beta[l];
    o[l + 64]  = d1 * rstd * gamma[l + 64]  + beta[l + 64];
    o[l + 128] = d2 * rstd * gamma[l + 128] + beta[l + 128];
}

extern "C" void kernel_launch(void* const* d_in, const int* in_sizes, int n_in,
                              void* d_out, int out_size, void* d_ws, size_t ws_size,
                              hipStream_t stream) {
    const float* nodes = (const float*)d_in[0];
    const float* W1    = (const float*)d_in[1];
    const float* b1    = (const float*)d_in[2];
    const float* W2    = (const float*)d_in[3];
    const float* b2    = (const float*)d_in[4];
    const float* gamma = (const float*)d_in[5];
    const float* beta  = (const float*)d_in[6];
    float* out = (float*)d_out;

    const size_t BPC = (size_t)NB * NP * NC;
    float*  xn  = (float*)d_ws;                        // B*P*C f32
    float*  up  = xn + BPC;                            // B*P*C f32
    float*  vv  = up + BPC;                            // B*P*C f32
    ushort* xh  = (ushort*)(vv + BPC);                 // B*P*C bf16 (normalized)
    ushort* xb  = xh + BPC;                            // B*P*C bf16 (raw)
    int*    knn = (int*)(xb + BPC);                    // B*P*K
    ushort* w2t = (ushort*)(knn + (size_t)NB * NP * KNN); // C*C bf16
    ushort* w1t = w2t + (size_t)NC * NC;               // 2C*C bf16
    ushort* simh = (ushort*)(((uintptr_t)(w1t + (size_t)2 * NC * NC) + 15) & ~(uintptr_t)15);

    size_t fixed_bytes = (size_t)((char*)simh - (char*)d_ws);
    bool full = ws_size >= fixed_bytes + (size_t)NB * NP * NP * 2;

    int prep_grid = NB * NP / 4 + 2 * NC * NC / 256 + NC * NC / 256;   // 2048+288+144
    k_prep<<<prep_grid, 256, 0, stream>>>(nodes, W1, W2, xn, xh, xb, w1t, w2t);
    if (full) {
        // fused uv | sim (dynamic LDS = sim tile size, 36864 B)
        k_uvsim<<<NB * NP / UVM + 16 * NB * (NP / 128), 256, 36864, stream>>>(
            xb, w1t, b1, up, vv, xh, simh);
        k_topk7<<<NB * NP / 4, 256, 0, stream>>>(simh, xn, knn,
                                                 (size_t)NP * NP, (size_t)NP * NC);
    } else {
        k_uv2<<<NB * NP / UVM, 256, 0, stream>>>(xb, w1t, b1, up, vv);
        for (int b = 0; b < NB; ++b) {
            k_sim4<<<dim3(NP / 128, NP / 128, 1), 256, 0, stream>>>(xh + (size_t)b * NP * NC, simh, 0, 0);
            k_topk7<<<NP / 4, 256, 0, stream>>>(simh, xn + (size_t)b * NP * NC,
                                                knn + (size_t)b * NP * KNN, 0, 0);
        }
    }
    k_edge7<<<NB * NP / EW, 1024, 0, stream>>>(up, vv, knn, w2t, b2, gamma, beta, out);
}

// Round 16
// 83.122 us; speedup vs baseline: 1.4627x; 1.0250x over previous
//
#include <hip/hip_runtime.h>
#include <hip/hip_bf16.h>
#include <hip/hip_fp16.h>
#include <math.h>

#define NB 4
#define NP 2048
#define NC 192
#define KNN 12
#define KSEL 16
#define NEG_SLOPE 0.2f

typedef __attribute__((ext_vector_type(8))) short bf16x8;
typedef __attribute__((ext_vector_type(8))) ushort u16x8;
typedef __attribute__((ext_vector_type(4))) float f32x4;

__device__ __forceinline__ float lrelu(float x) { return x >= 0.0f ? x : NEG_SLOPE * x; }

__device__ __forceinline__ ushort f2bf(float x) {
    unsigned u = __float_as_uint(x);
    unsigned r = (u + 0x7FFFu + ((u >> 16) & 1u)) >> 16;   // RNE
    return (ushort)r;
}

// monotone f16->u16 key, packed with complemented index; self -> 0 sentinel
__device__ __forceinline__ unsigned pkkey(unsigned b, int idx, int p) {
    unsigned key = (b & 0x8000u) ? (0xFFFFu & ~b) : (b | 0x8000u);
    unsigned v = (key << 11) | (unsigned)(2047 - idx);
    return (idx == p) ? 0u : v;
}

// ---------------- device bodies (shared by fused + standalone wrappers) -------

__device__ __forceinline__ void dev_normalize(const float* __restrict__ nodes,
                                              float* __restrict__ xn,
                                              ushort* __restrict__ xh,
                                              ushort* __restrict__ xb, int blk) {
    int wave = threadIdx.x >> 6;
    int lane = threadIdx.x & 63;
    size_t pt = (size_t)blk * 4 + wave;
    const float* x = nodes + pt * NC;
    float v0 = x[lane], v1 = x[lane + 64], v2 = x[lane + 128];
    float s = v0 * v0 + v1 * v1 + v2 * v2;
    #pragma unroll
    for (int off = 32; off; off >>= 1) s += __shfl_xor(s, off, 64);
    float inv = 1.0f / fmaxf(sqrtf(s), 1e-12f);
    float f0 = v0 * inv, f1 = v1 * inv, f2 = v2 * inv;
    float* o = xn + pt * NC;
    o[lane] = f0; o[lane + 64] = f1; o[lane + 128] = f2;
    ushort* oh = xh + pt * NC;
    oh[lane] = f2bf(f0); oh[lane + 64] = f2bf(f1); oh[lane + 128] = f2bf(f2);
    ushort* ob = xb + pt * NC;
    ob[lane] = f2bf(v0); ob[lane + 64] = f2bf(v1); ob[lane + 128] = f2bf(v2);
}

// ---- kernel 1 (fused prep): normalize | w1t | w2t, branch on blockIdx -------
__global__ void __launch_bounds__(256) k_prep(const float* __restrict__ nodes,
                                              const float* __restrict__ W1,
                                              const float* __restrict__ W2,
                                              float* __restrict__ xn,
                                              ushort* __restrict__ xh,
                                              ushort* __restrict__ xb,
                                              ushort* __restrict__ w1t,
                                              ushort* __restrict__ w2t) {
    int bid = blockIdx.x;
    if (bid < NB * NP / 4) {
        dev_normalize(nodes, xn, xh, xb, bid);
    } else if (bid < NB * NP / 4 + 2 * NC * NC / 256) {
        int idx = (bid - NB * NP / 4) * 256 + threadIdx.x;   // [0, 2*NC*NC)
        int n = idx / NC, k = idx % NC;
        float v;
        if (n < NC) v = W1[(size_t)k * NC + n] - W1[(size_t)(k + NC) * NC + n];
        else        v = W1[(size_t)(k + NC) * NC + (n - NC)];
        w1t[idx] = f2bf(v);
    } else {
        int idx = (bid - NB * NP / 4 - 2 * NC * NC / 256) * 256 + threadIdx.x;  // [0, NC*NC)
        int n = idx / NC, k = idx % NC;
        w2t[(size_t)n * NC + k] = f2bf(W2[(size_t)k * NC + n]);
    }
}

// ---- sim body: 128x128 tile bf16 MFMA, f16 out -------------------------------
__device__ __forceinline__ void dev_sim4(ushort (*Ah)[72], ushort (*Bh)[72],
                                         const ushort* __restrict__ xh,
                                         ushort* __restrict__ simh,
                                         int bx, int by, int bz,
                                         size_t xstride, size_t simstride) {
    const ushort* XbH = xh + (size_t)bz * xstride;
    ushort* sb = simh + (size_t)bz * simstride;
    int t = threadIdx.x;
    int w = t >> 6, l = t & 63;
    int wm = w >> 1, wn = w & 1;
    int lg = l >> 4, lr = l & 15;
    int m0 = by * 128, n0 = bx * 128;

    f32x4 acc[4][4];
    #pragma unroll
    for (int mi = 0; mi < 4; ++mi)
        #pragma unroll
        for (int ni = 0; ni < 4; ++ni)
            acc[mi][ni] = (f32x4){0.f, 0.f, 0.f, 0.f};

    int r = t >> 3, c = (t & 7) * 8;
    for (int ks = 0; ks < 3; ++ks) {
        int kb = ks * 64;
        #pragma unroll
        for (int i = 0; i < 4; ++i) {
            int row = r + 32 * i;
            *reinterpret_cast<bf16x8*>(&Ah[row][c]) =
                *reinterpret_cast<const bf16x8*>(&XbH[(size_t)(m0 + row) * NC + kb + c]);
            *reinterpret_cast<bf16x8*>(&Bh[row][c]) =
                *reinterpret_cast<const bf16x8*>(&XbH[(size_t)(n0 + row) * NC + kb + c]);
        }
        __syncthreads();
        #pragma unroll
        for (int ksub = 0; ksub < 2; ++ksub) {
            int ko = ksub * 32 + 8 * lg;
            bf16x8 af[4], bf[4];
            #pragma unroll
            for (int f = 0; f < 4; ++f) {
                af[f] = *reinterpret_cast<const bf16x8*>(&Ah[wm * 64 + f * 16 + lr][ko]);
                bf[f] = *reinterpret_cast<const bf16x8*>(&Bh[wn * 64 + f * 16 + lr][ko]);
            }
            #pragma unroll
            for (int mi = 0; mi < 4; ++mi)
                #pragma unroll
                for (int ni = 0; ni < 4; ++ni)
                    acc[mi][ni] = __builtin_amdgcn_mfma_f32_16x16x32_bf16(af[mi], bf[ni], acc[mi][ni], 0, 0, 0);
        }
        __syncthreads();
    }
    #pragma unroll
    for (int mi = 0; mi < 4; ++mi)
        #pragma unroll
        for (int j = 0; j < 4; ++j) {
            int row = m0 + wm * 64 + mi * 16 + lg * 4 + j;
            ushort* hrow = sb + (size_t)row * NP;
            #pragma unroll
            for (int ni = 0; ni < 4; ++ni) {
                __half h = __float2half(acc[mi][ni][j]);
                hrow[n0 + wn * 64 + ni * 16 + lr] = *reinterpret_cast<const ushort*>(&h);
            }
        }
}

// ---- uv body: [U'|V] = Xb @ w1t^T via MFMA; bias fused; bf16 out -------------
#define UVM 32
__device__ __forceinline__ void dev_uv2(ushort (*xs)[200],
                                        const ushort* __restrict__ xb,
                                        const ushort* __restrict__ w1t,
                                        const float* __restrict__ b1,
                                        ushort* __restrict__ up,
                                        ushort* __restrict__ vv, int blk) {
    int t = threadIdx.x;
    int w = t >> 6, l = t & 63;
    int lg = l >> 4, lr = l & 15;
    int p0 = blk * UVM;
    for (int i = t; i < UVM * 24; i += 256) {
        int row = i / 24, c = (i % 24) * 8;
        *reinterpret_cast<bf16x8*>(&xs[row][c]) =
            *reinterpret_cast<const bf16x8*>(&xb[(size_t)(p0 + row) * NC + c]);
    }
    __syncthreads();
    int n0 = w * 96;
    f32x4 acc[2][6];
    #pragma unroll
    for (int mt = 0; mt < 2; ++mt)
        #pragma unroll
        for (int nt = 0; nt < 6; ++nt)
            acc[mt][nt] = (f32x4){0.f, 0.f, 0.f, 0.f};
    #pragma unroll
    for (int ks = 0; ks < 6; ++ks) {
        bf16x8 bfr[6];
        #pragma unroll
        for (int nt = 0; nt < 6; ++nt)
            bfr[nt] = *reinterpret_cast<const bf16x8*>(
                &w1t[(size_t)(n0 + nt * 16 + lr) * NC + ks * 32 + lg * 8]);
        bf16x8 a0 = *reinterpret_cast<const bf16x8*>(&xs[lr][ks * 32 + lg * 8]);
        bf16x8 a1 = *reinterpret_cast<const bf16x8*>(&xs[16 + lr][ks * 32 + lg * 8]);
        #pragma unroll
        for (int nt = 0; nt < 6; ++nt) {
            acc[0][nt] = __builtin_amdgcn_mfma_f32_16x16x32_bf16(a0, bfr[nt], acc[0][nt], 0, 0, 0);
            acc[1][nt] = __builtin_amdgcn_mfma_f32_16x16x32_bf16(a1, bfr[nt], acc[1][nt], 0, 0, 0);
        }
    }
    bool isU = (n0 < NC);
    #pragma unroll
    for (int nt = 0; nt < 6; ++nt) {
        int col = n0 + nt * 16 + lr;
        float bb = isU ? b1[col] : 0.f;
        int ocol = isU ? col : col - NC;
        ushort* dst = isU ? up : vv;
        #pragma unroll
        for (int mt = 0; mt < 2; ++mt)
            #pragma unroll
            for (int j = 0; j < 4; ++j) {
                int pt = p0 + mt * 16 + lg * 4 + j;
                dst[(size_t)pt * NC + ocol] = f2bf(acc[mt][nt][j] + bb);
            }
    }
}

// ---- kernel 2 (fused): uv2 (blocks 0..255) | sim4 (blocks 256..1279) ---------
__global__ void __launch_bounds__(256) k_uvsim(const ushort* __restrict__ xb,
                                               const ushort* __restrict__ w1t,
                                               const float* __restrict__ b1,
                                               ushort* __restrict__ up,
                                               ushort* __restrict__ vv,
                                               const ushort* __restrict__ xh,
                                               ushort* __restrict__ simh) {
    extern __shared__ char smem[];
    if (blockIdx.x < NB * NP / UVM) {
        dev_uv2((ushort(*)[200])smem, xb, w1t, b1, up, vv, blockIdx.x);
    } else {
        int sb_ = blockIdx.x - NB * NP / UVM;
        int bz = sb_ >> 8, rem = sb_ & 255, by = rem >> 4, bx = rem & 15;
        ushort (*Ah)[72] = (ushort(*)[72])smem;
        ushort (*Bh)[72] = Ah + 128;
        dev_sim4(Ah, Bh, xh, simh, bx, by, bz, (size_t)NP * NC, (size_t)NP * NP);
    }
}

// ---- standalone wrappers (ws-frugal fallback path) ---------------------------
__global__ void __launch_bounds__(256) k_uv2(const ushort* __restrict__ xb,
                                             const ushort* __restrict__ w1t,
                                             const float* __restrict__ b1,
                                             ushort* __restrict__ up,
                                             ushort* __restrict__ vv) {
    __shared__ ushort xs[UVM][200];
    dev_uv2(xs, xb, w1t, b1, up, vv, blockIdx.x);
}

__global__ void __launch_bounds__(256) k_sim4(const ushort* __restrict__ xh,
                                              ushort* __restrict__ simh,
                                              size_t xstride, size_t simstride) {
    __shared__ ushort Ah[128][72];
    __shared__ ushort Bh[128][72];
    dev_sim4(Ah, Bh, xh, simh, blockIdx.x, blockIdx.y, blockIdx.z, xstride, simstride);
}

// rare fallback: u32 insert list depth 16 + 16 extraction rounds (forceinline:
// pointer-escape would spill h8 to scratch — R12 lesson, 33 MB WRITE_SIZE).
__device__ __forceinline__ int topk_fb(const u16x8 h8[4], int p, int lane) {
    unsigned tv[16];
    #pragma unroll
    for (int q = 0; q < 16; ++q) tv[q] = 0u;
    #pragma unroll
    for (int i = 0; i < 4; ++i)
        #pragma unroll
        for (int j = 0; j < 8; ++j) {
            unsigned v = pkkey((unsigned)(ushort)h8[i][j], lane * 8 + i * 512 + j, p);
            if (v > tv[0]) {
                bool cg[16];
                #pragma unroll
                for (int q = 0; q < 16; ++q) cg[q] = v > tv[q];
                #pragma unroll
                for (int q = 0; q < 15; ++q)
                    tv[q] = cg[q + 1] ? tv[q + 1] : (cg[q] ? v : tv[q]);
                tv[15] = cg[15] ? v : tv[15];
            }
        }
    unsigned mp = 0u;
    #pragma unroll
    for (int rr = 0; rr < 16; ++rr) {
        unsigned bv = tv[15];
        #pragma unroll
        for (int off = 1; off < 64; off <<= 1) {
            unsigned ov = __shfl_xor(bv, off, 64);
            bv = ov > bv ? ov : bv;
        }
        if ((lane >> 2) == rr) mp = bv;
        if (bv == tv[15]) {
            #pragma unroll
            for (int s = 15; s > 0; --s) tv[s] = tv[s - 1];
            tv[0] = 0u;
        }
    }
    return (mp == 0u) ? -1 : (int)(2047u - (mp & 0x7FFu));
}

// -- kernel 3: 1 row/wave, low-VGPR packed-u32 top-16 + exact f32 rescore ------
__global__ void __launch_bounds__(256) k_topk7(const ushort* __restrict__ simh,
                                               const float* __restrict__ xn,
                                               int* __restrict__ knn,
                                               size_t simstride, size_t xstride) {
    __shared__ unsigned cand[4][64];
    int wv = threadIdx.x >> 6, lane = threadIdx.x & 63;
    int row = blockIdx.x * 4 + wv;
    int b = row / NP, p = row % NP;
    const ushort* sr = simh + (size_t)b * simstride + (size_t)p * NP;

    u16x8 h8[4];
    #pragma unroll
    for (int i = 0; i < 4; ++i)
        h8[i] = *reinterpret_cast<const u16x8*>(sr + lane * 8 + i * 512);

    unsigned lmax = 0;
    #pragma unroll
    for (int i = 0; i < 4; ++i)
        #pragma unroll
        for (int j = 0; j < 8; ++j) {
            unsigned v = pkkey((unsigned)(ushort)h8[i][j], lane * 8 + i * 512 + j, p);
            lmax = v > lmax ? v : lmax;
        }

    unsigned sm = lmax;
    #pragma unroll
    for (int k = 2; k <= 64; k <<= 1) {
        #pragma unroll
        for (int j = k >> 1; j >= 1; j >>= 1) {
            unsigned ov = __shfl_xor(sm, j, 64);
            bool keep_lo = (((lane & k) != 0) == ((lane & j) == 0));
            unsigned lo = sm < ov ? sm : ov, hi = sm < ov ? ov : sm;
            sm = keep_lo ? lo : hi;
        }
    }
    unsigned theta = __shfl(sm, KSEL, 64);

    int cnt = 0;
    #pragma unroll
    for (int i = 0; i < 4; ++i)
        #pragma unroll
        for (int j = 0; j < 8; ++j)
            cnt += (pkkey((unsigned)(ushort)h8[i][j], lane * 8 + i * 512 + j, p) > theta) ? 1 : 0;
    int x = cnt;
    #pragma unroll
    for (int off = 1; off < 64; off <<= 1) {
        int y = __shfl_up(x, off, 64);
        if (lane >= off) x += y;
    }
    int excl = x - cnt;
    int total = __shfl(x, 63, 64);

    int my_q;
    if (total <= 64) {
        cand[wv][lane] = 0u;
        asm volatile("s_waitcnt lgkmcnt(0)" ::: "memory");
        int pos = excl;
        #pragma unroll
        for (int i = 0; i < 4; ++i)
            #pragma unroll
            for (int j = 0; j < 8; ++j) {
                unsigned v = pkkey((unsigned)(ushort)h8[i][j], lane * 8 + i * 512 + j, p);
                if (v > theta) { cand[wv][pos] = v; ++pos; }
            }
        asm volatile("s_waitcnt lgkmcnt(0)" ::: "memory");
        unsigned v = cand[wv][lane];
        #pragma unroll
        for (int k = 2; k <= 64; k <<= 1) {
            #pragma unroll
            for (int j = k >> 1; j >= 1; j >>= 1) {
                unsigned ov = __shfl_xor(v, j, 64);
                bool keep_lo = (((lane & k) != 0) == ((lane & j) == 0));
                unsigned lo = v < ov ? v : ov, hi = v < ov ? ov : v;
                v = keep_lo ? lo : hi;
            }
        }
        unsigned mp = __shfl(v, lane >> 2, 64);
        my_q = (mp == 0u) ? -1 : (int)(2047u - (mp & 0x7FFu));
    } else {
        my_q = topk_fb(h8, p, lane);
    }

    const float* xb = xn + (size_t)b * xstride;
    int qa = my_q < 0 ? 0 : my_q;
    const float* cp = xb + (size_t)p * NC + (lane & 3) * 48;
    const float* cq = xb + (size_t)qa * NC + (lane & 3) * 48;
    float dot = 0.f;
    #pragma unroll
    for (int i = 0; i < 12; ++i) {
        float4 a = *reinterpret_cast<const float4*>(cp + i * 4);
        float4 bq = *reinterpret_cast<const float4*>(cq + i * 4);
        dot += a.x * bq.x + a.y * bq.y + a.z * bq.z + a.w * bq.w;
    }
    dot += __shfl_xor(dot, 1, 64);
    dot += __shfl_xor(dot, 2, 64);
    int g = lane >> 2;
    int rank = 0;
    #pragma unroll
    for (int j = 0; j < KSEL; ++j) {
        float vj = __shfl(dot, j * 4, 64);
        int   qj = __shfl(my_q, j * 4, 64);
        if (j != g && qj >= 0 && (vj > dot || (vj == dot && qj < my_q))) ++rank;
    }
    bool keep = ((lane & 3) == 0) && (my_q >= 0) && (rank < KNN);
    unsigned long long mask = __ballot(keep);
    int pos = __popcll(mask & ((1ull << lane) - 1));
    if (keep) knn[(size_t)row * KNN + pos] = my_q;
}

// ---- kernel 5: edge MLP; bf16 up/vv gather (half the bytes of f32) -----------
__device__ __forceinline__ bf16x8 packh2(bf16x8 u, bf16x8 v) {
    union { bf16x8 v8; ushort us[8]; } U, V, R;
    U.v8 = u; V.v8 = v;
    #pragma unroll
    for (int i = 0; i < 8; i += 2) {
        float a0 = __uint_as_float((unsigned)U.us[i] << 16)
                 + __uint_as_float((unsigned)V.us[i] << 16);
        float a1 = __uint_as_float((unsigned)U.us[i + 1] << 16)
                 + __uint_as_float((unsigned)V.us[i + 1] << 16);
        __hip_bfloat162 h2 = __float22bfloat162_rn(make_float2(lrelu(a0), lrelu(a1)));
        R.us[i]     = *reinterpret_cast<const ushort*>(&h2.x);
        R.us[i + 1] = *reinterpret_cast<const ushort*>(&h2.y);
    }
    return R.v8;
}

#define EW 16   // waves/block, 1 point each
__global__ void __launch_bounds__(1024, 4) k_edge7(const ushort* __restrict__ up,
                                                   const ushort* __restrict__ vv,
                                                   const int* __restrict__ knn,
                                                   const ushort* __restrict__ w2t,
                                                   const float* __restrict__ b2,
                                                   const float* __restrict__ gamma,
                                                   const float* __restrict__ beta,
                                                   float* __restrict__ out) {
    __shared__ ushort w2s[NC][200];   // 76.8 KB
    __shared__ float aggs[EW][NC];    // 12.3 KB -> 89.1 KB total, 1 block/CU
    int t = threadIdx.x;
    int wv = t >> 6, l = t & 63;
    int lg = l >> 4, lr = l & 15;

    int pt0 = blockIdx.x * EW + wv;
    int lre = lr < KNN ? lr : KNN - 1;
    int q0 = knn[(size_t)pt0 * KNN + lre];

    for (int i = t; i < NC * 24; i += 1024) {
        int r_ = i / 24, c_ = i % 24;
        *reinterpret_cast<bf16x8*>(&w2s[r_][c_ * 8]) =
            *reinterpret_cast<const bf16x8*>(&w2t[(size_t)r_ * NC + c_ * 8]);
    }
    __syncthreads();

    int b = pt0 / NP;
    const ushort* u0p = up + (size_t)pt0 * NC + 8 * lg;
    const ushort* v0p = vv + ((size_t)b * NP + q0) * NC + 8 * lg;

    f32x4 acc[12];
    #pragma unroll
    for (int nt = 0; nt < 12; ++nt) acc[nt] = (f32x4){0.f, 0.f, 0.f, 0.f};

    bf16x8 sU[2], sV[2];
#define LDST(ph, ks) do { \
        sU[ph] = *reinterpret_cast<const bf16x8*>(u0p + (ks) * 32); \
        sV[ph] = *reinterpret_cast<const bf16x8*>(v0p + (ks) * 32); \
    } while (0)

    LDST(0, 0);
    #pragma unroll
    for (int ks = 0; ks < 6; ++ks) {
        int ph = ks & 1;
        if (ks < 5) LDST(ph ^ 1, ks + 1);
        bf16x8 a0 = packh2(sU[ph], sV[ph]);
        #pragma unroll
        for (int nt = 0; nt < 12; ++nt) {
            bf16x8 bfr = *reinterpret_cast<const bf16x8*>(&w2s[nt * 16 + lr][ks * 32 + lg * 8]);
            acc[nt] = __builtin_amdgcn_mfma_f32_16x16x32_bf16(a0, bfr, acc[nt], 0, 0, 0);
        }
    }
#undef LDST

    #pragma unroll
    for (int nt = 0; nt < 12; ++nt) {
        float bb = b2[nt * 16 + lr];
        float s = 0.f;
        if (lg < 3) {
            #pragma unroll
            for (int j = 0; j < 4; ++j) s += lrelu(acc[nt][j] + bb);
        }
        s += __shfl_xor(s, 16, 64);
        s += __shfl_xor(s, 32, 64);
        if (lg == 0) aggs[wv][nt * 16 + lr] = s * (1.0f / KNN);
    }
    asm volatile("s_waitcnt lgkmcnt(0)" ::: "memory");

    float a0 = aggs[wv][l], a1 = aggs[wv][l + 64], a2 = aggs[wv][l + 128];
    float s = a0 + a1 + a2;
    #pragma unroll
    for (int off = 32; off; off >>= 1) s += __shfl_xor(s, off, 64);
    float mu = s / (float)NC;
    float d0 = a0 - mu, d1 = a1 - mu, d2 = a2 - mu;
    float vs = d0 * d0 + d1 * d1 + d2 * d2;
    #pragma unroll
    for (int off = 32; off; off >>= 1) vs += __shfl_xor(vs, off, 64);
    float rstd = 1.0f / sqrtf(vs / (float)NC + 1e-5f);
    float* o = out + (size_t)pt0 * NC;
    o[l]       = d0 * rstd * gamma[l]       + beta[l];
    o[l + 64]  = d1 * rstd * gamma[l + 64]  + beta[l + 64];
    o[l + 128] = d2 * rstd * gamma[l + 128] + beta[l + 128];
}

extern "C" void kernel_launch(void* const* d_in, const int* in_sizes, int n_in,
                              void* d_out, int out_size, void* d_ws, size_t ws_size,
                              hipStream_t stream) {
    const float* nodes = (const float*)d_in[0];
    const float* W1    = (const float*)d_in[1];
    const float* b1    = (const float*)d_in[2];
    const float* W2    = (const float*)d_in[3];
    const float* b2    = (const float*)d_in[4];
    const float* gamma = (const float*)d_in[5];
    const float* beta  = (const float*)d_in[6];
    float* out = (float*)d_out;

    const size_t BPC = (size_t)NB * NP * NC;
    float*  xn  = (float*)d_ws;                        // B*P*C f32
    ushort* up  = (ushort*)(xn + BPC);                 // B*P*C bf16
    ushort* vv  = up + BPC;                            // B*P*C bf16
    ushort* xh  = vv + BPC;                            // B*P*C bf16 (normalized)
    ushort* xb  = xh + BPC;                            // B*P*C bf16 (raw)
    int*    knn = (int*)(xb + BPC);                    // B*P*K
    ushort* w2t = (ushort*)(knn + (size_t)NB * NP * KNN); // C*C bf16
    ushort* w1t = w2t + (size_t)NC * NC;               // 2C*C bf16
    ushort* simh = (ushort*)(((uintptr_t)(w1t + (size_t)2 * NC * NC) + 15) & ~(uintptr_t)15);

    size_t fixed_bytes = (size_t)((char*)simh - (char*)d_ws);
    bool full = ws_size >= fixed_bytes + (size_t)NB * NP * NP * 2;

    int prep_grid = NB * NP / 4 + 2 * NC * NC / 256 + NC * NC / 256;   // 2048+288+144
    k_prep<<<prep_grid, 256, 0, stream>>>(nodes, W1, W2, xn, xh, xb, w1t, w2t);
    if (full) {
        k_uvsim<<<NB * NP / UVM + 16 * NB * (NP / 128), 256, 36864, stream>>>(
            xb, w1t, b1, up, vv, xh, simh);
        k_topk7<<<NB * NP / 4, 256, 0, stream>>>(simh, xn, knn,
                                                 (size_t)NP * NP, (size_t)NP * NC);
    } else {
        k_uv2<<<NB * NP / UVM, 256, 0, stream>>>(xb, w1t, b1, up, vv);
        for (int b = 0; b < NB; ++b) {
            k_sim4<<<dim3(NP / 128, NP / 128, 1), 256, 0, stream>>>(xh + (size_t)b * NP * NC, simh, 0, 0);
            k_topk7<<<NP / 4, 256, 0, stream>>>(simh, xn + (size_t)b * NP * NC,
                                                knn + (size_t)b * NP * KNN, 0, 0);
        }
    }
    k_edge7<<<NB * NP / EW, 1024, 0, stream>>>(up, vv, knn, w2t, b2, gamma, beta, out);
}

// Round 17
// 82.037 us; speedup vs baseline: 1.4821x; 1.0132x over previous
//
#include <hip/hip_runtime.h>
#include <hip/hip_bf16.h>
#include <hip/hip_fp16.h>
#include <math.h>

#define NB 4
#define NP 2048
#define NC 192
#define KNN 12
#define KSEL 16
#define NEG_SLOPE 0.2f

typedef __attribute__((ext_vector_type(8))) short bf16x8;
typedef __attribute__((ext_vector_type(8))) ushort u16x8;
typedef __attribute__((ext_vector_type(4))) float f32x4;

__device__ __forceinline__ float lrelu(float x) { return x >= 0.0f ? x : NEG_SLOPE * x; }

__device__ __forceinline__ ushort f2bf(float x) {
    unsigned u = __float_as_uint(x);
    unsigned r = (u + 0x7FFFu + ((u >> 16) & 1u)) >> 16;   // RNE
    return (ushort)r;
}

// monotone f16->u16 key, packed with complemented index; self -> 0 sentinel
__device__ __forceinline__ unsigned pkkey(unsigned b, int idx, int p) {
    unsigned key = (b & 0x8000u) ? (0xFFFFu & ~b) : (b | 0x8000u);
    unsigned v = (key << 11) | (unsigned)(2047 - idx);
    return (idx == p) ? 0u : v;
}

// ---------------- device bodies (shared by fused + standalone wrappers) -------

__device__ __forceinline__ void dev_normalize(const float* __restrict__ nodes,
                                              float* __restrict__ xn,
                                              ushort* __restrict__ xh,
                                              ushort* __restrict__ xb, int blk) {
    int wave = threadIdx.x >> 6;
    int lane = threadIdx.x & 63;
    size_t pt = (size_t)blk * 4 + wave;
    const float* x = nodes + pt * NC;
    float v0 = x[lane], v1 = x[lane + 64], v2 = x[lane + 128];
    float s = v0 * v0 + v1 * v1 + v2 * v2;
    #pragma unroll
    for (int off = 32; off; off >>= 1) s += __shfl_xor(s, off, 64);
    float inv = 1.0f / fmaxf(sqrtf(s), 1e-12f);
    float f0 = v0 * inv, f1 = v1 * inv, f2 = v2 * inv;
    float* o = xn + pt * NC;
    o[lane] = f0; o[lane + 64] = f1; o[lane + 128] = f2;
    ushort* oh = xh + pt * NC;
    oh[lane] = f2bf(f0); oh[lane + 64] = f2bf(f1); oh[lane + 128] = f2bf(f2);
    ushort* ob = xb + pt * NC;
    ob[lane] = f2bf(v0); ob[lane + 64] = f2bf(v1); ob[lane + 128] = f2bf(v2);
}

// ---- kernel 1 (fused prep): normalize | w1t | w2t, branch on blockIdx -------
__global__ void __launch_bounds__(256) k_prep(const float* __restrict__ nodes,
                                              const float* __restrict__ W1,
                                              const float* __restrict__ W2,
                                              float* __restrict__ xn,
                                              ushort* __restrict__ xh,
                                              ushort* __restrict__ xb,
                                              ushort* __restrict__ w1t,
                                              ushort* __restrict__ w2t) {
    int bid = blockIdx.x;
    if (bid < NB * NP / 4) {
        dev_normalize(nodes, xn, xh, xb, bid);
    } else if (bid < NB * NP / 4 + 2 * NC * NC / 256) {
        int idx = (bid - NB * NP / 4) * 256 + threadIdx.x;
        int n = idx / NC, k = idx % NC;
        float v;
        if (n < NC) v = W1[(size_t)k * NC + n] - W1[(size_t)(k + NC) * NC + n];
        else        v = W1[(size_t)(k + NC) * NC + (n - NC)];
        w1t[idx] = f2bf(v);
    } else {
        int idx = (bid - NB * NP / 4 - 2 * NC * NC / 256) * 256 + threadIdx.x;
        int n = idx / NC, k = idx % NC;
        w2t[(size_t)n * NC + k] = f2bf(W2[(size_t)k * NC + n]);
    }
}

// ---- sim body: 128x128 tile bf16 MFMA, f16 out -------------------------------
__device__ __forceinline__ void dev_sim4(ushort (*Ah)[72], ushort (*Bh)[72],
                                         const ushort* __restrict__ xh,
                                         ushort* __restrict__ simh,
                                         int bx, int by, int bz,
                                         size_t xstride, size_t simstride) {
    const ushort* XbH = xh + (size_t)bz * xstride;
    ushort* sb = simh + (size_t)bz * simstride;
    int t = threadIdx.x;
    int w = t >> 6, l = t & 63;
    int wm = w >> 1, wn = w & 1;
    int lg = l >> 4, lr = l & 15;
    int m0 = by * 128, n0 = bx * 128;

    f32x4 acc[4][4];
    #pragma unroll
    for (int mi = 0; mi < 4; ++mi)
        #pragma unroll
        for (int ni = 0; ni < 4; ++ni)
            acc[mi][ni] = (f32x4){0.f, 0.f, 0.f, 0.f};

    int r = t >> 3, c = (t & 7) * 8;
    for (int ks = 0; ks < 3; ++ks) {
        int kb = ks * 64;
        #pragma unroll
        for (int i = 0; i < 4; ++i) {
            int row = r + 32 * i;
            *reinterpret_cast<bf16x8*>(&Ah[row][c]) =
                *reinterpret_cast<const bf16x8*>(&XbH[(size_t)(m0 + row) * NC + kb + c]);
            *reinterpret_cast<bf16x8*>(&Bh[row][c]) =
                *reinterpret_cast<const bf16x8*>(&XbH[(size_t)(n0 + row) * NC + kb + c]);
        }
        __syncthreads();
        #pragma unroll
        for (int ksub = 0; ksub < 2; ++ksub) {
            int ko = ksub * 32 + 8 * lg;
            bf16x8 af[4], bf[4];
            #pragma unroll
            for (int f = 0; f < 4; ++f) {
                af[f] = *reinterpret_cast<const bf16x8*>(&Ah[wm * 64 + f * 16 + lr][ko]);
                bf[f] = *reinterpret_cast<const bf16x8*>(&Bh[wn * 64 + f * 16 + lr][ko]);
            }
            #pragma unroll
            for (int mi = 0; mi < 4; ++mi)
                #pragma unroll
                for (int ni = 0; ni < 4; ++ni)
                    acc[mi][ni] = __builtin_amdgcn_mfma_f32_16x16x32_bf16(af[mi], bf[ni], acc[mi][ni], 0, 0, 0);
        }
        __syncthreads();
    }
    #pragma unroll
    for (int mi = 0; mi < 4; ++mi)
        #pragma unroll
        for (int j = 0; j < 4; ++j) {
            int row = m0 + wm * 64 + mi * 16 + lg * 4 + j;
            ushort* hrow = sb + (size_t)row * NP;
            #pragma unroll
            for (int ni = 0; ni < 4; ++ni) {
                __half h = __float2half(acc[mi][ni][j]);
                hrow[n0 + wn * 64 + ni * 16 + lr] = *reinterpret_cast<const ushort*>(&h);
            }
        }
}

// ---- uv body: [U'|V] = Xb @ w1t^T via MFMA; bias fused; bf16 out -------------
#define UVM 32
__device__ __forceinline__ void dev_uv2(ushort (*xs)[200],
                                        const ushort* __restrict__ xb,
                                        const ushort* __restrict__ w1t,
                                        const float* __restrict__ b1,
                                        ushort* __restrict__ up,
                                        ushort* __restrict__ vv, int blk) {
    int t = threadIdx.x;
    int w = t >> 6, l = t & 63;
    int lg = l >> 4, lr = l & 15;
    int p0 = blk * UVM;
    for (int i = t; i < UVM * 24; i += 256) {
        int row = i / 24, c = (i % 24) * 8;
        *reinterpret_cast<bf16x8*>(&xs[row][c]) =
            *reinterpret_cast<const bf16x8*>(&xb[(size_t)(p0 + row) * NC + c]);
    }
    __syncthreads();
    int n0 = w * 96;
    f32x4 acc[2][6];
    #pragma unroll
    for (int mt = 0; mt < 2; ++mt)
        #pragma unroll
        for (int nt = 0; nt < 6; ++nt)
            acc[mt][nt] = (f32x4){0.f, 0.f, 0.f, 0.f};
    #pragma unroll
    for (int ks = 0; ks < 6; ++ks) {
        bf16x8 bfr[6];
        #pragma unroll
        for (int nt = 0; nt < 6; ++nt)
            bfr[nt] = *reinterpret_cast<const bf16x8*>(
                &w1t[(size_t)(n0 + nt * 16 + lr) * NC + ks * 32 + lg * 8]);
        bf16x8 a0 = *reinterpret_cast<const bf16x8*>(&xs[lr][ks * 32 + lg * 8]);
        bf16x8 a1 = *reinterpret_cast<const bf16x8*>(&xs[16 + lr][ks * 32 + lg * 8]);
        #pragma unroll
        for (int nt = 0; nt < 6; ++nt) {
            acc[0][nt] = __builtin_amdgcn_mfma_f32_16x16x32_bf16(a0, bfr[nt], acc[0][nt], 0, 0, 0);
            acc[1][nt] = __builtin_amdgcn_mfma_f32_16x16x32_bf16(a1, bfr[nt], acc[1][nt], 0, 0, 0);
        }
    }
    bool isU = (n0 < NC);
    #pragma unroll
    for (int nt = 0; nt < 6; ++nt) {
        int col = n0 + nt * 16 + lr;
        float bb = isU ? b1[col] : 0.f;
        int ocol = isU ? col : col - NC;
        ushort* dst = isU ? up : vv;
        #pragma unroll
        for (int mt = 0; mt < 2; ++mt)
            #pragma unroll
            for (int j = 0; j < 4; ++j) {
                int pt = p0 + mt * 16 + lg * 4 + j;
                dst[(size_t)pt * NC + ocol] = f2bf(acc[mt][nt][j] + bb);
            }
    }
}

// ---- kernel 2 (fused): uv2 (blocks 0..255) | sim4 (blocks 256..1279) ---------
__global__ void __launch_bounds__(256) k_uvsim(const ushort* __restrict__ xb,
                                               const ushort* __restrict__ w1t,
                                               const float* __restrict__ b1,
                                               ushort* __restrict__ up,
                                               ushort* __restrict__ vv,
                                               const ushort* __restrict__ xh,
                                               ushort* __restrict__ simh) {
    extern __shared__ char smem[];
    if (blockIdx.x < NB * NP / UVM) {
        dev_uv2((ushort(*)[200])smem, xb, w1t, b1, up, vv, blockIdx.x);
    } else {
        int sb_ = blockIdx.x - NB * NP / UVM;
        int bz = sb_ >> 8, rem = sb_ & 255, by = rem >> 4, bx = rem & 15;
        ushort (*Ah)[72] = (ushort(*)[72])smem;
        ushort (*Bh)[72] = Ah + 128;
        dev_sim4(Ah, Bh, xh, simh, bx, by, bz, (size_t)NP * NC, (size_t)NP * NP);
    }
}

// ---- standalone wrappers (ws-frugal fallback path) ---------------------------
__global__ void __launch_bounds__(256) k_uv2(const ushort* __restrict__ xb,
                                             const ushort* __restrict__ w1t,
                                             const float* __restrict__ b1,
                                             ushort* __restrict__ up,
                                             ushort* __restrict__ vv) {
    __shared__ ushort xs[UVM][200];
    dev_uv2(xs, xb, w1t, b1, up, vv, blockIdx.x);
}

__global__ void __launch_bounds__(256) k_sim4(const ushort* __restrict__ xh,
                                              ushort* __restrict__ simh,
                                              size_t xstride, size_t simstride) {
    __shared__ ushort Ah[128][72];
    __shared__ ushort Bh[128][72];
    dev_sim4(Ah, Bh, xh, simh, blockIdx.x, blockIdx.y, blockIdx.z, xstride, simstride);
}

// rare fallback: u32 insert list depth 16 + 16 extraction rounds (forceinline:
// pointer-escape would spill h8 to scratch — R12 lesson, 33 MB WRITE_SIZE).
__device__ __forceinline__ int topk_fb(const u16x8 h8[4], int p, int lane) {
    unsigned tv[16];
    #pragma unroll
    for (int q = 0; q < 16; ++q) tv[q] = 0u;
    #pragma unroll
    for (int i = 0; i < 4; ++i)
        #pragma unroll
        for (int j = 0; j < 8; ++j) {
            unsigned v = pkkey((unsigned)(ushort)h8[i][j], lane * 8 + i * 512 + j, p);
            if (v > tv[0]) {
                bool cg[16];
                #pragma unroll
                for (int q = 0; q < 16; ++q) cg[q] = v > tv[q];
                #pragma unroll
                for (int q = 0; q < 15; ++q)
                    tv[q] = cg[q + 1] ? tv[q + 1] : (cg[q] ? v : tv[q]);
                tv[15] = cg[15] ? v : tv[15];
            }
        }
    unsigned mp = 0u;
    #pragma unroll
    for (int rr = 0; rr < 16; ++rr) {
        unsigned bv = tv[15];
        #pragma unroll
        for (int off = 1; off < 64; off <<= 1) {
            unsigned ov = __shfl_xor(bv, off, 64);
            bv = ov > bv ? ov : bv;
        }
        if ((lane >> 2) == rr) mp = bv;
        if (bv == tv[15]) {
            #pragma unroll
            for (int s = 15; s > 0; --s) tv[s] = tv[s - 1];
            tv[0] = 0u;
        }
    }
    return (mp == 0u) ? -1 : (int)(2047u - (mp & 0x7FFu));
}

// ---- selection body: one row per wave; writes 12 winners to out12 ------------
__device__ __forceinline__ void dev_topk_row(const ushort* __restrict__ sr,
                                             const float* __restrict__ xb,
                                             int p, unsigned* candw, int lane,
                                             int* out12) {
    u16x8 h8[4];
    #pragma unroll
    for (int i = 0; i < 4; ++i)
        h8[i] = *reinterpret_cast<const u16x8*>(sr + lane * 8 + i * 512);

    unsigned lmax = 0;
    #pragma unroll
    for (int i = 0; i < 4; ++i)
        #pragma unroll
        for (int j = 0; j < 8; ++j) {
            unsigned v = pkkey((unsigned)(ushort)h8[i][j], lane * 8 + i * 512 + j, p);
            lmax = v > lmax ? v : lmax;
        }

    unsigned sm = lmax;
    #pragma unroll
    for (int k = 2; k <= 64; k <<= 1) {
        #pragma unroll
        for (int j = k >> 1; j >= 1; j >>= 1) {
            unsigned ov = __shfl_xor(sm, j, 64);
            bool keep_lo = (((lane & k) != 0) == ((lane & j) == 0));
            unsigned lo = sm < ov ? sm : ov, hi = sm < ov ? ov : sm;
            sm = keep_lo ? lo : hi;
        }
    }
    unsigned theta = __shfl(sm, KSEL, 64);

    int cnt = 0;
    #pragma unroll
    for (int i = 0; i < 4; ++i)
        #pragma unroll
        for (int j = 0; j < 8; ++j)
            cnt += (pkkey((unsigned)(ushort)h8[i][j], lane * 8 + i * 512 + j, p) > theta) ? 1 : 0;
    int x = cnt;
    #pragma unroll
    for (int off = 1; off < 64; off <<= 1) {
        int y = __shfl_up(x, off, 64);
        if (lane >= off) x += y;
    }
    int excl = x - cnt;
    int total = __shfl(x, 63, 64);

    int my_q;
    if (total <= 64) {
        candw[lane] = 0u;
        asm volatile("s_waitcnt lgkmcnt(0)" ::: "memory");
        int pos = excl;
        #pragma unroll
        for (int i = 0; i < 4; ++i)
            #pragma unroll
            for (int j = 0; j < 8; ++j) {
                unsigned v = pkkey((unsigned)(ushort)h8[i][j], lane * 8 + i * 512 + j, p);
                if (v > theta) { candw[pos] = v; ++pos; }
            }
        asm volatile("s_waitcnt lgkmcnt(0)" ::: "memory");
        unsigned v = candw[lane];
        #pragma unroll
        for (int k = 2; k <= 64; k <<= 1) {
            #pragma unroll
            for (int j = k >> 1; j >= 1; j >>= 1) {
                unsigned ov = __shfl_xor(v, j, 64);
                bool keep_lo = (((lane & k) != 0) == ((lane & j) == 0));
                unsigned lo = v < ov ? v : ov, hi = v < ov ? ov : v;
                v = keep_lo ? lo : hi;
            }
        }
        unsigned mp = __shfl(v, lane >> 2, 64);
        my_q = (mp == 0u) ? -1 : (int)(2047u - (mp & 0x7FFu));
    } else {
        my_q = topk_fb(h8, p, lane);
    }

    int qa = my_q < 0 ? 0 : my_q;
    const float* cp = xb + (size_t)p * NC + (lane & 3) * 48;
    const float* cq = xb + (size_t)qa * NC + (lane & 3) * 48;
    float dot = 0.f;
    #pragma unroll
    for (int i = 0; i < 12; ++i) {
        float4 a = *reinterpret_cast<const float4*>(cp + i * 4);
        float4 bq = *reinterpret_cast<const float4*>(cq + i * 4);
        dot += a.x * bq.x + a.y * bq.y + a.z * bq.z + a.w * bq.w;
    }
    dot += __shfl_xor(dot, 1, 64);
    dot += __shfl_xor(dot, 2, 64);
    int g = lane >> 2;
    int rank = 0;
    #pragma unroll
    for (int j = 0; j < KSEL; ++j) {
        float vj = __shfl(dot, j * 4, 64);
        int   qj = __shfl(my_q, j * 4, 64);
        if (j != g && qj >= 0 && (vj > dot || (vj == dot && qj < my_q))) ++rank;
    }
    bool keep = ((lane & 3) == 0) && (my_q >= 0) && (rank < KNN);
    unsigned long long mask = __ballot(keep);
    int pos = __popcll(mask & ((1ull << lane) - 1));
    if (keep) out12[pos] = my_q;
}

// -- kernel 3 (fallback): standalone top-k ------------------------------------
__global__ void __launch_bounds__(256) k_topk7(const ushort* __restrict__ simh,
                                               const float* __restrict__ xn,
                                               int* __restrict__ knn,
                                               size_t simstride, size_t xstride) {
    __shared__ unsigned cand[4][64];
    int wv = threadIdx.x >> 6, lane = threadIdx.x & 63;
    int row = blockIdx.x * 4 + wv;
    int b = row / NP, p = row % NP;
    dev_topk_row(simh + (size_t)b * simstride + (size_t)p * NP,
                 xn + (size_t)b * xstride, p, cand[wv], lane,
                 knn + (size_t)row * KNN);
}

// ---- edge body: one point per wave ------------------------------------------
__device__ __forceinline__ bf16x8 packh2(bf16x8 u, bf16x8 v) {
    union { bf16x8 v8; ushort us[8]; } U, V, R;
    U.v8 = u; V.v8 = v;
    #pragma unroll
    for (int i = 0; i < 8; i += 2) {
        float a0 = __uint_as_float((unsigned)U.us[i] << 16)
                 + __uint_as_float((unsigned)V.us[i] << 16);
        float a1 = __uint_as_float((unsigned)U.us[i + 1] << 16)
                 + __uint_as_float((unsigned)V.us[i + 1] << 16);
        __hip_bfloat162 h2 = __float22bfloat162_rn(make_float2(lrelu(a0), lrelu(a1)));
        R.us[i]     = *reinterpret_cast<const ushort*>(&h2.x);
        R.us[i + 1] = *reinterpret_cast<const ushort*>(&h2.y);
    }
    return R.v8;
}

__device__ __forceinline__ void dev_edge_point(const ushort* __restrict__ up,
                                               const ushort* __restrict__ vv,
                                               int q0, int pt0,
                                               ushort (*w2s)[200], float* aggsw,
                                               const float* __restrict__ b2,
                                               const float* __restrict__ gamma,
                                               const float* __restrict__ beta,
                                               float* __restrict__ out,
                                               int l, int lg, int lr) {
    int b = pt0 / NP;
    const ushort* u0p = up + (size_t)pt0 * NC + 8 * lg;
    const ushort* v0p = vv + ((size_t)b * NP + q0) * NC + 8 * lg;

    f32x4 acc[12];
    #pragma unroll
    for (int nt = 0; nt < 12; ++nt) acc[nt] = (f32x4){0.f, 0.f, 0.f, 0.f};

    bf16x8 sU[2], sV[2];
#define LDST(ph, ks) do { \
        sU[ph] = *reinterpret_cast<const bf16x8*>(u0p + (ks) * 32); \
        sV[ph] = *reinterpret_cast<const bf16x8*>(v0p + (ks) * 32); \
    } while (0)

    LDST(0, 0);
    #pragma unroll
    for (int ks = 0; ks < 6; ++ks) {
        int ph = ks & 1;
        if (ks < 5) LDST(ph ^ 1, ks + 1);
        bf16x8 a0 = packh2(sU[ph], sV[ph]);
        #pragma unroll
        for (int nt = 0; nt < 12; ++nt) {
            bf16x8 bfr = *reinterpret_cast<const bf16x8*>(&w2s[nt * 16 + lr][ks * 32 + lg * 8]);
            acc[nt] = __builtin_amdgcn_mfma_f32_16x16x32_bf16(a0, bfr, acc[nt], 0, 0, 0);
        }
    }
#undef LDST

    #pragma unroll
    for (int nt = 0; nt < 12; ++nt) {
        float bb = b2[nt * 16 + lr];
        float s = 0.f;
        if (lg < 3) {
            #pragma unroll
            for (int j = 0; j < 4; ++j) s += lrelu(acc[nt][j] + bb);
        }
        s += __shfl_xor(s, 16, 64);
        s += __shfl_xor(s, 32, 64);
        if (lg == 0) aggsw[nt * 16 + lr] = s * (1.0f / KNN);
    }
    asm volatile("s_waitcnt lgkmcnt(0)" ::: "memory");

    float a0 = aggsw[l], a1 = aggsw[l + 64], a2 = aggsw[l + 128];
    float s = a0 + a1 + a2;
    #pragma unroll
    for (int off = 32; off; off >>= 1) s += __shfl_xor(s, off, 64);
    float mu = s / (float)NC;
    float d0 = a0 - mu, d1 = a1 - mu, d2 = a2 - mu;
    float vs = d0 * d0 + d1 * d1 + d2 * d2;
    #pragma unroll
    for (int off = 32; off; off >>= 1) vs += __shfl_xor(vs, off, 64);
    float rstd = 1.0f / sqrtf(vs / (float)NC + 1e-5f);
    float* o = out + (size_t)pt0 * NC;
    o[l]       = d0 * rstd * gamma[l]       + beta[l];
    o[l + 64]  = d1 * rstd * gamma[l + 64]  + beta[l + 64];
    o[l + 128] = d2 * rstd * gamma[l + 128] + beta[l + 128];
}

#define EW 16   // waves/block, 1 point each

// ---- kernel 3+5 fused: per-wave topk row -> LDS knn -> edge MLP --------------
__global__ void __launch_bounds__(1024, 4) k_topkedge(const ushort* __restrict__ simh,
                                                      const float* __restrict__ xn,
                                                      const ushort* __restrict__ up,
                                                      const ushort* __restrict__ vv,
                                                      const ushort* __restrict__ w2t,
                                                      const float* __restrict__ b2,
                                                      const float* __restrict__ gamma,
                                                      const float* __restrict__ beta,
                                                      float* __restrict__ out) {
    __shared__ ushort w2s[NC][200];    // 76.8 KB
    __shared__ float aggs[EW][NC];     // 12.3 KB
    __shared__ unsigned cand[EW][64];  // 4 KB
    __shared__ int knn_s[EW][KNN];     // 0.75 KB  -> 93.9 KB total
    int t = threadIdx.x;
    int wv = t >> 6, l = t & 63;
    int lg = l >> 4, lr = l & 15;

    int pt0 = blockIdx.x * EW + wv;
    int b = pt0 / NP, p = pt0 % NP;

    // issue W2 staging; selection below hides its latency (barrier comes after)
    for (int i = t; i < NC * 24; i += 1024) {
        int r_ = i / 24, c_ = i % 24;
        *reinterpret_cast<bf16x8*>(&w2s[r_][c_ * 8]) =
            *reinterpret_cast<const bf16x8*>(&w2t[(size_t)r_ * NC + c_ * 8]);
    }

    // selection phase (wave-local; no barrier needed)
    dev_topk_row(simh + (size_t)b * ((size_t)NP * NP) + (size_t)p * NP,
                 xn + (size_t)b * ((size_t)NP * NC), p, cand[wv], l, knn_s[wv]);

    __syncthreads();   // single barrier: drains W2 staging + knn_s writes

    int lre = l & 15; lre = lre < KNN ? lre : KNN - 1;
    int q0 = knn_s[wv][lre];
    dev_edge_point(up, vv, q0, pt0, w2s, aggs[wv], b2, gamma, beta, out, l, lg, lr);
}

// ---- standalone edge kernel (fallback path) ----------------------------------
__global__ void __launch_bounds__(1024, 4) k_edge7(const ushort* __restrict__ up,
                                                   const ushort* __restrict__ vv,
                                                   const int* __restrict__ knn,
                                                   const ushort* __restrict__ w2t,
                                                   const float* __restrict__ b2,
                                                   const float* __restrict__ gamma,
                                                   const float* __restrict__ beta,
                                                   float* __restrict__ out) {
    __shared__ ushort w2s[NC][200];
    __shared__ float aggs[EW][NC];
    int t = threadIdx.x;
    int wv = t >> 6, l = t & 63;
    int lg = l >> 4, lr = l & 15;

    int pt0 = blockIdx.x * EW + wv;
    int lre = lr < KNN ? lr : KNN - 1;
    int q0 = knn[(size_t)pt0 * KNN + lre];

    for (int i = t; i < NC * 24; i += 1024) {
        int r_ = i / 24, c_ = i % 24;
        *reinterpret_cast<bf16x8*>(&w2s[r_][c_ * 8]) =
            *reinterpret_cast<const bf16x8*>(&w2t[(size_t)r_ * NC + c_ * 8]);
    }
    __syncthreads();

    dev_edge_point(up, vv, q0, pt0, w2s, aggs[wv], b2, gamma, beta, out, l, lg, lr);
}

extern "C" void kernel_launch(void* const* d_in, const int* in_sizes, int n_in,
                              void* d_out, int out_size, void* d_ws, size_t ws_size,
                              hipStream_t stream) {
    const float* nodes = (const float*)d_in[0];
    const float* W1    = (const float*)d_in[1];
    const float* b1    = (const float*)d_in[2];
    const float* W2    = (const float*)d_in[3];
    const float* b2    = (const float*)d_in[4];
    const float* gamma = (const float*)d_in[5];
    const float* beta  = (const float*)d_in[6];
    float* out = (float*)d_out;

    const size_t BPC = (size_t)NB * NP * NC;
    float*  xn  = (float*)d_ws;                        // B*P*C f32
    ushort* up  = (ushort*)(xn + BPC);                 // B*P*C bf16
    ushort* vv  = up + BPC;                            // B*P*C bf16
    ushort* xh  = vv + BPC;                            // B*P*C bf16 (normalized)
    ushort* xb  = xh + BPC;                            // B*P*C bf16 (raw)
    int*    knn = (int*)(xb + BPC);                    // B*P*K (fallback only)
    ushort* w2t = (ushort*)(knn + (size_t)NB * NP * KNN); // C*C bf16
    ushort* w1t = w2t + (size_t)NC * NC;               // 2C*C bf16
    ushort* simh = (ushort*)(((uintptr_t)(w1t + (size_t)2 * NC * NC) + 15) & ~(uintptr_t)15);

    size_t fixed_bytes = (size_t)((char*)simh - (char*)d_ws);
    bool full = ws_size >= fixed_bytes + (size_t)NB * NP * NP * 2;

    int prep_grid = NB * NP / 4 + 2 * NC * NC / 256 + NC * NC / 256;   // 2048+288+144
    k_prep<<<prep_grid, 256, 0, stream>>>(nodes, W1, W2, xn, xh, xb, w1t, w2t);
    if (full) {
        k_uvsim<<<NB * NP / UVM + 16 * NB * (NP / 128), 256, 36864, stream>>>(
            xb, w1t, b1, up, vv, xh, simh);
        k_topkedge<<<NB * NP / EW, 1024, 0, stream>>>(simh, xn, up, vv, w2t,
                                                      b2, gamma, beta, out);
    } else {
        k_uv2<<<NB * NP / UVM, 256, 0, stream>>>(xb, w1t, b1, up, vv);
        for (int b = 0; b < NB; ++b) {
            k_sim4<<<dim3(NP / 128, NP / 128, 1), 256, 0, stream>>>(xh + (size_t)b * NP * NC, simh, 0, 0);
            k_topk7<<<NP / 4, 256, 0, stream>>>(simh, xn + (size_t)b * NP * NC,
                                                knn + (size_t)b * NP * KNN, 0, 0);
        }
        k_edge7<<<NB * NP / EW, 1024, 0, stream>>>(up, vv, knn, w2t, b2, gamma, beta, out);
    }
}

// Round 18
// 81.944 us; speedup vs baseline: 1.4838x; 1.0011x over previous
//
#include <hip/hip_runtime.h>
#include <hip/hip_bf16.h>
#include <hip/hip_fp16.h>
#include <math.h>

#define NB 4
#define NP 2048
#define NC 192
#define KNN 12
#define KSEL 16
#define NEG_SLOPE 0.2f

typedef __attribute__((ext_vector_type(8))) short bf16x8;
typedef __attribute__((ext_vector_type(8))) ushort u16x8;
typedef __attribute__((ext_vector_type(4))) float f32x4;

__device__ __forceinline__ float lrelu(float x) { return x >= 0.0f ? x : NEG_SLOPE * x; }

__device__ __forceinline__ ushort f2bf(float x) {
    unsigned u = __float_as_uint(x);
    unsigned r = (u + 0x7FFFu + ((u >> 16) & 1u)) >> 16;   // RNE
    return (ushort)r;
}

// monotone f16->u16 key, packed with complemented index; self -> 0 sentinel
__device__ __forceinline__ unsigned pkkey(unsigned b, int idx, int p) {
    unsigned key = (b & 0x8000u) ? (0xFFFFu & ~b) : (b | 0x8000u);
    unsigned v = (key << 11) | (unsigned)(2047 - idx);
    return (idx == p) ? 0u : v;
}

// ---------------- device bodies (shared by fused + standalone wrappers) -------

__device__ __forceinline__ void dev_normalize(const float* __restrict__ nodes,
                                              float* __restrict__ xn,
                                              ushort* __restrict__ xh,
                                              ushort* __restrict__ xb, int blk) {
    int wave = threadIdx.x >> 6;
    int lane = threadIdx.x & 63;
    size_t pt = (size_t)blk * 4 + wave;
    const float* x = nodes + pt * NC;
    float v0 = x[lane], v1 = x[lane + 64], v2 = x[lane + 128];
    float s = v0 * v0 + v1 * v1 + v2 * v2;
    #pragma unroll
    for (int off = 32; off; off >>= 1) s += __shfl_xor(s, off, 64);
    float inv = 1.0f / fmaxf(sqrtf(s), 1e-12f);
    float f0 = v0 * inv, f1 = v1 * inv, f2 = v2 * inv;
    float* o = xn + pt * NC;
    o[lane] = f0; o[lane + 64] = f1; o[lane + 128] = f2;
    ushort* oh = xh + pt * NC;
    oh[lane] = f2bf(f0); oh[lane + 64] = f2bf(f1); oh[lane + 128] = f2bf(f2);
    ushort* ob = xb + pt * NC;
    ob[lane] = f2bf(v0); ob[lane + 64] = f2bf(v1); ob[lane + 128] = f2bf(v2);
}

// ---- kernel 1 (fused prep): normalize | w1t | w2t, branch on blockIdx -------
__global__ void __launch_bounds__(256) k_prep(const float* __restrict__ nodes,
                                              const float* __restrict__ W1,
                                              const float* __restrict__ W2,
                                              float* __restrict__ xn,
                                              ushort* __restrict__ xh,
                                              ushort* __restrict__ xb,
                                              ushort* __restrict__ w1t,
                                              ushort* __restrict__ w2t) {
    int bid = blockIdx.x;
    if (bid < NB * NP / 4) {
        dev_normalize(nodes, xn, xh, xb, bid);
    } else if (bid < NB * NP / 4 + 2 * NC * NC / 256) {
        int idx = (bid - NB * NP / 4) * 256 + threadIdx.x;
        int n = idx / NC, k = idx % NC;
        float v;
        if (n < NC) v = W1[(size_t)k * NC + n] - W1[(size_t)(k + NC) * NC + n];
        else        v = W1[(size_t)(k + NC) * NC + (n - NC)];
        w1t[idx] = f2bf(v);
    } else {
        int idx = (bid - NB * NP / 4 - 2 * NC * NC / 256) * 256 + threadIdx.x;
        int n = idx / NC, k = idx % NC;
        w2t[(size_t)n * NC + k] = f2bf(W2[(size_t)k * NC + n]);
    }
}

// ---- sim body: 128x128 tile bf16 MFMA, f16 out -------------------------------
__device__ __forceinline__ void dev_sim4(ushort (*Ah)[72], ushort (*Bh)[72],
                                         const ushort* __restrict__ xh,
                                         ushort* __restrict__ simh,
                                         int bx, int by, int bz,
                                         size_t xstride, size_t simstride) {
    const ushort* XbH = xh + (size_t)bz * xstride;
    ushort* sb = simh + (size_t)bz * simstride;
    int t = threadIdx.x;
    int w = t >> 6, l = t & 63;
    int wm = w >> 1, wn = w & 1;
    int lg = l >> 4, lr = l & 15;
    int m0 = by * 128, n0 = bx * 128;

    f32x4 acc[4][4];
    #pragma unroll
    for (int mi = 0; mi < 4; ++mi)
        #pragma unroll
        for (int ni = 0; ni < 4; ++ni)
            acc[mi][ni] = (f32x4){0.f, 0.f, 0.f, 0.f};

    int r = t >> 3, c = (t & 7) * 8;
    for (int ks = 0; ks < 3; ++ks) {
        int kb = ks * 64;
        #pragma unroll
        for (int i = 0; i < 4; ++i) {
            int row = r + 32 * i;
            *reinterpret_cast<bf16x8*>(&Ah[row][c]) =
                *reinterpret_cast<const bf16x8*>(&XbH[(size_t)(m0 + row) * NC + kb + c]);
            *reinterpret_cast<bf16x8*>(&Bh[row][c]) =
                *reinterpret_cast<const bf16x8*>(&XbH[(size_t)(n0 + row) * NC + kb + c]);
        }
        __syncthreads();
        #pragma unroll
        for (int ksub = 0; ksub < 2; ++ksub) {
            int ko = ksub * 32 + 8 * lg;
            bf16x8 af[4], bf[4];
            #pragma unroll
            for (int f = 0; f < 4; ++f) {
                af[f] = *reinterpret_cast<const bf16x8*>(&Ah[wm * 64 + f * 16 + lr][ko]);
                bf[f] = *reinterpret_cast<const bf16x8*>(&Bh[wn * 64 + f * 16 + lr][ko]);
            }
            #pragma unroll
            for (int mi = 0; mi < 4; ++mi)
                #pragma unroll
                for (int ni = 0; ni < 4; ++ni)
                    acc[mi][ni] = __builtin_amdgcn_mfma_f32_16x16x32_bf16(af[mi], bf[ni], acc[mi][ni], 0, 0, 0);
        }
        __syncthreads();
    }
    #pragma unroll
    for (int mi = 0; mi < 4; ++mi)
        #pragma unroll
        for (int j = 0; j < 4; ++j) {
            int row = m0 + wm * 64 + mi * 16 + lg * 4 + j;
            ushort* hrow = sb + (size_t)row * NP;
            #pragma unroll
            for (int ni = 0; ni < 4; ++ni) {
                __half h = __float2half(acc[mi][ni][j]);
                hrow[n0 + wn * 64 + ni * 16 + lr] = *reinterpret_cast<const ushort*>(&h);
            }
        }
}

// ---- uv body: [U'|V] = Xb @ w1t^T via MFMA; bias fused; bf16 out -------------
#define UVM 32
__device__ __forceinline__ void dev_uv2(ushort (*xs)[200],
                                        const ushort* __restrict__ xb,
                                        const ushort* __restrict__ w1t,
                                        const float* __restrict__ b1,
                                        ushort* __restrict__ up,
                                        ushort* __restrict__ vv, int blk) {
    int t = threadIdx.x;
    int w = t >> 6, l = t & 63;
    int lg = l >> 4, lr = l & 15;
    int p0 = blk * UVM;
    for (int i = t; i < UVM * 24; i += 256) {
        int row = i / 24, c = (i % 24) * 8;
        *reinterpret_cast<bf16x8*>(&xs[row][c]) =
            *reinterpret_cast<const bf16x8*>(&xb[(size_t)(p0 + row) * NC + c]);
    }
    __syncthreads();
    int n0 = w * 96;
    f32x4 acc[2][6];
    #pragma unroll
    for (int mt = 0; mt < 2; ++mt)
        #pragma unroll
        for (int nt = 0; nt < 6; ++nt)
            acc[mt][nt] = (f32x4){0.f, 0.f, 0.f, 0.f};
    #pragma unroll
    for (int ks = 0; ks < 6; ++ks) {
        bf16x8 bfr[6];
        #pragma unroll
        for (int nt = 0; nt < 6; ++nt)
            bfr[nt] = *reinterpret_cast<const bf16x8*>(
                &w1t[(size_t)(n0 + nt * 16 + lr) * NC + ks * 32 + lg * 8]);
        bf16x8 a0 = *reinterpret_cast<const bf16x8*>(&xs[lr][ks * 32 + lg * 8]);
        bf16x8 a1 = *reinterpret_cast<const bf16x8*>(&xs[16 + lr][ks * 32 + lg * 8]);
        #pragma unroll
        for (int nt = 0; nt < 6; ++nt) {
            acc[0][nt] = __builtin_amdgcn_mfma_f32_16x16x32_bf16(a0, bfr[nt], acc[0][nt], 0, 0, 0);
            acc[1][nt] = __builtin_amdgcn_mfma_f32_16x16x32_bf16(a1, bfr[nt], acc[1][nt], 0, 0, 0);
        }
    }
    bool isU = (n0 < NC);
    #pragma unroll
    for (int nt = 0; nt < 6; ++nt) {
        int col = n0 + nt * 16 + lr;
        float bb = isU ? b1[col] : 0.f;
        int ocol = isU ? col : col - NC;
        ushort* dst = isU ? up : vv;
        #pragma unroll
        for (int mt = 0; mt < 2; ++mt)
            #pragma unroll
            for (int j = 0; j < 4; ++j) {
                int pt = p0 + mt * 16 + lg * 4 + j;
                dst[(size_t)pt * NC + ocol] = f2bf(acc[mt][nt][j] + bb);
            }
    }
}

// ---- kernel 2 (fused): uv2 (blocks 0..255) | sim4 (blocks 256..1279) ---------
__global__ void __launch_bounds__(256) k_uvsim(const ushort* __restrict__ xb,
                                               const ushort* __restrict__ w1t,
                                               const float* __restrict__ b1,
                                               ushort* __restrict__ up,
                                               ushort* __restrict__ vv,
                                               const ushort* __restrict__ xh,
                                               ushort* __restrict__ simh) {
    extern __shared__ char smem[];
    if (blockIdx.x < NB * NP / UVM) {
        dev_uv2((ushort(*)[200])smem, xb, w1t, b1, up, vv, blockIdx.x);
    } else {
        int sb_ = blockIdx.x - NB * NP / UVM;
        int bz = sb_ >> 8, rem = sb_ & 255, by = rem >> 4, bx = rem & 15;
        ushort (*Ah)[72] = (ushort(*)[72])smem;
        ushort (*Bh)[72] = Ah + 128;
        dev_sim4(Ah, Bh, xh, simh, bx, by, bz, (size_t)NP * NC, (size_t)NP * NP);
    }
}

// ---- standalone wrappers (ws-frugal fallback path) ---------------------------
__global__ void __launch_bounds__(256) k_uv2(const ushort* __restrict__ xb,
                                             const ushort* __restrict__ w1t,
                                             const float* __restrict__ b1,
                                             ushort* __restrict__ up,
                                             ushort* __restrict__ vv) {
    __shared__ ushort xs[UVM][200];
    dev_uv2(xs, xb, w1t, b1, up, vv, blockIdx.x);
}

__global__ void __launch_bounds__(256) k_sim4(const ushort* __restrict__ xh,
                                              ushort* __restrict__ simh,
                                              size_t xstride, size_t simstride) {
    __shared__ ushort Ah[128][72];
    __shared__ ushort Bh[128][72];
    dev_sim4(Ah, Bh, xh, simh, blockIdx.x, blockIdx.y, blockIdx.z, xstride, simstride);
}

// rare fallback: u32 insert list depth 16 + 16 extraction rounds (forceinline:
// pointer-escape would spill h8 to scratch — R12 lesson, 33 MB WRITE_SIZE).
__device__ __forceinline__ int topk_fb(const u16x8 h8[4], int p, int lane) {
    unsigned tv[16];
    #pragma unroll
    for (int q = 0; q < 16; ++q) tv[q] = 0u;
    #pragma unroll
    for (int i = 0; i < 4; ++i)
        #pragma unroll
        for (int j = 0; j < 8; ++j) {
            unsigned v = pkkey((unsigned)(ushort)h8[i][j], lane * 8 + i * 512 + j, p);
            if (v > tv[0]) {
                bool cg[16];
                #pragma unroll
                for (int q = 0; q < 16; ++q) cg[q] = v > tv[q];
                #pragma unroll
                for (int q = 0; q < 15; ++q)
                    tv[q] = cg[q + 1] ? tv[q + 1] : (cg[q] ? v : tv[q]);
                tv[15] = cg[15] ? v : tv[15];
            }
        }
    unsigned mp = 0u;
    #pragma unroll
    for (int rr = 0; rr < 16; ++rr) {
        unsigned bv = tv[15];
        #pragma unroll
        for (int off = 1; off < 64; off <<= 1) {
            unsigned ov = __shfl_xor(bv, off, 64);
            bv = ov > bv ? ov : bv;
        }
        if ((lane >> 2) == rr) mp = bv;
        if (bv == tv[15]) {
            #pragma unroll
            for (int s = 15; s > 0; --s) tv[s] = tv[s - 1];
            tv[0] = 0u;
        }
    }
    return (mp == 0u) ? -1 : (int)(2047u - (mp & 0x7FFu));
}

// ---- selection body: one row per wave; writes 12 winners to out12 ------------
__device__ __forceinline__ void dev_topk_row(const ushort* __restrict__ sr,
                                             const float* __restrict__ xb,
                                             int p, unsigned* candw, int lane,
                                             int* out12) {
    u16x8 h8[4];
    #pragma unroll
    for (int i = 0; i < 4; ++i)
        h8[i] = *reinterpret_cast<const u16x8*>(sr + lane * 8 + i * 512);

    unsigned lmax = 0;
    #pragma unroll
    for (int i = 0; i < 4; ++i)
        #pragma unroll
        for (int j = 0; j < 8; ++j) {
            unsigned v = pkkey((unsigned)(ushort)h8[i][j], lane * 8 + i * 512 + j, p);
            lmax = v > lmax ? v : lmax;
        }

    unsigned sm = lmax;
    #pragma unroll
    for (int k = 2; k <= 64; k <<= 1) {
        #pragma unroll
        for (int j = k >> 1; j >= 1; j >>= 1) {
            unsigned ov = __shfl_xor(sm, j, 64);
            bool keep_lo = (((lane & k) != 0) == ((lane & j) == 0));
            unsigned lo = sm < ov ? sm : ov, hi = sm < ov ? ov : sm;
            sm = keep_lo ? lo : hi;
        }
    }
    unsigned theta = __shfl(sm, KSEL, 64);

    int cnt = 0;
    #pragma unroll
    for (int i = 0; i < 4; ++i)
        #pragma unroll
        for (int j = 0; j < 8; ++j)
            cnt += (pkkey((unsigned)(ushort)h8[i][j], lane * 8 + i * 512 + j, p) > theta) ? 1 : 0;
    int x = cnt;
    #pragma unroll
    for (int off = 1; off < 64; off <<= 1) {
        int y = __shfl_up(x, off, 64);
        if (lane >= off) x += y;
    }
    int excl = x - cnt;
    int total = __shfl(x, 63, 64);

    int my_q;
    if (total <= 64) {
        candw[lane] = 0u;
        asm volatile("s_waitcnt lgkmcnt(0)" ::: "memory");
        int pos = excl;
        #pragma unroll
        for (int i = 0; i < 4; ++i)
            #pragma unroll
            for (int j = 0; j < 8; ++j) {
                unsigned v = pkkey((unsigned)(ushort)h8[i][j], lane * 8 + i * 512 + j, p);
                if (v > theta) { candw[pos] = v; ++pos; }
            }
        asm volatile("s_waitcnt lgkmcnt(0)" ::: "memory");
        unsigned v = candw[lane];
        #pragma unroll
        for (int k = 2; k <= 64; k <<= 1) {
            #pragma unroll
            for (int j = k >> 1; j >= 1; j >>= 1) {
                unsigned ov = __shfl_xor(v, j, 64);
                bool keep_lo = (((lane & k) != 0) == ((lane & j) == 0));
                unsigned lo = v < ov ? v : ov, hi = v < ov ? ov : v;
                v = keep_lo ? lo : hi;
            }
        }
        unsigned mp = __shfl(v, lane >> 2, 64);
        my_q = (mp == 0u) ? -1 : (int)(2047u - (mp & 0x7FFu));
    } else {
        my_q = topk_fb(h8, p, lane);
    }

    int qa = my_q < 0 ? 0 : my_q;
    const float* cp = xb + (size_t)p * NC + (lane & 3) * 48;
    const float* cq = xb + (size_t)qa * NC + (lane & 3) * 48;
    float dot = 0.f;
    #pragma unroll
    for (int i = 0; i < 12; ++i) {
        float4 a = *reinterpret_cast<const float4*>(cp + i * 4);
        float4 bq = *reinterpret_cast<const float4*>(cq + i * 4);
        dot += a.x * bq.x + a.y * bq.y + a.z * bq.z + a.w * bq.w;
    }
    dot += __shfl_xor(dot, 1, 64);
    dot += __shfl_xor(dot, 2, 64);
    int g = lane >> 2;
    int rank = 0;
    #pragma unroll
    for (int j = 0; j < KSEL; ++j) {
        float vj = __shfl(dot, j * 4, 64);
        int   qj = __shfl(my_q, j * 4, 64);
        if (j != g && qj >= 0 && (vj > dot || (vj == dot && qj < my_q))) ++rank;
    }
    bool keep = ((lane & 3) == 0) && (my_q >= 0) && (rank < KNN);
    unsigned long long mask = __ballot(keep);
    int pos = __popcll(mask & ((1ull << lane) - 1));
    if (keep) out12[pos] = my_q;
}

// -- kernel 3 (fallback): standalone top-k ------------------------------------
__global__ void __launch_bounds__(256) k_topk7(const ushort* __restrict__ simh,
                                               const float* __restrict__ xn,
                                               int* __restrict__ knn,
                                               size_t simstride, size_t xstride) {
    __shared__ unsigned cand[4][64];
    int wv = threadIdx.x >> 6, lane = threadIdx.x & 63;
    int row = blockIdx.x * 4 + wv;
    int b = row / NP, p = row % NP;
    dev_topk_row(simh + (size_t)b * simstride + (size_t)p * NP,
                 xn + (size_t)b * xstride, p, cand[wv], lane,
                 knn + (size_t)row * KNN);
}

// ---- edge body: one point per wave; 3-deep gather prefetch ring --------------
__device__ __forceinline__ bf16x8 packh2(bf16x8 u, bf16x8 v) {
    union { bf16x8 v8; ushort us[8]; } U, V, R;
    U.v8 = u; V.v8 = v;
    #pragma unroll
    for (int i = 0; i < 8; i += 2) {
        float a0 = __uint_as_float((unsigned)U.us[i] << 16)
                 + __uint_as_float((unsigned)V.us[i] << 16);
        float a1 = __uint_as_float((unsigned)U.us[i + 1] << 16)
                 + __uint_as_float((unsigned)V.us[i + 1] << 16);
        __hip_bfloat162 h2 = __float22bfloat162_rn(make_float2(lrelu(a0), lrelu(a1)));
        R.us[i]     = *reinterpret_cast<const ushort*>(&h2.x);
        R.us[i + 1] = *reinterpret_cast<const ushort*>(&h2.y);
    }
    return R.v8;
}

__device__ __forceinline__ void dev_edge_point(const ushort* __restrict__ up,
                                               const ushort* __restrict__ vv,
                                               int q0, int pt0,
                                               ushort (*w2s)[200], float* aggsw,
                                               const float* __restrict__ b2,
                                               const float* __restrict__ gamma,
                                               const float* __restrict__ beta,
                                               float* __restrict__ out,
                                               int l, int lg, int lr) {
    int b = pt0 / NP;
    const ushort* u0p = up + (size_t)pt0 * NC + 8 * lg;
    const ushort* v0p = vv + ((size_t)b * NP + q0) * NC + 8 * lg;

    f32x4 acc[12];
    #pragma unroll
    for (int nt = 0; nt < 12; ++nt) acc[nt] = (f32x4){0.f, 0.f, 0.f, 0.f};

    // 3-slot ring, 3 iterations of lookahead: issue-to-use distance
    // ~3x(pack + 12 MFMA) >> L2 latency.
    bf16x8 sU[3], sV[3];
#define LDST(ph, ks) do { \
        sU[ph] = *reinterpret_cast<const bf16x8*>(u0p + (ks) * 32); \
        sV[ph] = *reinterpret_cast<const bf16x8*>(v0p + (ks) * 32); \
    } while (0)

    LDST(0, 0); LDST(1, 1); LDST(2, 2);
    #pragma unroll
    for (int ks = 0; ks < 6; ++ks) {
        int ph = ks % 3;
        bf16x8 a0 = packh2(sU[ph], sV[ph]);
        if (ks < 3) LDST(ph, ks + 3);   // refill slot for ks+3
        #pragma unroll
        for (int nt = 0; nt < 12; ++nt) {
            bf16x8 bfr = *reinterpret_cast<const bf16x8*>(&w2s[nt * 16 + lr][ks * 32 + lg * 8]);
            acc[nt] = __builtin_amdgcn_mfma_f32_16x16x32_bf16(a0, bfr, acc[nt], 0, 0, 0);
        }
    }
#undef LDST

    #pragma unroll
    for (int nt = 0; nt < 12; ++nt) {
        float bb = b2[nt * 16 + lr];
        float s = 0.f;
        if (lg < 3) {
            #pragma unroll
            for (int j = 0; j < 4; ++j) s += lrelu(acc[nt][j] + bb);
        }
        s += __shfl_xor(s, 16, 64);
        s += __shfl_xor(s, 32, 64);
        if (lg == 0) aggsw[nt * 16 + lr] = s * (1.0f / KNN);
    }
    asm volatile("s_waitcnt lgkmcnt(0)" ::: "memory");

    float a0 = aggsw[l], a1 = aggsw[l + 64], a2 = aggsw[l + 128];
    float s = a0 + a1 + a2;
    #pragma unroll
    for (int off = 32; off; off >>= 1) s += __shfl_xor(s, off, 64);
    float mu = s / (float)NC;
    float d0 = a0 - mu, d1 = a1 - mu, d2 = a2 - mu;
    float vs = d0 * d0 + d1 * d1 + d2 * d2;
    #pragma unroll
    for (int off = 32; off; off >>= 1) vs += __shfl_xor(vs, off, 64);
    float rstd = 1.0f / sqrtf(vs / (float)NC + 1e-5f);
    float* o = out + (size_t)pt0 * NC;
    o[l]       = d0 * rstd * gamma[l]       + beta[l];
    o[l + 64]  = d1 * rstd * gamma[l + 64]  + beta[l + 64];
    o[l + 128] = d2 * rstd * gamma[l + 128] + beta[l + 128];
}

#define EW 16   // waves/block, 1 point each

// ---- kernel 3+5 fused: per-wave topk row -> LDS knn -> edge MLP --------------
__global__ void __launch_bounds__(1024, 4) k_topkedge(const ushort* __restrict__ simh,
                                                      const float* __restrict__ xn,
                                                      const ushort* __restrict__ up,
                                                      const ushort* __restrict__ vv,
                                                      const ushort* __restrict__ w2t,
                                                      const float* __restrict__ b2,
                                                      const float* __restrict__ gamma,
                                                      const float* __restrict__ beta,
                                                      float* __restrict__ out) {
    __shared__ ushort w2s[NC][200];    // 76.8 KB
    __shared__ float aggs[EW][NC];     // 12.3 KB
    __shared__ unsigned cand[EW][64];  // 4 KB
    __shared__ int knn_s[EW][KNN];     // 0.75 KB  -> 93.9 KB total
    int t = threadIdx.x;
    int wv = t >> 6, l = t & 63;
    int lg = l >> 4, lr = l & 15;

    int pt0 = blockIdx.x * EW + wv;
    int b = pt0 / NP, p = pt0 % NP;

    // issue W2 staging; selection below hides its latency (barrier comes after)
    for (int i = t; i < NC * 24; i += 1024) {
        int r_ = i / 24, c_ = i % 24;
        *reinterpret_cast<bf16x8*>(&w2s[r_][c_ * 8]) =
            *reinterpret_cast<const bf16x8*>(&w2t[(size_t)r_ * NC + c_ * 8]);
    }

    // selection phase (wave-local; no barrier needed)
    dev_topk_row(simh + (size_t)b * ((size_t)NP * NP) + (size_t)p * NP,
                 xn + (size_t)b * ((size_t)NP * NC), p, cand[wv], l, knn_s[wv]);

    __syncthreads();   // single barrier: drains W2 staging + knn_s writes

    int lre = l & 15; lre = lre < KNN ? lre : KNN - 1;
    int q0 = knn_s[wv][lre];
    dev_edge_point(up, vv, q0, pt0, w2s, aggs[wv], b2, gamma, beta, out, l, lg, lr);
}

// ---- standalone edge kernel (fallback path) ----------------------------------
__global__ void __launch_bounds__(1024, 4) k_edge7(const ushort* __restrict__ up,
                                                   const ushort* __restrict__ vv,
                                                   const int* __restrict__ knn,
                                                   const ushort* __restrict__ w2t,
                                                   const float* __restrict__ b2,
                                                   const float* __restrict__ gamma,
                                                   const float* __restrict__ beta,
                                                   float* __restrict__ out) {
    __shared__ ushort w2s[NC][200];
    __shared__ float aggs[EW][NC];
    int t = threadIdx.x;
    int wv = t >> 6, l = t & 63;
    int lg = l >> 4, lr = l & 15;

    int pt0 = blockIdx.x * EW + wv;
    int lre = lr < KNN ? lr : KNN - 1;
    int q0 = knn[(size_t)pt0 * KNN + lre];

    for (int i = t; i < NC * 24; i += 1024) {
        int r_ = i / 24, c_ = i % 24;
        *reinterpret_cast<bf16x8*>(&w2s[r_][c_ * 8]) =
            *reinterpret_cast<const bf16x8*>(&w2t[(size_t)r_ * NC + c_ * 8]);
    }
    __syncthreads();

    dev_edge_point(up, vv, q0, pt0, w2s, aggs[wv], b2, gamma, beta, out, l, lg, lr);
}

extern "C" void kernel_launch(void* const* d_in, const int* in_sizes, int n_in,
                              void* d_out, int out_size, void* d_ws, size_t ws_size,
                              hipStream_t stream) {
    const float* nodes = (const float*)d_in[0];
    const float* W1    = (const float*)d_in[1];
    const float* b1    = (const float*)d_in[2];
    const float* W2    = (const float*)d_in[3];
    const float* b2    = (const float*)d_in[4];
    const float* gamma = (const float*)d_in[5];
    const float* beta  = (const float*)d_in[6];
    float* out = (float*)d_out;

    const size_t BPC = (size_t)NB * NP * NC;
    float*  xn  = (float*)d_ws;                        // B*P*C f32
    ushort* up  = (ushort*)(xn + BPC);                 // B*P*C bf16
    ushort* vv  = up + BPC;                            // B*P*C bf16
    ushort* xh  = vv + BPC;                            // B*P*C bf16 (normalized)
    ushort* xb  = xh + BPC;                            // B*P*C bf16 (raw)
    int*    knn = (int*)(xb + BPC);                    // B*P*K (fallback only)
    ushort* w2t = (ushort*)(knn + (size_t)NB * NP * KNN); // C*C bf16
    ushort* w1t = w2t + (size_t)NC * NC;               // 2C*C bf16
    ushort* simh = (ushort*)(((uintptr_t)(w1t + (size_t)2 * NC * NC) + 15) & ~(uintptr_t)15);

    size_t fixed_bytes = (size_t)((char*)simh - (char*)d_ws);
    bool full = ws_size >= fixed_bytes + (size_t)NB * NP * NP * 2;

    int prep_grid = NB * NP / 4 + 2 * NC * NC / 256 + NC * NC / 256;   // 2048+288+144
    k_prep<<<prep_grid, 256, 0, stream>>>(nodes, W1, W2, xn, xh, xb, w1t, w2t);
    if (full) {
        k_uvsim<<<NB * NP / UVM + 16 * NB * (NP / 128), 256, 36864, stream>>>(
            xb, w1t, b1, up, vv, xh, simh);
        k_topkedge<<<NB * NP / EW, 1024, 0, stream>>>(simh, xn, up, vv, w2t,
                                                      b2, gamma, beta, out);
    } else {
        k_uv2<<<NB * NP / UVM, 256, 0, stream>>>(xb, w1t, b1, up, vv);
        for (int b = 0; b < NB; ++b) {
            k_sim4<<<dim3(NP / 128, NP / 128, 1), 256, 0, stream>>>(xh + (size_t)b * NP * NC, simh, 0, 0);
            k_topk7<<<NP / 4, 256, 0, stream>>>(simh, xn + (size_t)b * NP * NC,
                                                knn + (size_t)b * NP * KNN, 0, 0);
        }
        k_edge7<<<NB * NP / EW, 1024, 0, stream>>>(up, vv, knn, w2t, b2, gamma, beta, out);
    }
}

// Round 19
// 79.128 us; speedup vs baseline: 1.5366x; 1.0356x over previous
//
#include <hip/hip_runtime.h>
#include <hip/hip_bf16.h>
#include <hip/hip_fp16.h>
#include <math.h>

#define NB 4
#define NP 2048
#define NC 192
#define KNN 12
#define KSEL 16
#define NEG_SLOPE 0.2f

typedef __attribute__((ext_vector_type(8))) short bf16x8;
typedef __attribute__((ext_vector_type(8))) ushort u16x8;
typedef __attribute__((ext_vector_type(4))) float f32x4;

__device__ __forceinline__ float lrelu(float x) { return x >= 0.0f ? x : NEG_SLOPE * x; }

__device__ __forceinline__ ushort f2bf(float x) {
    unsigned u = __float_as_uint(x);
    unsigned r = (u + 0x7FFFu + ((u >> 16) & 1u)) >> 16;   // RNE
    return (ushort)r;
}

// monotone f16->u16 key, packed with complemented index; self -> 0 sentinel
__device__ __forceinline__ unsigned pkkey(unsigned b, int idx, int p) {
    unsigned key = (b & 0x8000u) ? (0xFFFFu & ~b) : (b | 0x8000u);
    unsigned v = (key << 11) | (unsigned)(2047 - idx);
    return (idx == p) ? 0u : v;
}

// ---------------- device bodies (shared by fused + standalone wrappers) -------

__device__ __forceinline__ void dev_normalize(const float* __restrict__ nodes,
                                              float* __restrict__ xn,
                                              ushort* __restrict__ xh,
                                              ushort* __restrict__ xb, int blk) {
    int wave = threadIdx.x >> 6;
    int lane = threadIdx.x & 63;
    size_t pt = (size_t)blk * 4 + wave;
    const float* x = nodes + pt * NC;
    float v0 = x[lane], v1 = x[lane + 64], v2 = x[lane + 128];
    float s = v0 * v0 + v1 * v1 + v2 * v2;
    #pragma unroll
    for (int off = 32; off; off >>= 1) s += __shfl_xor(s, off, 64);
    float inv = 1.0f / fmaxf(sqrtf(s), 1e-12f);
    float f0 = v0 * inv, f1 = v1 * inv, f2 = v2 * inv;
    float* o = xn + pt * NC;
    o[lane] = f0; o[lane + 64] = f1; o[lane + 128] = f2;
    ushort* oh = xh + pt * NC;
    oh[lane] = f2bf(f0); oh[lane + 64] = f2bf(f1); oh[lane + 128] = f2bf(f2);
    ushort* ob = xb + pt * NC;
    ob[lane] = f2bf(v0); ob[lane + 64] = f2bf(v1); ob[lane + 128] = f2bf(v2);
}

// ---- kernel 1 (fused prep): normalize | w1t | w2t, branch on blockIdx -------
__global__ void __launch_bounds__(256) k_prep(const float* __restrict__ nodes,
                                              const float* __restrict__ W1,
                                              const float* __restrict__ W2,
                                              float* __restrict__ xn,
                                              ushort* __restrict__ xh,
                                              ushort* __restrict__ xb,
                                              ushort* __restrict__ w1t,
                                              ushort* __restrict__ w2t) {
    int bid = blockIdx.x;
    if (bid < NB * NP / 4) {
        dev_normalize(nodes, xn, xh, xb, bid);
    } else if (bid < NB * NP / 4 + 2 * NC * NC / 256) {
        int idx = (bid - NB * NP / 4) * 256 + threadIdx.x;
        int n = idx / NC, k = idx % NC;
        float v;
        if (n < NC) v = W1[(size_t)k * NC + n] - W1[(size_t)(k + NC) * NC + n];
        else        v = W1[(size_t)(k + NC) * NC + (n - NC)];
        w1t[idx] = f2bf(v);
    } else {
        int idx = (bid - NB * NP / 4 - 2 * NC * NC / 256) * 256 + threadIdx.x;
        int n = idx / NC, k = idx % NC;
        w2t[(size_t)n * NC + k] = f2bf(W2[(size_t)k * NC + n]);
    }
}

// ---- sim body: 128x128 tile bf16 MFMA, f16 out -------------------------------
__device__ __forceinline__ void dev_sim4(ushort (*Ah)[72], ushort (*Bh)[72],
                                         const ushort* __restrict__ xh,
                                         ushort* __restrict__ simh,
                                         int bx, int by, int bz,
                                         size_t xstride, size_t simstride) {
    const ushort* XbH = xh + (size_t)bz * xstride;
    ushort* sb = simh + (size_t)bz * simstride;
    int t = threadIdx.x;
    int w = t >> 6, l = t & 63;
    int wm = w >> 1, wn = w & 1;
    int lg = l >> 4, lr = l & 15;
    int m0 = by * 128, n0 = bx * 128;

    f32x4 acc[4][4];
    #pragma unroll
    for (int mi = 0; mi < 4; ++mi)
        #pragma unroll
        for (int ni = 0; ni < 4; ++ni)
            acc[mi][ni] = (f32x4){0.f, 0.f, 0.f, 0.f};

    int r = t >> 3, c = (t & 7) * 8;
    for (int ks = 0; ks < 3; ++ks) {
        int kb = ks * 64;
        #pragma unroll
        for (int i = 0; i < 4; ++i) {
            int row = r + 32 * i;
            *reinterpret_cast<bf16x8*>(&Ah[row][c]) =
                *reinterpret_cast<const bf16x8*>(&XbH[(size_t)(m0 + row) * NC + kb + c]);
            *reinterpret_cast<bf16x8*>(&Bh[row][c]) =
                *reinterpret_cast<const bf16x8*>(&XbH[(size_t)(n0 + row) * NC + kb + c]);
        }
        __syncthreads();
        #pragma unroll
        for (int ksub = 0; ksub < 2; ++ksub) {
            int ko = ksub * 32 + 8 * lg;
            bf16x8 af[4], bf[4];
            #pragma unroll
            for (int f = 0; f < 4; ++f) {
                af[f] = *reinterpret_cast<const bf16x8*>(&Ah[wm * 64 + f * 16 + lr][ko]);
                bf[f] = *reinterpret_cast<const bf16x8*>(&Bh[wn * 64 + f * 16 + lr][ko]);
            }
            #pragma unroll
            for (int mi = 0; mi < 4; ++mi)
                #pragma unroll
                for (int ni = 0; ni < 4; ++ni)
                    acc[mi][ni] = __builtin_amdgcn_mfma_f32_16x16x32_bf16(af[mi], bf[ni], acc[mi][ni], 0, 0, 0);
        }
        __syncthreads();
    }
    #pragma unroll
    for (int mi = 0; mi < 4; ++mi)
        #pragma unroll
        for (int j = 0; j < 4; ++j) {
            int row = m0 + wm * 64 + mi * 16 + lg * 4 + j;
            ushort* hrow = sb + (size_t)row * NP;
            #pragma unroll
            for (int ni = 0; ni < 4; ++ni) {
                __half h = __float2half(acc[mi][ni][j]);
                hrow[n0 + wn * 64 + ni * 16 + lr] = *reinterpret_cast<const ushort*>(&h);
            }
        }
}

// ---- uv body: [U'|V] = Xb @ w1t^T via MFMA; bias fused; bf16 out -------------
#define UVM 32
__device__ __forceinline__ void dev_uv2(ushort (*xs)[200],
                                        const ushort* __restrict__ xb,
                                        const ushort* __restrict__ w1t,
                                        const float* __restrict__ b1,
                                        ushort* __restrict__ up,
                                        ushort* __restrict__ vv, int blk) {
    int t = threadIdx.x;
    int w = t >> 6, l = t & 63;
    int lg = l >> 4, lr = l & 15;
    int p0 = blk * UVM;
    for (int i = t; i < UVM * 24; i += 256) {
        int row = i / 24, c = (i % 24) * 8;
        *reinterpret_cast<bf16x8*>(&xs[row][c]) =
            *reinterpret_cast<const bf16x8*>(&xb[(size_t)(p0 + row) * NC + c]);
    }
    __syncthreads();
    int n0 = w * 96;
    f32x4 acc[2][6];
    #pragma unroll
    for (int mt = 0; mt < 2; ++mt)
        #pragma unroll
        for (int nt = 0; nt < 6; ++nt)
            acc[mt][nt] = (f32x4){0.f, 0.f, 0.f, 0.f};
    #pragma unroll
    for (int ks = 0; ks < 6; ++ks) {
        bf16x8 bfr[6];
        #pragma unroll
        for (int nt = 0; nt < 6; ++nt)
            bfr[nt] = *reinterpret_cast<const bf16x8*>(
                &w1t[(size_t)(n0 + nt * 16 + lr) * NC + ks * 32 + lg * 8]);
        bf16x8 a0 = *reinterpret_cast<const bf16x8*>(&xs[lr][ks * 32 + lg * 8]);
        bf16x8 a1 = *reinterpret_cast<const bf16x8*>(&xs[16 + lr][ks * 32 + lg * 8]);
        #pragma unroll
        for (int nt = 0; nt < 6; ++nt) {
            acc[0][nt] = __builtin_amdgcn_mfma_f32_16x16x32_bf16(a0, bfr[nt], acc[0][nt], 0, 0, 0);
            acc[1][nt] = __builtin_amdgcn_mfma_f32_16x16x32_bf16(a1, bfr[nt], acc[1][nt], 0, 0, 0);
        }
    }
    bool isU = (n0 < NC);
    #pragma unroll
    for (int nt = 0; nt < 6; ++nt) {
        int col = n0 + nt * 16 + lr;
        float bb = isU ? b1[col] : 0.f;
        int ocol = isU ? col : col - NC;
        ushort* dst = isU ? up : vv;
        #pragma unroll
        for (int mt = 0; mt < 2; ++mt)
            #pragma unroll
            for (int j = 0; j < 4; ++j) {
                int pt = p0 + mt * 16 + lg * 4 + j;
                dst[(size_t)pt * NC + ocol] = f2bf(acc[mt][nt][j] + bb);
            }
    }
}

// ---- kernel 2 (fused): uv2 (blocks 0..255) | sim4 (blocks 256..1279) ---------
__global__ void __launch_bounds__(256) k_uvsim(const ushort* __restrict__ xb,
                                               const ushort* __restrict__ w1t,
                                               const float* __restrict__ b1,
                                               ushort* __restrict__ up,
                                               ushort* __restrict__ vv,
                                               const ushort* __restrict__ xh,
                                               ushort* __restrict__ simh) {
    extern __shared__ char smem[];
    if (blockIdx.x < NB * NP / UVM) {
        dev_uv2((ushort(*)[200])smem, xb, w1t, b1, up, vv, blockIdx.x);
    } else {
        int sb_ = blockIdx.x - NB * NP / UVM;
        int bz = sb_ >> 8, rem = sb_ & 255, by = rem >> 4, bx = rem & 15;
        ushort (*Ah)[72] = (ushort(*)[72])smem;
        ushort (*Bh)[72] = Ah + 128;
        dev_sim4(Ah, Bh, xh, simh, bx, by, bz, (size_t)NP * NC, (size_t)NP * NP);
    }
}

// ---- standalone wrappers (ws-frugal fallback path) ---------------------------
__global__ void __launch_bounds__(256) k_uv2(const ushort* __restrict__ xb,
                                             const ushort* __restrict__ w1t,
                                             const float* __restrict__ b1,
                                             ushort* __restrict__ up,
                                             ushort* __restrict__ vv) {
    __shared__ ushort xs[UVM][200];
    dev_uv2(xs, xb, w1t, b1, up, vv, blockIdx.x);
}

__global__ void __launch_bounds__(256) k_sim4(const ushort* __restrict__ xh,
                                              ushort* __restrict__ simh,
                                              size_t xstride, size_t simstride) {
    __shared__ ushort Ah[128][72];
    __shared__ ushort Bh[128][72];
    dev_sim4(Ah, Bh, xh, simh, blockIdx.x, blockIdx.y, blockIdx.z, xstride, simstride);
}

// rare fallback: u32 insert list depth 16 + 16 extraction rounds (forceinline:
// pointer-escape would spill h8 to scratch — R12 lesson, 33 MB WRITE_SIZE).
__device__ __forceinline__ int topk_fb(const u16x8 h8[4], int p, int lane) {
    unsigned tv[16];
    #pragma unroll
    for (int q = 0; q < 16; ++q) tv[q] = 0u;
    #pragma unroll
    for (int i = 0; i < 4; ++i)
        #pragma unroll
        for (int j = 0; j < 8; ++j) {
            unsigned v = pkkey((unsigned)(ushort)h8[i][j], lane * 8 + i * 512 + j, p);
            if (v > tv[0]) {
                bool cg[16];
                #pragma unroll
                for (int q = 0; q < 16; ++q) cg[q] = v > tv[q];
                #pragma unroll
                for (int q = 0; q < 15; ++q)
                    tv[q] = cg[q + 1] ? tv[q + 1] : (cg[q] ? v : tv[q]);
                tv[15] = cg[15] ? v : tv[15];
            }
        }
    unsigned mp = 0u;
    #pragma unroll
    for (int rr = 0; rr < 16; ++rr) {
        unsigned bv = tv[15];
        #pragma unroll
        for (int off = 1; off < 64; off <<= 1) {
            unsigned ov = __shfl_xor(bv, off, 64);
            bv = ov > bv ? ov : bv;
        }
        if ((lane >> 2) == rr) mp = bv;
        if (bv == tv[15]) {
            #pragma unroll
            for (int s = 15; s > 0; --s) tv[s] = tv[s - 1];
            tv[0] = 0u;
        }
    }
    return (mp == 0u) ? -1 : (int)(2047u - (mp & 0x7FFu));
}

// ---- selection body: one row per wave; writes 12 winners to out12 ------------
__device__ __forceinline__ void dev_topk_row(const ushort* __restrict__ sr,
                                             const float* __restrict__ xb,
                                             int p, unsigned* candw, int lane,
                                             int* out12) {
    u16x8 h8[4];
    #pragma unroll
    for (int i = 0; i < 4; ++i)
        h8[i] = *reinterpret_cast<const u16x8*>(sr + lane * 8 + i * 512);

    unsigned lmax = 0;
    #pragma unroll
    for (int i = 0; i < 4; ++i)
        #pragma unroll
        for (int j = 0; j < 8; ++j) {
            unsigned v = pkkey((unsigned)(ushort)h8[i][j], lane * 8 + i * 512 + j, p);
            lmax = v > lmax ? v : lmax;
        }

    unsigned sm = lmax;
    #pragma unroll
    for (int k = 2; k <= 64; k <<= 1) {
        #pragma unroll
        for (int j = k >> 1; j >= 1; j >>= 1) {
            unsigned ov = __shfl_xor(sm, j, 64);
            bool keep_lo = (((lane & k) != 0) == ((lane & j) == 0));
            unsigned lo = sm < ov ? sm : ov, hi = sm < ov ? ov : sm;
            sm = keep_lo ? lo : hi;
        }
    }
    unsigned theta = __shfl(sm, KSEL, 64);

    int cnt = 0;
    #pragma unroll
    for (int i = 0; i < 4; ++i)
        #pragma unroll
        for (int j = 0; j < 8; ++j)
            cnt += (pkkey((unsigned)(ushort)h8[i][j], lane * 8 + i * 512 + j, p) > theta) ? 1 : 0;
    int x = cnt;
    #pragma unroll
    for (int off = 1; off < 64; off <<= 1) {
        int y = __shfl_up(x, off, 64);
        if (lane >= off) x += y;
    }
    int excl = x - cnt;
    int total = __shfl(x, 63, 64);

    int my_q;
    if (total <= 64) {
        candw[lane] = 0u;
        asm volatile("s_waitcnt lgkmcnt(0)" ::: "memory");
        int pos = excl;
        #pragma unroll
        for (int i = 0; i < 4; ++i)
            #pragma unroll
            for (int j = 0; j < 8; ++j) {
                unsigned v = pkkey((unsigned)(ushort)h8[i][j], lane * 8 + i * 512 + j, p);
                if (v > theta) { candw[pos] = v; ++pos; }
            }
        asm volatile("s_waitcnt lgkmcnt(0)" ::: "memory");
        unsigned v = candw[lane];
        #pragma unroll
        for (int k = 2; k <= 64; k <<= 1) {
            #pragma unroll
            for (int j = k >> 1; j >= 1; j >>= 1) {
                unsigned ov = __shfl_xor(v, j, 64);
                bool keep_lo = (((lane & k) != 0) == ((lane & j) == 0));
                unsigned lo = v < ov ? v : ov, hi = v < ov ? ov : v;
                v = keep_lo ? lo : hi;
            }
        }
        unsigned mp = __shfl(v, lane >> 2, 64);
        my_q = (mp == 0u) ? -1 : (int)(2047u - (mp & 0x7FFu));
    } else {
        my_q = topk_fb(h8, p, lane);
    }

    int qa = my_q < 0 ? 0 : my_q;
    const float* cp = xb + (size_t)p * NC + (lane & 3) * 48;
    const float* cq = xb + (size_t)qa * NC + (lane & 3) * 48;
    float dot = 0.f;
    #pragma unroll
    for (int i = 0; i < 12; ++i) {
        float4 a = *reinterpret_cast<const float4*>(cp + i * 4);
        float4 bq = *reinterpret_cast<const float4*>(cq + i * 4);
        dot += a.x * bq.x + a.y * bq.y + a.z * bq.z + a.w * bq.w;
    }
    dot += __shfl_xor(dot, 1, 64);
    dot += __shfl_xor(dot, 2, 64);
    int g = lane >> 2;
    int rank = 0;
    #pragma unroll
    for (int j = 0; j < KSEL; ++j) {
        float vj = __shfl(dot, j * 4, 64);
        int   qj = __shfl(my_q, j * 4, 64);
        if (j != g && qj >= 0 && (vj > dot || (vj == dot && qj < my_q))) ++rank;
    }
    bool keep = ((lane & 3) == 0) && (my_q >= 0) && (rank < KNN);
    unsigned long long mask = __ballot(keep);
    int pos = __popcll(mask & ((1ull << lane) - 1));
    if (keep) out12[pos] = my_q;
}

// -- kernel 3 (fallback): standalone top-k ------------------------------------
__global__ void __launch_bounds__(256) k_topk7(const ushort* __restrict__ simh,
                                               const float* __restrict__ xn,
                                               int* __restrict__ knn,
                                               size_t simstride, size_t xstride) {
    __shared__ unsigned cand[4][64];
    int wv = threadIdx.x >> 6, lane = threadIdx.x & 63;
    int row = blockIdx.x * 4 + wv;
    int b = row / NP, p = row % NP;
    dev_topk_row(simh + (size_t)b * simstride + (size_t)p * NP,
                 xn + (size_t)b * xstride, p, cand[wv], lane,
                 knn + (size_t)row * KNN);
}

// ---- edge body: one point per wave; 3-deep gather ring + setprio MFMA --------
__device__ __forceinline__ bf16x8 packh2(bf16x8 u, bf16x8 v) {
    union { bf16x8 v8; ushort us[8]; } U, V, R;
    U.v8 = u; V.v8 = v;
    #pragma unroll
    for (int i = 0; i < 8; i += 2) {
        float a0 = __uint_as_float((unsigned)U.us[i] << 16)
                 + __uint_as_float((unsigned)V.us[i] << 16);
        float a1 = __uint_as_float((unsigned)U.us[i + 1] << 16)
                 + __uint_as_float((unsigned)V.us[i + 1] << 16);
        __hip_bfloat162 h2 = __float22bfloat162_rn(make_float2(lrelu(a0), lrelu(a1)));
        R.us[i]     = *reinterpret_cast<const ushort*>(&h2.x);
        R.us[i + 1] = *reinterpret_cast<const ushort*>(&h2.y);
    }
    return R.v8;
}

__device__ __forceinline__ void dev_edge_point(const ushort* __restrict__ up,
                                               const ushort* __restrict__ vv,
                                               int q0, int pt0,
                                               ushort (*w2s)[200], float* aggsw,
                                               const float* __restrict__ b2,
                                               const float* __restrict__ gamma,
                                               const float* __restrict__ beta,
                                               float* __restrict__ out,
                                               int l, int lg, int lr) {
    int b = pt0 / NP;
    const ushort* u0p = up + (size_t)pt0 * NC + 8 * lg;
    const ushort* v0p = vv + ((size_t)b * NP + q0) * NC + 8 * lg;

    f32x4 acc[12];
    #pragma unroll
    for (int nt = 0; nt < 12; ++nt) acc[nt] = (f32x4){0.f, 0.f, 0.f, 0.f};

    bf16x8 sU[3], sV[3];
#define LDST(ph, ks) do { \
        sU[ph] = *reinterpret_cast<const bf16x8*>(u0p + (ks) * 32); \
        sV[ph] = *reinterpret_cast<const bf16x8*>(v0p + (ks) * 32); \
    } while (0)

    LDST(0, 0); LDST(1, 1); LDST(2, 2);
    #pragma unroll
    for (int ks = 0; ks < 6; ++ks) {
        int ph = ks % 3;
        bf16x8 a0 = packh2(sU[ph], sV[ph]);
        if (ks < 3) LDST(ph, ks + 3);
        __builtin_amdgcn_s_setprio(1);   // T5: favor MFMA-phase waves
        #pragma unroll
        for (int nt = 0; nt < 12; ++nt) {
            bf16x8 bfr = *reinterpret_cast<const bf16x8*>(&w2s[nt * 16 + lr][ks * 32 + lg * 8]);
            acc[nt] = __builtin_amdgcn_mfma_f32_16x16x32_bf16(a0, bfr, acc[nt], 0, 0, 0);
        }
        __builtin_amdgcn_s_setprio(0);
    }
#undef LDST

    #pragma unroll
    for (int nt = 0; nt < 12; ++nt) {
        float bb = b2[nt * 16 + lr];
        float s = 0.f;
        if (lg < 3) {
            #pragma unroll
            for (int j = 0; j < 4; ++j) s += lrelu(acc[nt][j] + bb);
        }
        s += __shfl_xor(s, 16, 64);
        s += __shfl_xor(s, 32, 64);
        if (lg == 0) aggsw[nt * 16 + lr] = s * (1.0f / KNN);
    }
    asm volatile("s_waitcnt lgkmcnt(0)" ::: "memory");

    float a0 = aggsw[l], a1 = aggsw[l + 64], a2 = aggsw[l + 128];
    float s = a0 + a1 + a2;
    #pragma unroll
    for (int off = 32; off; off >>= 1) s += __shfl_xor(s, off, 64);
    float mu = s / (float)NC;
    float d0 = a0 - mu, d1 = a1 - mu, d2 = a2 - mu;
    float vs = d0 * d0 + d1 * d1 + d2 * d2;
    #pragma unroll
    for (int off = 32; off; off >>= 1) vs += __shfl_xor(vs, off, 64);
    float rstd = 1.0f / sqrtf(vs / (float)NC + 1e-5f);
    float* o = out + (size_t)pt0 * NC;
    o[l]       = d0 * rstd * gamma[l]       + beta[l];
    o[l + 64]  = d1 * rstd * gamma[l + 64]  + beta[l + 64];
    o[l + 128] = d2 * rstd * gamma[l + 128] + beta[l + 128];
}

#define EW 16   // waves/block, 1 point each

// ---- kernel 3+5 fused: early W2 barrier, then wave-independent topk->edge ----
__global__ void __launch_bounds__(1024, 4) k_topkedge(const ushort* __restrict__ simh,
                                                      const float* __restrict__ xn,
                                                      const ushort* __restrict__ up,
                                                      const ushort* __restrict__ vv,
                                                      const ushort* __restrict__ w2t,
                                                      const float* __restrict__ b2,
                                                      const float* __restrict__ gamma,
                                                      const float* __restrict__ beta,
                                                      float* __restrict__ out) {
    __shared__ ushort w2s[NC][200];    // 76.8 KB
    __shared__ float aggs[EW][NC];     // 12.3 KB
    __shared__ unsigned cand[EW][64];  // 4 KB
    __shared__ int knn_s[EW][KNN];     // 0.75 KB
    int t = threadIdx.x;
    int wv = t >> 6, l = t & 63;
    int lg = l >> 4, lr = l & 15;

    int pt0 = blockIdx.x * EW + wv;
    int b = pt0 / NP, p = pt0 % NP;

    // W2 staging + single barrier FIRST: after this, each wave flows
    // selection -> edge independently (knn_s[wv] is wave-private; no convoy).
    for (int i = t; i < NC * 24; i += 1024) {
        int r_ = i / 24, c_ = i % 24;
        *reinterpret_cast<bf16x8*>(&w2s[r_][c_ * 8]) =
            *reinterpret_cast<const bf16x8*>(&w2t[(size_t)r_ * NC + c_ * 8]);
    }
    __syncthreads();   // only block-wide barrier (w2s visibility)

    // selection (wave-local)
    dev_topk_row(simh + (size_t)b * ((size_t)NP * NP) + (size_t)p * NP,
                 xn + (size_t)b * ((size_t)NP * NC), p, cand[wv], l, knn_s[wv]);
    asm volatile("s_waitcnt lgkmcnt(0)" ::: "memory");   // same-wave knn_s RAW

    int lre = l & 15; lre = lre < KNN ? lre : KNN - 1;
    int q0 = knn_s[wv][lre];
    dev_edge_point(up, vv, q0, pt0, w2s, aggs[wv], b2, gamma, beta, out, l, lg, lr);
}

// ---- standalone edge kernel (fallback path) ----------------------------------
__global__ void __launch_bounds__(1024, 4) k_edge7(const ushort* __restrict__ up,
                                                   const ushort* __restrict__ vv,
                                                   const int* __restrict__ knn,
                                                   const ushort* __restrict__ w2t,
                                                   const float* __restrict__ b2,
                                                   const float* __restrict__ gamma,
                                                   const float* __restrict__ beta,
                                                   float* __restrict__ out) {
    __shared__ ushort w2s[NC][200];
    __shared__ float aggs[EW][NC];
    int t = threadIdx.x;
    int wv = t >> 6, l = t & 63;
    int lg = l >> 4, lr = l & 15;

    int pt0 = blockIdx.x * EW + wv;
    int lre = lr < KNN ? lr : KNN - 1;
    int q0 = knn[(size_t)pt0 * KNN + lre];

    for (int i = t; i < NC * 24; i += 1024) {
        int r_ = i / 24, c_ = i % 24;
        *reinterpret_cast<bf16x8*>(&w2s[r_][c_ * 8]) =
            *reinterpret_cast<const bf16x8*>(&w2t[(size_t)r_ * NC + c_ * 8]);
    }
    __syncthreads();

    dev_edge_point(up, vv, q0, pt0, w2s, aggs[wv], b2, gamma, beta, out, l, lg, lr);
}

extern "C" void kernel_launch(void* const* d_in, const int* in_sizes, int n_in,
                              void* d_out, int out_size, void* d_ws, size_t ws_size,
                              hipStream_t stream) {
    const float* nodes = (const float*)d_in[0];
    const float* W1    = (const float*)d_in[1];
    const float* b1    = (const float*)d_in[2];
    const float* W2    = (const float*)d_in[3];
    const float* b2    = (const float*)d_in[4];
    const float* gamma = (const float*)d_in[5];
    const float* beta  = (const float*)d_in[6];
    float* out = (float*)d_out;

    const size_t BPC = (size_t)NB * NP * NC;
    float*  xn  = (float*)d_ws;                        // B*P*C f32
    ushort* up  = (ushort*)(xn + BPC);                 // B*P*C bf16
    ushort* vv  = up + BPC;                            // B*P*C bf16
    ushort* xh  = vv + BPC;                            // B*P*C bf16 (normalized)
    ushort* xb  = xh + BPC;                            // B*P*C bf16 (raw)
    int*    knn = (int*)(xb + BPC);                    // B*P*K (fallback only)
    ushort* w2t = (ushort*)(knn + (size_t)NB * NP * KNN); // C*C bf16
    ushort* w1t = w2t + (size_t)NC * NC;               // 2C*C bf16
    ushort* simh = (ushort*)(((uintptr_t)(w1t + (size_t)2 * NC * NC) + 15) & ~(uintptr_t)15);

    size_t fixed_bytes = (size_t)((char*)simh - (char*)d_ws);
    bool full = ws_size >= fixed_bytes + (size_t)NB * NP * NP * 2;

    int prep_grid = NB * NP / 4 + 2 * NC * NC / 256 + NC * NC / 256;   // 2048+288+144
    k_prep<<<prep_grid, 256, 0, stream>>>(nodes, W1, W2, xn, xh, xb, w1t, w2t);
    if (full) {
        k_uvsim<<<NB * NP / UVM + 16 * NB * (NP / 128), 256, 36864, stream>>>(
            xb, w1t, b1, up, vv, xh, simh);
        k_topkedge<<<NB * NP / EW, 1024, 0, stream>>>(simh, xn, up, vv, w2t,
                                                      b2, gamma, beta, out);
    } else {
        k_uv2<<<NB * NP / UVM, 256, 0, stream>>>(xb, w1t, b1, up, vv);
        for (int b = 0; b < NB; ++b) {
            k_sim4<<<dim3(NP / 128, NP / 128, 1), 256, 0, stream>>>(xh + (size_t)b * NP * NC, simh, 0, 0);
            k_topk7<<<NP / 4, 256, 0, stream>>>(simh, xn + (size_t)b * NP * NC,
                                                knn + (size_t)b * NP * KNN, 0, 0);
        }
        k_edge7<<<NB * NP / EW, 1024, 0, stream>>>(up, vv, knn, w2t, b2, gamma, beta, out);
    }
}

// Round 20
// 76.971 us; speedup vs baseline: 1.5796x; 1.0280x over previous
//
#include <hip/hip_runtime.h>
#include <hip/hip_bf16.h>
#include <hip/hip_fp16.h>
#include <math.h>

#define NB 4
#define NP 2048
#define NC 192
#define KNN 12
#define KSEL 16
#define NEG_SLOPE 0.2f

typedef __attribute__((ext_vector_type(8))) short bf16x8;
typedef __attribute__((ext_vector_type(8))) ushort u16x8;
typedef __attribute__((ext_vector_type(4))) float f32x4;

__device__ __forceinline__ float lrelu(float x) { return x >= 0.0f ? x : NEG_SLOPE * x; }

__device__ __forceinline__ ushort f2bf(float x) {
    unsigned u = __float_as_uint(x);
    unsigned r = (u + 0x7FFFu + ((u >> 16) & 1u)) >> 16;   // RNE
    return (ushort)r;
}

// monotone f16->u16 key, packed with complemented index; self -> 0 sentinel
__device__ __forceinline__ unsigned pkkey(unsigned b, int idx, int p) {
    unsigned key = (b & 0x8000u) ? (0xFFFFu & ~b) : (b | 0x8000u);
    unsigned v = (key << 11) | (unsigned)(2047 - idx);
    return (idx == p) ? 0u : v;
}

// ---------------- device bodies (shared by fused + standalone wrappers) -------

__device__ __forceinline__ void dev_normalize(const float* __restrict__ nodes,
                                              float* __restrict__ xn,
                                              ushort* __restrict__ xh,
                                              ushort* __restrict__ xb, int blk) {
    int wave = threadIdx.x >> 6;
    int lane = threadIdx.x & 63;
    size_t pt = (size_t)blk * 4 + wave;
    const float* x = nodes + pt * NC;
    float v0 = x[lane], v1 = x[lane + 64], v2 = x[lane + 128];
    float s = v0 * v0 + v1 * v1 + v2 * v2;
    #pragma unroll
    for (int off = 32; off; off >>= 1) s += __shfl_xor(s, off, 64);
    float inv = 1.0f / fmaxf(sqrtf(s), 1e-12f);
    float f0 = v0 * inv, f1 = v1 * inv, f2 = v2 * inv;
    float* o = xn + pt * NC;
    o[lane] = f0; o[lane + 64] = f1; o[lane + 128] = f2;
    ushort* oh = xh + pt * NC;
    oh[lane] = f2bf(f0); oh[lane + 64] = f2bf(f1); oh[lane + 128] = f2bf(f2);
    ushort* ob = xb + pt * NC;
    ob[lane] = f2bf(v0); ob[lane + 64] = f2bf(v1); ob[lane + 128] = f2bf(v2);
}

// ---- kernel 1 (fused prep): normalize | w1t | w2t, branch on blockIdx -------
__global__ void __launch_bounds__(256) k_prep(const float* __restrict__ nodes,
                                              const float* __restrict__ W1,
                                              const float* __restrict__ W2,
                                              float* __restrict__ xn,
                                              ushort* __restrict__ xh,
                                              ushort* __restrict__ xb,
                                              ushort* __restrict__ w1t,
                                              ushort* __restrict__ w2t) {
    int bid = blockIdx.x;
    if (bid < NB * NP / 4) {
        dev_normalize(nodes, xn, xh, xb, bid);
    } else if (bid < NB * NP / 4 + 2 * NC * NC / 256) {
        int idx = (bid - NB * NP / 4) * 256 + threadIdx.x;
        int n = idx / NC, k = idx % NC;
        float v;
        if (n < NC) v = W1[(size_t)k * NC + n] - W1[(size_t)(k + NC) * NC + n];
        else        v = W1[(size_t)(k + NC) * NC + (n - NC)];
        w1t[idx] = f2bf(v);
    } else {
        int idx = (bid - NB * NP / 4 - 2 * NC * NC / 256) * 256 + threadIdx.x;
        int n = idx / NC, k = idx % NC;
        w2t[(size_t)n * NC + k] = f2bf(W2[(size_t)k * NC + n]);
    }
}

// ---- sim body: 128x128 tile bf16 MFMA, f16 out -------------------------------
__device__ __forceinline__ void dev_sim4(ushort (*Ah)[72], ushort (*Bh)[72],
                                         const ushort* __restrict__ xh,
                                         ushort* __restrict__ simh,
                                         int bx, int by, int bz,
                                         size_t xstride, size_t simstride) {
    const ushort* XbH = xh + (size_t)bz * xstride;
    ushort* sb = simh + (size_t)bz * simstride;
    int t = threadIdx.x;
    int w = t >> 6, l = t & 63;
    int wm = w >> 1, wn = w & 1;
    int lg = l >> 4, lr = l & 15;
    int m0 = by * 128, n0 = bx * 128;

    f32x4 acc[4][4];
    #pragma unroll
    for (int mi = 0; mi < 4; ++mi)
        #pragma unroll
        for (int ni = 0; ni < 4; ++ni)
            acc[mi][ni] = (f32x4){0.f, 0.f, 0.f, 0.f};

    int r = t >> 3, c = (t & 7) * 8;
    for (int ks = 0; ks < 3; ++ks) {
        int kb = ks * 64;
        #pragma unroll
        for (int i = 0; i < 4; ++i) {
            int row = r + 32 * i;
            *reinterpret_cast<bf16x8*>(&Ah[row][c]) =
                *reinterpret_cast<const bf16x8*>(&XbH[(size_t)(m0 + row) * NC + kb + c]);
            *reinterpret_cast<bf16x8*>(&Bh[row][c]) =
                *reinterpret_cast<const bf16x8*>(&XbH[(size_t)(n0 + row) * NC + kb + c]);
        }
        __syncthreads();
        #pragma unroll
        for (int ksub = 0; ksub < 2; ++ksub) {
            int ko = ksub * 32 + 8 * lg;
            bf16x8 af[4], bf[4];
            #pragma unroll
            for (int f = 0; f < 4; ++f) {
                af[f] = *reinterpret_cast<const bf16x8*>(&Ah[wm * 64 + f * 16 + lr][ko]);
                bf[f] = *reinterpret_cast<const bf16x8*>(&Bh[wn * 64 + f * 16 + lr][ko]);
            }
            #pragma unroll
            for (int mi = 0; mi < 4; ++mi)
                #pragma unroll
                for (int ni = 0; ni < 4; ++ni)
                    acc[mi][ni] = __builtin_amdgcn_mfma_f32_16x16x32_bf16(af[mi], bf[ni], acc[mi][ni], 0, 0, 0);
        }
        __syncthreads();
    }
    #pragma unroll
    for (int mi = 0; mi < 4; ++mi)
        #pragma unroll
        for (int j = 0; j < 4; ++j) {
            int row = m0 + wm * 64 + mi * 16 + lg * 4 + j;
            ushort* hrow = sb + (size_t)row * NP;
            #pragma unroll
            for (int ni = 0; ni < 4; ++ni) {
                __half h = __float2half(acc[mi][ni][j]);
                hrow[n0 + wn * 64 + ni * 16 + lr] = *reinterpret_cast<const ushort*>(&h);
            }
        }
}

// ---- uv body: [U'|V] = Xb @ w1t^T via MFMA; bias fused; bf16 out -------------
#define UVM 32
__device__ __forceinline__ void dev_uv2(ushort (*xs)[200],
                                        const ushort* __restrict__ xb,
                                        const ushort* __restrict__ w1t,
                                        const float* __restrict__ b1,
                                        ushort* __restrict__ up,
                                        ushort* __restrict__ vv, int blk) {
    int t = threadIdx.x;
    int w = t >> 6, l = t & 63;
    int lg = l >> 4, lr = l & 15;
    int p0 = blk * UVM;
    for (int i = t; i < UVM * 24; i += 256) {
        int row = i / 24, c = (i % 24) * 8;
        *reinterpret_cast<bf16x8*>(&xs[row][c]) =
            *reinterpret_cast<const bf16x8*>(&xb[(size_t)(p0 + row) * NC + c]);
    }
    __syncthreads();
    int n0 = w * 96;
    f32x4 acc[2][6];
    #pragma unroll
    for (int mt = 0; mt < 2; ++mt)
        #pragma unroll
        for (int nt = 0; nt < 6; ++nt)
            acc[mt][nt] = (f32x4){0.f, 0.f, 0.f, 0.f};
    #pragma unroll
    for (int ks = 0; ks < 6; ++ks) {
        bf16x8 bfr[6];
        #pragma unroll
        for (int nt = 0; nt < 6; ++nt)
            bfr[nt] = *reinterpret_cast<const bf16x8*>(
                &w1t[(size_t)(n0 + nt * 16 + lr) * NC + ks * 32 + lg * 8]);
        bf16x8 a0 = *reinterpret_cast<const bf16x8*>(&xs[lr][ks * 32 + lg * 8]);
        bf16x8 a1 = *reinterpret_cast<const bf16x8*>(&xs[16 + lr][ks * 32 + lg * 8]);
        #pragma unroll
        for (int nt = 0; nt < 6; ++nt) {
            acc[0][nt] = __builtin_amdgcn_mfma_f32_16x16x32_bf16(a0, bfr[nt], acc[0][nt], 0, 0, 0);
            acc[1][nt] = __builtin_amdgcn_mfma_f32_16x16x32_bf16(a1, bfr[nt], acc[1][nt], 0, 0, 0);
        }
    }
    bool isU = (n0 < NC);
    #pragma unroll
    for (int nt = 0; nt < 6; ++nt) {
        int col = n0 + nt * 16 + lr;
        float bb = isU ? b1[col] : 0.f;
        int ocol = isU ? col : col - NC;
        ushort* dst = isU ? up : vv;
        #pragma unroll
        for (int mt = 0; mt < 2; ++mt)
            #pragma unroll
            for (int j = 0; j < 4; ++j) {
                int pt = p0 + mt * 16 + lg * 4 + j;
                dst[(size_t)pt * NC + ocol] = f2bf(acc[mt][nt][j] + bb);
            }
    }
}

// ---- kernel 2 (fused): uv2 (blocks 0..255) | sim4 (blocks 256..1279) ---------
__global__ void __launch_bounds__(256) k_uvsim(const ushort* __restrict__ xb,
                                               const ushort* __restrict__ w1t,
                                               const float* __restrict__ b1,
                                               ushort* __restrict__ up,
                                               ushort* __restrict__ vv,
                                               const ushort* __restrict__ xh,
                                               ushort* __restrict__ simh) {
    extern __shared__ char smem[];
    if (blockIdx.x < NB * NP / UVM) {
        dev_uv2((ushort(*)[200])smem, xb, w1t, b1, up, vv, blockIdx.x);
    } else {
        int sb_ = blockIdx.x - NB * NP / UVM;
        int bz = sb_ >> 8, rem = sb_ & 255, by = rem >> 4, bx = rem & 15;
        ushort (*Ah)[72] = (ushort(*)[72])smem;
        ushort (*Bh)[72] = Ah + 128;
        dev_sim4(Ah, Bh, xh, simh, bx, by, bz, (size_t)NP * NC, (size_t)NP * NP);
    }
}

// ---- standalone wrappers (ws-frugal fallback path) ---------------------------
__global__ void __launch_bounds__(256) k_uv2(const ushort* __restrict__ xb,
                                             const ushort* __restrict__ w1t,
                                             const float* __restrict__ b1,
                                             ushort* __restrict__ up,
                                             ushort* __restrict__ vv) {
    __shared__ ushort xs[UVM][200];
    dev_uv2(xs, xb, w1t, b1, up, vv, blockIdx.x);
}

__global__ void __launch_bounds__(256) k_sim4(const ushort* __restrict__ xh,
                                              ushort* __restrict__ simh,
                                              size_t xstride, size_t simstride) {
    __shared__ ushort Ah[128][72];
    __shared__ ushort Bh[128][72];
    dev_sim4(Ah, Bh, xh, simh, blockIdx.x, blockIdx.y, blockIdx.z, xstride, simstride);
}

// rare fallback: u32 insert list depth 16 + 16 extraction rounds (forceinline:
// pointer-escape would spill h8 to scratch — R12 lesson, 33 MB WRITE_SIZE).
__device__ __forceinline__ int topk_fb(const u16x8 h8[4], int p, int lane) {
    unsigned tv[16];
    #pragma unroll
    for (int q = 0; q < 16; ++q) tv[q] = 0u;
    #pragma unroll
    for (int i = 0; i < 4; ++i)
        #pragma unroll
        for (int j = 0; j < 8; ++j) {
            unsigned v = pkkey((unsigned)(ushort)h8[i][j], lane * 8 + i * 512 + j, p);
            if (v > tv[0]) {
                bool cg[16];
                #pragma unroll
                for (int q = 0; q < 16; ++q) cg[q] = v > tv[q];
                #pragma unroll
                for (int q = 0; q < 15; ++q)
                    tv[q] = cg[q + 1] ? tv[q + 1] : (cg[q] ? v : tv[q]);
                tv[15] = cg[15] ? v : tv[15];
            }
        }
    unsigned mp = 0u;
    #pragma unroll
    for (int rr = 0; rr < 16; ++rr) {
        unsigned bv = tv[15];
        #pragma unroll
        for (int off = 1; off < 64; off <<= 1) {
            unsigned ov = __shfl_xor(bv, off, 64);
            bv = ov > bv ? ov : bv;
        }
        if ((lane >> 2) == rr) mp = bv;
        if (bv == tv[15]) {
            #pragma unroll
            for (int s = 15; s > 0; --s) tv[s] = tv[s - 1];
            tv[0] = 0u;
        }
    }
    return (mp == 0u) ? -1 : (int)(2047u - (mp & 0x7FFu));
}

// ---- selection body: one row per wave; atomic-compact (no count/scan pass) ---
__device__ __forceinline__ void dev_topk_row(const ushort* __restrict__ sr,
                                             const float* __restrict__ xb,
                                             int p, unsigned* candw, int* cntw,
                                             int lane, int* out12) {
    u16x8 h8[4];
    #pragma unroll
    for (int i = 0; i < 4; ++i)
        h8[i] = *reinterpret_cast<const u16x8*>(sr + lane * 8 + i * 512);

    unsigned lmax = 0;
    #pragma unroll
    for (int i = 0; i < 4; ++i)
        #pragma unroll
        for (int j = 0; j < 8; ++j) {
            unsigned v = pkkey((unsigned)(ushort)h8[i][j], lane * 8 + i * 512 + j, p);
            lmax = v > lmax ? v : lmax;
        }

    unsigned sm = lmax;
    #pragma unroll
    for (int k = 2; k <= 64; k <<= 1) {
        #pragma unroll
        for (int j = k >> 1; j >= 1; j >>= 1) {
            unsigned ov = __shfl_xor(sm, j, 64);
            bool keep_lo = (((lane & k) != 0) == ((lane & j) == 0));
            unsigned lo = sm < ov ? sm : ov, hi = sm < ov ? ov : sm;
            sm = keep_lo ? lo : hi;
        }
    }
    unsigned theta = __shfl(sm, KSEL, 64);   // 17th-largest lane-max

    // atomic-counter compact: order irrelevant (bitonic canonicalizes);
    // >= KSEL candidates guaranteed (the 16 lane-maxes above theta are distinct).
    candw[lane] = 0u;
    if (lane == 0) *cntw = 0;
    asm volatile("s_waitcnt lgkmcnt(0)" ::: "memory");
    #pragma unroll
    for (int i = 0; i < 4; ++i)
        #pragma unroll
        for (int j = 0; j < 8; ++j) {
            unsigned v = pkkey((unsigned)(ushort)h8[i][j], lane * 8 + i * 512 + j, p);
            if (v > theta) {
                int pos = atomicAdd(cntw, 1);
                if (pos < 64) candw[pos] = v;
            }
        }
    asm volatile("s_waitcnt lgkmcnt(0)" ::: "memory");
    int total = *cntw;
    asm volatile("s_waitcnt lgkmcnt(0)" ::: "memory");

    int my_q;
    if (total <= 64) {
        unsigned v = candw[lane];
        #pragma unroll
        for (int k = 2; k <= 64; k <<= 1) {
            #pragma unroll
            for (int j = k >> 1; j >= 1; j >>= 1) {
                unsigned ov = __shfl_xor(v, j, 64);
                bool keep_lo = (((lane & k) != 0) == ((lane & j) == 0));
                unsigned lo = v < ov ? v : ov, hi = v < ov ? ov : v;
                v = keep_lo ? lo : hi;
            }
        }
        unsigned mp = __shfl(v, lane >> 2, 64);
        my_q = (mp == 0u) ? -1 : (int)(2047u - (mp & 0x7FFu));
    } else {
        my_q = topk_fb(h8, p, lane);   // rare overflow path
    }

    int qa = my_q < 0 ? 0 : my_q;
    const float* cp = xb + (size_t)p * NC + (lane & 3) * 48;
    const float* cq = xb + (size_t)qa * NC + (lane & 3) * 48;
    float dot = 0.f;
    #pragma unroll
    for (int i = 0; i < 12; ++i) {
        float4 a = *reinterpret_cast<const float4*>(cp + i * 4);
        float4 bq = *reinterpret_cast<const float4*>(cq + i * 4);
        dot += a.x * bq.x + a.y * bq.y + a.z * bq.z + a.w * bq.w;
    }
    dot += __shfl_xor(dot, 1, 64);
    dot += __shfl_xor(dot, 2, 64);
    int g = lane >> 2;
    int rank = 0;
    #pragma unroll
    for (int j = 0; j < KSEL; ++j) {
        float vj = __shfl(dot, j * 4, 64);
        int   qj = __shfl(my_q, j * 4, 64);
        if (j != g && qj >= 0 && (vj > dot || (vj == dot && qj < my_q))) ++rank;
    }
    bool keep = ((lane & 3) == 0) && (my_q >= 0) && (rank < KNN);
    unsigned long long mask = __ballot(keep);
    int pos = __popcll(mask & ((1ull << lane) - 1));
    if (keep) out12[pos] = my_q;
}

// -- kernel 3 (fallback): standalone top-k ------------------------------------
__global__ void __launch_bounds__(256) k_topk7(const ushort* __restrict__ simh,
                                               const float* __restrict__ xn,
                                               int* __restrict__ knn,
                                               size_t simstride, size_t xstride) {
    __shared__ unsigned cand[4][64];
    __shared__ int ccnt[4];
    int wv = threadIdx.x >> 6, lane = threadIdx.x & 63;
    int row = blockIdx.x * 4 + wv;
    int b = row / NP, p = row % NP;
    dev_topk_row(simh + (size_t)b * simstride + (size_t)p * NP,
                 xn + (size_t)b * xstride, p, cand[wv], &ccnt[wv], lane,
                 knn + (size_t)row * KNN);
}

// ---- edge body: one point per wave; 3-deep gather ring + setprio MFMA --------
__device__ __forceinline__ bf16x8 packh2(bf16x8 u, bf16x8 v) {
    union { bf16x8 v8; ushort us[8]; } U, V, R;
    U.v8 = u; V.v8 = v;
    #pragma unroll
    for (int i = 0; i < 8; i += 2) {
        float a0 = __uint_as_float((unsigned)U.us[i] << 16)
                 + __uint_as_float((unsigned)V.us[i] << 16);
        float a1 = __uint_as_float((unsigned)U.us[i + 1] << 16)
                 + __uint_as_float((unsigned)V.us[i + 1] << 16);
        __hip_bfloat162 h2 = __float22bfloat162_rn(make_float2(lrelu(a0), lrelu(a1)));
        R.us[i]     = *reinterpret_cast<const ushort*>(&h2.x);
        R.us[i + 1] = *reinterpret_cast<const ushort*>(&h2.y);
    }
    return R.v8;
}

__device__ __forceinline__ void dev_edge_point(const ushort* __restrict__ up,
                                               const ushort* __restrict__ vv,
                                               int q0, int pt0,
                                               ushort (*w2s)[200], float* aggsw,
                                               const float* __restrict__ b2,
                                               const float* __restrict__ gamma,
                                               const float* __restrict__ beta,
                                               float* __restrict__ out,
                                               int l, int lg, int lr) {
    int b = pt0 / NP;
    const ushort* u0p = up + (size_t)pt0 * NC + 8 * lg;
    const ushort* v0p = vv + ((size_t)b * NP + q0) * NC + 8 * lg;

    f32x4 acc[12];
    #pragma unroll
    for (int nt = 0; nt < 12; ++nt) acc[nt] = (f32x4){0.f, 0.f, 0.f, 0.f};

    bf16x8 sU[3], sV[3];
#define LDST(ph, ks) do { \
        sU[ph] = *reinterpret_cast<const bf16x8*>(u0p + (ks) * 32); \
        sV[ph] = *reinterpret_cast<const bf16x8*>(v0p + (ks) * 32); \
    } while (0)

    LDST(0, 0); LDST(1, 1); LDST(2, 2);
    #pragma unroll
    for (int ks = 0; ks < 6; ++ks) {
        int ph = ks % 3;
        bf16x8 a0 = packh2(sU[ph], sV[ph]);
        if (ks < 3) LDST(ph, ks + 3);
        __builtin_amdgcn_s_setprio(1);
        #pragma unroll
        for (int nt = 0; nt < 12; ++nt) {
            bf16x8 bfr = *reinterpret_cast<const bf16x8*>(&w2s[nt * 16 + lr][ks * 32 + lg * 8]);
            acc[nt] = __builtin_amdgcn_mfma_f32_16x16x32_bf16(a0, bfr, acc[nt], 0, 0, 0);
        }
        __builtin_amdgcn_s_setprio(0);
    }
#undef LDST

    #pragma unroll
    for (int nt = 0; nt < 12; ++nt) {
        float bb = b2[nt * 16 + lr];
        float s = 0.f;
        if (lg < 3) {
            #pragma unroll
            for (int j = 0; j < 4; ++j) s += lrelu(acc[nt][j] + bb);
        }
        s += __shfl_xor(s, 16, 64);
        s += __shfl_xor(s, 32, 64);
        if (lg == 0) aggsw[nt * 16 + lr] = s * (1.0f / KNN);
    }
    asm volatile("s_waitcnt lgkmcnt(0)" ::: "memory");

    float a0 = aggsw[l], a1 = aggsw[l + 64], a2 = aggsw[l + 128];
    float s = a0 + a1 + a2;
    #pragma unroll
    for (int off = 32; off; off >>= 1) s += __shfl_xor(s, off, 64);
    float mu = s / (float)NC;
    float d0 = a0 - mu, d1 = a1 - mu, d2 = a2 - mu;
    float vs = d0 * d0 + d1 * d1 + d2 * d2;
    #pragma unroll
    for (int off = 32; off; off >>= 1) vs += __shfl_xor(vs, off, 64);
    float rstd = 1.0f / sqrtf(vs / (float)NC + 1e-5f);
    float* o = out + (size_t)pt0 * NC;
    o[l]       = d0 * rstd * gamma[l]       + beta[l];
    o[l + 64]  = d1 * rstd * gamma[l + 64]  + beta[l + 64];
    o[l + 128] = d2 * rstd * gamma[l + 128] + beta[l + 128];
}

#define EW 16   // waves/block, 1 point each

// ---- kernel 3+5 fused: early W2 barrier, then wave-independent topk->edge ----
__global__ void __launch_bounds__(1024, 4) k_topkedge(const ushort* __restrict__ simh,
                                                      const float* __restrict__ xn,
                                                      const ushort* __restrict__ up,
                                                      const ushort* __restrict__ vv,
                                                      const ushort* __restrict__ w2t,
                                                      const float* __restrict__ b2,
                                                      const float* __restrict__ gamma,
                                                      const float* __restrict__ beta,
                                                      float* __restrict__ out) {
    __shared__ ushort w2s[NC][200];    // 76.8 KB
    __shared__ float aggs[EW][NC];     // 12.3 KB
    __shared__ unsigned cand[EW][64];  // 4 KB
    __shared__ int knn_s[EW][KNN];     // 0.75 KB
    __shared__ int ccnt[EW];
    int t = threadIdx.x;
    int wv = t >> 6, l = t & 63;
    int lg = l >> 4, lr = l & 15;

    int pt0 = blockIdx.x * EW + wv;
    int b = pt0 / NP, p = pt0 % NP;

    for (int i = t; i < NC * 24; i += 1024) {
        int r_ = i / 24, c_ = i % 24;
        *reinterpret_cast<bf16x8*>(&w2s[r_][c_ * 8]) =
            *reinterpret_cast<const bf16x8*>(&w2t[(size_t)r_ * NC + c_ * 8]);
    }
    __syncthreads();   // only block-wide barrier (w2s visibility)

    dev_topk_row(simh + (size_t)b * ((size_t)NP * NP) + (size_t)p * NP,
                 xn + (size_t)b * ((size_t)NP * NC), p, cand[wv], &ccnt[wv],
                 l, knn_s[wv]);
    asm volatile("s_waitcnt lgkmcnt(0)" ::: "memory");   // same-wave knn_s RAW

    int lre = l & 15; lre = lre < KNN ? lre : KNN - 1;
    int q0 = knn_s[wv][lre];
    dev_edge_point(up, vv, q0, pt0, w2s, aggs[wv], b2, gamma, beta, out, l, lg, lr);
}

// ---- standalone edge kernel (fallback path) ----------------------------------
__global__ void __launch_bounds__(1024, 4) k_edge7(const ushort* __restrict__ up,
                                                   const ushort* __restrict__ vv,
                                                   const int* __restrict__ knn,
                                                   const ushort* __restrict__ w2t,
                                                   const float* __restrict__ b2,
                                                   const float* __restrict__ gamma,
                                                   const float* __restrict__ beta,
                                                   float* __restrict__ out) {
    __shared__ ushort w2s[NC][200];
    __shared__ float aggs[EW][NC];
    int t = threadIdx.x;
    int wv = t >> 6, l = t & 63;
    int lg = l >> 4, lr = l & 15;

    int pt0 = blockIdx.x * EW + wv;
    int lre = lr < KNN ? lr : KNN - 1;
    int q0 = knn[(size_t)pt0 * KNN + lre];

    for (int i = t; i < NC * 24; i += 1024) {
        int r_ = i / 24, c_ = i % 24;
        *reinterpret_cast<bf16x8*>(&w2s[r_][c_ * 8]) =
            *reinterpret_cast<const bf16x8*>(&w2t[(size_t)r_ * NC + c_ * 8]);
    }
    __syncthreads();

    dev_edge_point(up, vv, q0, pt0, w2s, aggs[wv], b2, gamma, beta, out, l, lg, lr);
}

extern "C" void kernel_launch(void* const* d_in, const int* in_sizes, int n_in,
                              void* d_out, int out_size, void* d_ws, size_t ws_size,
                              hipStream_t stream) {
    const float* nodes = (const float*)d_in[0];
    const float* W1    = (const float*)d_in[1];
    const float* b1    = (const float*)d_in[2];
    const float* W2    = (const float*)d_in[3];
    const float* b2    = (const float*)d_in[4];
    const float* gamma = (const float*)d_in[5];
    const float* beta  = (const float*)d_in[6];
    float* out = (float*)d_out;

    const size_t BPC = (size_t)NB * NP * NC;
    float*  xn  = (float*)d_ws;                        // B*P*C f32
    ushort* up  = (ushort*)(xn + BPC);                 // B*P*C bf16
    ushort* vv  = up + BPC;                            // B*P*C bf16
    ushort* xh  = vv + BPC;                            // B*P*C bf16 (normalized)
    ushort* xb  = xh + BPC;                            // B*P*C bf16 (raw)
    int*    knn = (int*)(xb + BPC);                    // B*P*K (fallback only)
    ushort* w2t = (ushort*)(knn + (size_t)NB * NP * KNN); // C*C bf16
    ushort* w1t = w2t + (size_t)NC * NC;               // 2C*C bf16
    ushort* simh = (ushort*)(((uintptr_t)(w1t + (size_t)2 * NC * NC) + 15) & ~(uintptr_t)15);

    size_t fixed_bytes = (size_t)((char*)simh - (char*)d_ws);
    bool full = ws_size >= fixed_bytes + (size_t)NB * NP * NP * 2;

    int prep_grid = NB * NP / 4 + 2 * NC * NC / 256 + NC * NC / 256;   // 2048+288+144
    k_prep<<<prep_grid, 256, 0, stream>>>(nodes, W1, W2, xn, xh, xb, w1t, w2t);
    if (full) {
        k_uvsim<<<NB * NP / UVM + 16 * NB * (NP / 128), 256, 36864, stream>>>(
            xb, w1t, b1, up, vv, xh, simh);
        k_topkedge<<<NB * NP / EW, 1024, 0, stream>>>(simh, xn, up, vv, w2t,
                                                      b2, gamma, beta, out);
    } else {
        k_uv2<<<NB * NP / UVM, 256, 0, stream>>>(xb, w1t, b1, up, vv);
        for (int b = 0; b < NB; ++b) {
            k_sim4<<<dim3(NP / 128, NP / 128, 1), 256, 0, stream>>>(xh + (size_t)b * NP * NC, simh, 0, 0);
            k_topk7<<<NP / 4, 256, 0, stream>>>(simh, xn + (size_t)b * NP * NC,
                                                knn + (size_t)b * NP * KNN, 0, 0);
        }
        k_edge7<<<NB * NP / EW, 1024, 0, stream>>>(up, vv, knn, w2t, b2, gamma, beta, out);
    }
}